// Round 3
// baseline (196.129 us; speedup 1.0000x reference)
//
#include <hip/hip_runtime.h>

typedef __attribute__((ext_vector_type(8))) __bf16 bf16x8;
typedef __attribute__((ext_vector_type(4))) __bf16 bf16x4;
typedef __attribute__((ext_vector_type(4))) float  f32x4;

// Problem: x (8,512,32,32) fp32 -> B=8, C=512, T=1024; 32 groups; 8 heads (ch=64)

// ws layout (bytes)
static constexpr size_t QKV_OFF = 0;                     // fp32 (8,1536,1024) 48MB [gemm1..attn]
static constexpr size_t HT_OFF  = 50331648;              // bf16 (8,1024,512) 8MB: hT [gn..gemm1], aT [attn..gemm2]
static constexpr size_t WQ_OFF  = HT_OFF + 8388608;      // bf16 (1536,512) 1.5MB
static constexpr size_t WP_OFF  = WQ_OFF + 1572864;      // bf16 (512,512) 0.5MB
static constexpr size_t MM_OFF  = WP_OFF + 524288;       // 6 x u32
static constexpr size_t KI_OFF  = MM_OFF + 4096;         // bf16 (64,1024,64) 8MB  [new path]
static constexpr size_t VI_OFF  = KI_OFF + 8388608;      // bf16 (64,64,1024) 8MB  [new path]
static constexpr size_t NEED_NEW = VI_OFF + 8388608;

__device__ __forceinline__ unsigned encf(float f) {
    unsigned u = __float_as_uint(f);
    return (u & 0x80000000u) ? ~u : (u | 0x80000000u);
}
__device__ __forceinline__ float decf(unsigned e) {
    unsigned u = (e & 0x80000000u) ? (e & 0x7fffffffu) : ~e;
    return __uint_as_float(u);
}
// integer-valued dequant core: clip(rint(x/s)+zp,0,255)-zp == clip(rint(x/s), -zp, 255-zp)
__device__ __forceinline__ float dqi(float x, float inv_s, float zp) {
    float y = rintf(x * inv_s);
    return fminf(fmaxf(y, -zp), 255.0f - zp);
}
__device__ __forceinline__ f32x4 mfma16(bf16x8 a, bf16x8 b, f32x4 c) {
    return __builtin_amdgcn_mfma_f32_16x16x32_bf16(a, b, c, 0, 0, 0);
}

// ---------------- prep: weight fp32->bf16 (both) + mm init ----------------
__global__ __launch_bounds__(256) void prep(const float* __restrict__ qw,
                                            __bf16* __restrict__ wq,
                                            const float* __restrict__ pw,
                                            __bf16* __restrict__ wp,
                                            unsigned* __restrict__ mm) {
    int bid = blockIdx.x, tid = threadIdx.x;
    if (bid == 0 && tid < 3) { mm[2 * tid] = 0xFFFFFFFFu; mm[2 * tid + 1] = 0u; }
    if (bid < 768) {
        int i = bid * 256 + tid;
        float4 v = ((const float4*)qw)[i];
        bf16x4 o = {(__bf16)v.x, (__bf16)v.y, (__bf16)v.z, (__bf16)v.w};
        ((bf16x4*)wq)[i] = o;
    } else {
        int i = (bid - 768) * 256 + tid;
        float4 v = ((const float4*)pw)[i];
        bf16x4 o = {(__bf16)v.x, (__bf16)v.y, (__bf16)v.z, (__bf16)v.w};
        ((bf16x4*)wp)[i] = o;
    }
}

// ---------------- GroupNorm -> hT bf16 (B,T,C) ----------------
__global__ __launch_bounds__(256) void gn_kernel(const float* __restrict__ x,
                                                 const float* __restrict__ w,
                                                 const float* __restrict__ bv,
                                                 __bf16* __restrict__ hT) {
    int blk = blockIdx.x;
    int b = blk >> 5, g = blk & 31;
    const float* xp = x + (size_t)(b * 512 + g * 16) * 1024;
    int tid = threadIdx.x;

    float sum = 0.f, ss = 0.f;
#pragma unroll
    for (int i = 0; i < 16; ++i) {
        float4 v = *(const float4*)(xp + (size_t)i * 1024 + tid * 4);
        sum += v.x + v.y + v.z + v.w;
        ss  += v.x * v.x + v.y * v.y + v.z * v.z + v.w * v.w;
    }
#pragma unroll
    for (int m = 1; m < 64; m <<= 1) {
        sum += __shfl_xor(sum, m);
        ss  += __shfl_xor(ss, m);
    }
    __shared__ float s1[4], s2[4];
    int wid = tid >> 6;
    if ((tid & 63) == 0) { s1[wid] = sum; s2[wid] = ss; }
    __syncthreads();
    sum = s1[0] + s1[1] + s1[2] + s1[3];
    ss  = s2[0] + s2[1] + s2[2] + s2[3];
    float mean = sum * (1.0f / 16384.0f);
    float var  = ss * (1.0f / 16384.0f) - mean * mean;
    float rstd = rsqrtf(var + 1e-5f);

    int cl = ((tid >> 4) & 3) * 4;
    int tb = (tid & 15) + ((tid >> 6) << 4);
    float wc[4], bc[4];
#pragma unroll
    for (int j = 0; j < 4; ++j) { wc[j] = w[g * 16 + cl + j]; bc[j] = bv[g * 16 + cl + j]; }
    __bf16* hp = hT + (size_t)b * 1024 * 512 + g * 16 + cl;
#pragma unroll
    for (int r = 0; r < 16; ++r) {
        int t = tb + r * 64;
        float o0 = (xp[(size_t)(cl + 0) * 1024 + t] - mean) * rstd * wc[0] + bc[0];
        float o1 = (xp[(size_t)(cl + 1) * 1024 + t] - mean) * rstd * wc[1] + bc[1];
        float o2 = (xp[(size_t)(cl + 2) * 1024 + t] - mean) * rstd * wc[2] + bc[2];
        float o3 = (xp[(size_t)(cl + 3) * 1024 + t] - mean) * rstd * wc[3] + bc[3];
        bf16x4 ob = {(__bf16)o0, (__bf16)o1, (__bf16)o2, (__bf16)o3};
        *(bf16x4*)(hp + (size_t)t * 512) = ob;
    }
}

// ---------------- MFMA GEMM (both operands row-major, k-fastest) ----------------
template <bool MINMAX, bool RESID>
__global__ __launch_bounds__(256) void mgemm(const __bf16* __restrict__ A,   // [M][512]
                                             const __bf16* __restrict__ Bt,  // [8][1024][512]
                                             const float* __restrict__ bias,
                                             const float* __restrict__ resid,
                                             float* __restrict__ out,
                                             int M, unsigned* __restrict__ mm) {
    __shared__ __bf16 sA[128][72];
    __shared__ __bf16 sB[128][72];
    __shared__ float smn[4], smx[4];
    int tid = threadIdx.x;
    int l = tid & 63, w = tid >> 6;
    int lo = l & 15, hi = l >> 4;
    int mo = blockIdx.x, nt = blockIdx.y, b = blockIdx.z;
    const __bf16* Ap = A + (size_t)mo * 128 * 512;
    const __bf16* Bp = Bt + ((size_t)b * 1024 + (size_t)nt * 128) * 512;
    int m0 = (w >> 1) * 64, n0 = (w & 1) * 64;
    f32x4 acc[4][4] = {};

    for (int k0 = 0; k0 < 512; k0 += 64) {
        __syncthreads();
#pragma unroll
        for (int p = 0; p < 4; ++p) {
            int s = tid + p * 256;
            int row = s >> 3, ch = (s & 7) * 8;
            *(bf16x8*)&sA[row][ch] = *(const bf16x8*)(Ap + (size_t)row * 512 + k0 + ch);
            *(bf16x8*)&sB[row][ch] = *(const bf16x8*)(Bp + (size_t)row * 512 + k0 + ch);
        }
        __syncthreads();
#pragma unroll
        for (int kk = 0; kk < 2; ++kk) {
            int co = kk * 32 + hi * 8;
            bf16x8 af[4], bfr[4];
#pragma unroll
            for (int i = 0; i < 4; ++i) af[i]  = *(const bf16x8*)&sA[m0 + 16 * i + lo][co];
#pragma unroll
            for (int j = 0; j < 4; ++j) bfr[j] = *(const bf16x8*)&sB[n0 + 16 * j + lo][co];
#pragma unroll
            for (int i = 0; i < 4; ++i)
#pragma unroll
                for (int j = 0; j < 4; ++j) acc[i][j] = mfma16(af[i], bfr[j], acc[i][j]);
        }
    }

    float mn = 1e30f, mx = -1e30f;
    int gcol = nt * 128 + n0 + lo;
#pragma unroll
    for (int i = 0; i < 4; ++i) {
#pragma unroll
        for (int r = 0; r < 4; ++r) {
            int grow = mo * 128 + m0 + 16 * i + hi * 4 + r;
            float bi = bias[grow];
            size_t base = ((size_t)b * M + grow) * 1024 + gcol;
#pragma unroll
            for (int j = 0; j < 4; ++j) {
                float v = acc[i][j][r] + bi;
                if (MINMAX) { mn = fminf(mn, v); mx = fmaxf(mx, v); }
                if (RESID) v += resid[base + 16 * j];
                out[base + 16 * j] = v;
            }
        }
    }

    if (MINMAX) {
#pragma unroll
        for (int msk = 1; msk < 64; msk <<= 1) {
            mn = fminf(mn, __shfl_xor(mn, msk));
            mx = fmaxf(mx, __shfl_xor(mx, msk));
        }
        if (l == 0) { smn[w] = mn; smx[w] = mx; }
        __syncthreads();
        if (tid == 0) {
            mn = fminf(fminf(smn[0], smn[1]), fminf(smn[2], smn[3]));
            mx = fmaxf(fmaxf(smx[0], smx[1]), fmaxf(smx[2], smx[3]));
            int id = mo >> 2;
            atomicMin(&mm[2 * id], encf(mn));
            atomicMax(&mm[2 * id + 1], encf(mx));
        }
    }
}

// ---------------- quant K/V pass ----------------
// grid (64 bh, 16 tile); writes integer-valued bf16: ki (bh,s,c), vi (bh,c,s)
__global__ __launch_bounds__(256) void quant_kv(const float* __restrict__ qkv,
                                                const unsigned* __restrict__ mm,
                                                __bf16* __restrict__ ki,
                                                __bf16* __restrict__ vi) {
    int bh = blockIdx.x, tt = blockIdx.y;
    int b = bh >> 3, hh = bh & 7;
    int t0 = tt * 64;
    const float* kg = qkv + ((size_t)(b * 1536 + hh * 192) + 64) * 1024;
    const float* vg = kg + (size_t)64 * 1024;

    float mn1 = fminf(decf(mm[2]), 0.f), mx1 = fmaxf(decf(mm[3]), 0.f);
    float ksc = fmaxf((mx1 - mn1) * (1.f / 255.f), 1e-8f), kzp = rintf(-mn1 / ksc);
    float mn2 = fminf(decf(mm[4]), 0.f), mx2 = fmaxf(decf(mm[5]), 0.f);
    float vsc = fmaxf((mx2 - mn2) * (1.f / 255.f), 1e-8f), vzp = rintf(-mn2 / vsc);
    float inv_k = 1.f / ksc, inv_v = 1.f / vsc;

    __shared__ __bf16 sT[64][68];
    int tid = threadIdx.x;

    // V stream (layout unchanged)
    __bf16* vd = vi + (size_t)bh * 64 * 1024;
#pragma unroll
    for (int r = 0; r < 4; ++r) {
        int c = 16 * r + (tid >> 4), t4 = tid & 15;
        float4 v = *(const float4*)(vg + (size_t)c * 1024 + t0 + t4 * 4);
        bf16x4 o = {(__bf16)dqi(v.x, inv_v, vzp), (__bf16)dqi(v.y, inv_v, vzp),
                    (__bf16)dqi(v.z, inv_v, vzp), (__bf16)dqi(v.w, inv_v, vzp)};
        *(bf16x4*)(vd + (size_t)c * 1024 + t0 + t4 * 4) = o;
    }

    // K transpose via LDS -> (s, c)
#pragma unroll
    for (int r = 0; r < 4; ++r) {
        int c = 16 * r + (tid >> 4), t4 = tid & 15;
        float4 v = *(const float4*)(kg + (size_t)c * 1024 + t0 + t4 * 4);
        sT[t4 * 4 + 0][c] = (__bf16)dqi(v.x, inv_k, kzp);
        sT[t4 * 4 + 1][c] = (__bf16)dqi(v.y, inv_k, kzp);
        sT[t4 * 4 + 2][c] = (__bf16)dqi(v.z, inv_k, kzp);
        sT[t4 * 4 + 3][c] = (__bf16)dqi(v.w, inv_k, kzp);
    }
    __syncthreads();
    int s = tid >> 2, c0 = (tid & 3) * 16;
    bf16x8 a0 = *(const bf16x8*)&sT[s][c0];
    bf16x8 a1 = *(const bf16x8*)&sT[s][c0 + 8];
    __bf16* kd = ki + ((size_t)bh * 1024 + t0 + s) * 64 + c0;
    *(bf16x8*)kd = a0;
    *(bf16x8*)(kd + 8) = a1;
}

// ---------------- attention v2: bf16 K/V direct from L2, MFMA ----------------
__global__ __launch_bounds__(256) void attn2(const float* __restrict__ qkv,
                                             const __bf16* __restrict__ ki,
                                             const __bf16* __restrict__ vi,
                                             const unsigned* __restrict__ mm,
                                             __bf16* __restrict__ aT) {
    int f = blockIdx.x;
    int bh = (f & 7) * 8 + ((f >> 3) & 7);  // 8 heads x 16 t-tiles per XCD
    int tt = f >> 6;
    int b = bh >> 3, hh = bh & 7;
    int t0 = tt * 64;
    const float* qg = qkv + (size_t)(b * 1536 + hh * 192) * 1024;
    const __bf16* kb = ki + (size_t)bh * 1024 * 64;
    const __bf16* vb = vi + (size_t)bh * 64 * 1024;

    float mn0 = fminf(decf(mm[0]), 0.f), mx0 = fmaxf(decf(mm[1]), 0.f);
    float qsc = fmaxf((mx0 - mn0) * (1.f / 255.f), 1e-8f), qzp = rintf(-mn0 / qsc);
    float mn1 = fminf(decf(mm[2]), 0.f), mx1 = fmaxf(decf(mm[3]), 0.f);
    float ksc = fmaxf((mx1 - mn1) * (1.f / 255.f), 1e-8f);
    float mn2 = fminf(decf(mm[4]), 0.f), mx2 = fmaxf(decf(mm[5]), 0.f);
    float vsc = fmaxf((mx2 - mn2) * (1.f / 255.f), 1e-8f);
    float inv_q = 1.f / qsc;
    float alpha = qsc * ksc * 0.125f;

    __shared__ __bf16 sh[64][72];  // q stage -> per-wave P -> output stage
    int tid = threadIdx.x;
    int l = tid & 63, w = tid >> 6;
    int lo = l & 15, hi = l >> 4;

    // stage q tile transposed (integer-valued bf16)
    {
        int c0 = (tid >> 4) * 4, tl = tid & 15;
#pragma unroll
        for (int r = 0; r < 4; ++r) {
            int t = tl + 16 * r;
            float y0 = dqi(qg[(size_t)(c0 + 0) * 1024 + t0 + t], inv_q, qzp);
            float y1 = dqi(qg[(size_t)(c0 + 1) * 1024 + t0 + t], inv_q, qzp);
            float y2 = dqi(qg[(size_t)(c0 + 2) * 1024 + t0 + t], inv_q, qzp);
            float y3 = dqi(qg[(size_t)(c0 + 3) * 1024 + t0 + t], inv_q, qzp);
            bf16x4 o = {(__bf16)y0, (__bf16)y1, (__bf16)y2, (__bf16)y3};
            *(bf16x4*)&sh[t][c0] = o;
        }
    }
    __syncthreads();
    bf16x8 qf0 = *(const bf16x8*)&sh[16 * w + lo][hi * 8];
    bf16x8 qf1 = *(const bf16x8*)&sh[16 * w + lo][32 + hi * 8];
    // no barrier needed: wave w's P region (rows 16w..16w+15) is wave-private

    f32x4 acc0 = {}, acc1 = {}, acc2 = {}, acc3 = {};
    float m_run = -1e30f, l_run = 0.f;

    for (int st = 0; st < 16; ++st) {
        const __bf16* kt = kb + (size_t)(st * 64) * 64;
        const __bf16* vt = vb + st * 64;

        // scores: D[s][t] = K·Q (A-frags straight from L2)
        f32x4 sf[4] = {};
#pragma unroll
        for (int sm = 0; sm < 4; ++sm)
            sf[sm] = mfma16(*(const bf16x8*)(kt + (size_t)(16 * sm + lo) * 64 + hi * 8), qf0, sf[sm]);
#pragma unroll
        for (int sm = 0; sm < 4; ++sm)
            sf[sm] = mfma16(*(const bf16x8*)(kt + (size_t)(16 * sm + lo) * 64 + 32 + hi * 8), qf1, sf[sm]);

        // online softmax (t = lane-local)
        float tm = -1e30f;
#pragma unroll
        for (int sm = 0; sm < 4; ++sm)
#pragma unroll
            for (int r = 0; r < 4; ++r) { sf[sm][r] *= alpha; tm = fmaxf(tm, sf[sm][r]); }
        tm = fmaxf(tm, __shfl_xor(tm, 16));
        tm = fmaxf(tm, __shfl_xor(tm, 32));
        float mnew = fmaxf(m_run, tm);
        float ts = 0.f;
#pragma unroll
        for (int sm = 0; sm < 4; ++sm)
#pragma unroll
            for (int r = 0; r < 4; ++r) {
                float p = __expf(sf[sm][r] - mnew);
                sf[sm][r] = p;
                ts += p;
            }
        ts += __shfl_xor(ts, 16);
        ts += __shfl_xor(ts, 32);
        float fr = __expf(m_run - mnew);
        l_run = l_run * fr + ts;
        m_run = mnew;
        acc0 *= fr; acc1 *= fr; acc2 *= fr; acc3 *= fr;

        // P -> LDS (wave-private rows)
#pragma unroll
        for (int sm = 0; sm < 4; ++sm) {
            bf16x4 pb = {(__bf16)sf[sm][0], (__bf16)sf[sm][1], (__bf16)sf[sm][2], (__bf16)sf[sm][3]};
            *(bf16x4*)&sh[16 * w + lo][16 * sm + hi * 4] = pb;
        }
        bf16x8 pf0 = *(const bf16x8*)&sh[16 * w + lo][hi * 8];
        bf16x8 pf1 = *(const bf16x8*)&sh[16 * w + lo][32 + hi * 8];

        // PV: D[c][t] += V·P  (V A-frags straight from L2)
        acc0 = mfma16(*(const bf16x8*)(vt + (size_t)(lo) * 1024 + hi * 8), pf0, acc0);
        acc1 = mfma16(*(const bf16x8*)(vt + (size_t)(16 + lo) * 1024 + hi * 8), pf0, acc1);
        acc2 = mfma16(*(const bf16x8*)(vt + (size_t)(32 + lo) * 1024 + hi * 8), pf0, acc2);
        acc3 = mfma16(*(const bf16x8*)(vt + (size_t)(48 + lo) * 1024 + hi * 8), pf0, acc3);
        acc0 = mfma16(*(const bf16x8*)(vt + (size_t)(lo) * 1024 + 32 + hi * 8), pf1, acc0);
        acc1 = mfma16(*(const bf16x8*)(vt + (size_t)(16 + lo) * 1024 + 32 + hi * 8), pf1, acc1);
        acc2 = mfma16(*(const bf16x8*)(vt + (size_t)(32 + lo) * 1024 + 32 + hi * 8), pf1, acc2);
        acc3 = mfma16(*(const bf16x8*)(vt + (size_t)(48 + lo) * 1024 + 32 + hi * 8), pf1, acc3);
    }

    float rl = vsc / l_run;
    __syncthreads();  // everyone done with P region before output staging reads cross-wave
    {
        bf16x4 o0 = {(__bf16)(acc0[0] * rl), (__bf16)(acc0[1] * rl), (__bf16)(acc0[2] * rl), (__bf16)(acc0[3] * rl)};
        bf16x4 o1 = {(__bf16)(acc1[0] * rl), (__bf16)(acc1[1] * rl), (__bf16)(acc1[2] * rl), (__bf16)(acc1[3] * rl)};
        bf16x4 o2 = {(__bf16)(acc2[0] * rl), (__bf16)(acc2[1] * rl), (__bf16)(acc2[2] * rl), (__bf16)(acc2[3] * rl)};
        bf16x4 o3 = {(__bf16)(acc3[0] * rl), (__bf16)(acc3[1] * rl), (__bf16)(acc3[2] * rl), (__bf16)(acc3[3] * rl)};
        *(bf16x4*)&sh[16 * w + lo][0  + hi * 4] = o0;
        *(bf16x4*)&sh[16 * w + lo][16 + hi * 4] = o1;
        *(bf16x4*)&sh[16 * w + lo][32 + hi * 4] = o2;
        *(bf16x4*)&sh[16 * w + lo][48 + hi * 4] = o3;
    }
    __syncthreads();
    __bf16* ap = aT + ((size_t)b * 1024 + t0 + (tid >> 2)) * 512 + hh * 64;
    bf16x8 v0 = *(const bf16x8*)&sh[tid >> 2][(tid & 3) * 8];
    bf16x8 v1 = *(const bf16x8*)&sh[tid >> 2][32 + (tid & 3) * 8];
    *(bf16x8*)(ap + (tid & 3) * 8) = v0;
    *(bf16x8*)(ap + 32 + (tid & 3) * 8) = v1;
}

// ---------------- fallback attention (round-2, used if ws too small) ----------------
__global__ __launch_bounds__(256) void attn_mfma(const float* __restrict__ qkv,
                                                 const unsigned* __restrict__ mm,
                                                 __bf16* __restrict__ aT) {
    int f = blockIdx.x;
    int bh = (f & 7) * 8 + ((f >> 3) & 7);
    int tt = f >> 6;
    int b = bh >> 3, hh = bh & 7;
    int t0 = tt * 64;
    const float* qg = qkv + (size_t)(b * 1536 + hh * 192) * 1024;
    const float* kg = qg + (size_t)64 * 1024;
    const float* vg = qg + (size_t)128 * 1024;

    float mn0 = fminf(decf(mm[0]), 0.f), mx0 = fmaxf(decf(mm[1]), 0.f);
    float qsc = fmaxf((mx0 - mn0) * (1.f / 255.f), 1e-8f), qzp = rintf(-mn0 / qsc);
    float mn1 = fminf(decf(mm[2]), 0.f), mx1 = fmaxf(decf(mm[3]), 0.f);
    float ksc = fmaxf((mx1 - mn1) * (1.f / 255.f), 1e-8f), kzp = rintf(-mn1 / ksc);
    float mn2 = fminf(decf(mm[4]), 0.f), mx2 = fmaxf(decf(mm[5]), 0.f);
    float vsc = fmaxf((mx2 - mn2) * (1.f / 255.f), 1e-8f), vzp = rintf(-mn2 / vsc);
    float inv_q = 1.f / qsc, inv_k = 1.f / ksc, inv_v = 1.f / vsc;
    float alpha = qsc * ksc * 0.125f;

    __shared__ __bf16 qT[64][72];
    __shared__ __bf16 kT[64][72];
    __shared__ __bf16 vL[64][72];
    __shared__ __bf16 pL[4][16][72];

    int tid = threadIdx.x;
    int l = tid & 63, w = tid >> 6;
    int lo = l & 15, hi = l >> 4;
    int c0 = (tid >> 4) * 4;
    int tl = tid & 15;

#pragma unroll
    for (int r = 0; r < 4; ++r) {
        int t = tl + 16 * r;
        float y0 = dqi(qg[(size_t)(c0 + 0) * 1024 + t0 + t], inv_q, qzp);
        float y1 = dqi(qg[(size_t)(c0 + 1) * 1024 + t0 + t], inv_q, qzp);
        float y2 = dqi(qg[(size_t)(c0 + 2) * 1024 + t0 + t], inv_q, qzp);
        float y3 = dqi(qg[(size_t)(c0 + 3) * 1024 + t0 + t], inv_q, qzp);
        bf16x4 o = {(__bf16)y0, (__bf16)y1, (__bf16)y2, (__bf16)y3};
        *(bf16x4*)&qT[t][c0] = o;
    }
    __syncthreads();
    bf16x8 qf0 = *(const bf16x8*)&qT[16 * w + lo][hi * 8];
    bf16x8 qf1 = *(const bf16x8*)&qT[16 * w + lo][32 + hi * 8];

    f32x4 acc0 = {}, acc1 = {}, acc2 = {}, acc3 = {};
    float m_run = -1e30f, l_run = 0.f;

    for (int st = 0; st < 16; ++st) {
        int s0 = st * 64;
        __syncthreads();
#pragma unroll
        for (int r = 0; r < 4; ++r) {
            int srow = tl + 16 * r;
            float y0 = dqi(kg[(size_t)(c0 + 0) * 1024 + s0 + srow], inv_k, kzp);
            float y1 = dqi(kg[(size_t)(c0 + 1) * 1024 + s0 + srow], inv_k, kzp);
            float y2 = dqi(kg[(size_t)(c0 + 2) * 1024 + s0 + srow], inv_k, kzp);
            float y3 = dqi(kg[(size_t)(c0 + 3) * 1024 + s0 + srow], inv_k, kzp);
            bf16x4 ok = {(__bf16)y0, (__bf16)y1, (__bf16)y2, (__bf16)y3};
            *(bf16x4*)&kT[srow][c0] = ok;
            int c = (tid >> 4) + 16 * r;
            float4 vv = *(const float4*)(vg + (size_t)c * 1024 + s0 + (tid & 15) * 4);
            bf16x4 ov = {(__bf16)dqi(vv.x, inv_v, vzp), (__bf16)dqi(vv.y, inv_v, vzp),
                         (__bf16)dqi(vv.z, inv_v, vzp), (__bf16)dqi(vv.w, inv_v, vzp)};
            *(bf16x4*)&vL[c][(tid & 15) * 4] = ov;
        }
        __syncthreads();

        f32x4 sf[4] = {};
#pragma unroll
        for (int sm = 0; sm < 4; ++sm)
            sf[sm] = mfma16(*(const bf16x8*)&kT[16 * sm + lo][hi * 8], qf0, sf[sm]);
#pragma unroll
        for (int sm = 0; sm < 4; ++sm)
            sf[sm] = mfma16(*(const bf16x8*)&kT[16 * sm + lo][32 + hi * 8], qf1, sf[sm]);

        float tm = -1e30f;
#pragma unroll
        for (int sm = 0; sm < 4; ++sm)
#pragma unroll
            for (int r = 0; r < 4; ++r) { sf[sm][r] *= alpha; tm = fmaxf(tm, sf[sm][r]); }
        tm = fmaxf(tm, __shfl_xor(tm, 16));
        tm = fmaxf(tm, __shfl_xor(tm, 32));
        float mnew = fmaxf(m_run, tm);
        float ts = 0.f;
#pragma unroll
        for (int sm = 0; sm < 4; ++sm)
#pragma unroll
            for (int r = 0; r < 4; ++r) {
                float p = __expf(sf[sm][r] - mnew);
                sf[sm][r] = p;
                ts += p;
            }
        ts += __shfl_xor(ts, 16);
        ts += __shfl_xor(ts, 32);
        float fr = __expf(m_run - mnew);
        l_run = l_run * fr + ts;
        m_run = mnew;
        acc0 *= fr; acc1 *= fr; acc2 *= fr; acc3 *= fr;

#pragma unroll
        for (int sm = 0; sm < 4; ++sm) {
            bf16x4 pb = {(__bf16)sf[sm][0], (__bf16)sf[sm][1], (__bf16)sf[sm][2], (__bf16)sf[sm][3]};
            *(bf16x4*)&pL[w][lo][16 * sm + hi * 4] = pb;
        }
        bf16x8 pf0 = *(const bf16x8*)&pL[w][lo][hi * 8];
        bf16x8 pf1 = *(const bf16x8*)&pL[w][lo][32 + hi * 8];
        acc0 = mfma16(*(const bf16x8*)&vL[lo][hi * 8], pf0, acc0);
        acc1 = mfma16(*(const bf16x8*)&vL[16 + lo][hi * 8], pf0, acc1);
        acc2 = mfma16(*(const bf16x8*)&vL[32 + lo][hi * 8], pf0, acc2);
        acc3 = mfma16(*(const bf16x8*)&vL[48 + lo][hi * 8], pf0, acc3);
        acc0 = mfma16(*(const bf16x8*)&vL[lo][32 + hi * 8], pf1, acc0);
        acc1 = mfma16(*(const bf16x8*)&vL[16 + lo][32 + hi * 8], pf1, acc1);
        acc2 = mfma16(*(const bf16x8*)&vL[32 + lo][32 + hi * 8], pf1, acc2);
        acc3 = mfma16(*(const bf16x8*)&vL[48 + lo][32 + hi * 8], pf1, acc3);
    }

    float rl = vsc / l_run;
    __syncthreads();
    {
        bf16x4 o0 = {(__bf16)(acc0[0] * rl), (__bf16)(acc0[1] * rl), (__bf16)(acc0[2] * rl), (__bf16)(acc0[3] * rl)};
        bf16x4 o1 = {(__bf16)(acc1[0] * rl), (__bf16)(acc1[1] * rl), (__bf16)(acc1[2] * rl), (__bf16)(acc1[3] * rl)};
        bf16x4 o2 = {(__bf16)(acc2[0] * rl), (__bf16)(acc2[1] * rl), (__bf16)(acc2[2] * rl), (__bf16)(acc2[3] * rl)};
        bf16x4 o3 = {(__bf16)(acc3[0] * rl), (__bf16)(acc3[1] * rl), (__bf16)(acc3[2] * rl), (__bf16)(acc3[3] * rl)};
        *(bf16x4*)&qT[16 * w + lo][0  + hi * 4] = o0;
        *(bf16x4*)&qT[16 * w + lo][16 + hi * 4] = o1;
        *(bf16x4*)&qT[16 * w + lo][32 + hi * 4] = o2;
        *(bf16x4*)&qT[16 * w + lo][48 + hi * 4] = o3;
    }
    __syncthreads();
    __bf16* ap = aT + ((size_t)b * 1024 + t0 + (tid >> 2)) * 512 + hh * 64;
    bf16x8 v0 = *(const bf16x8*)&qT[tid >> 2][(tid & 3) * 8];
    bf16x8 v1 = *(const bf16x8*)&qT[tid >> 2][32 + (tid & 3) * 8];
    *(bf16x8*)(ap + (tid & 3) * 8) = v0;
    *(bf16x8*)(ap + 32 + (tid & 3) * 8) = v1;
}

extern "C" void kernel_launch(void* const* d_in, const int* in_sizes, int n_in,
                              void* d_out, int out_size, void* d_ws, size_t ws_size,
                              hipStream_t stream) {
    const float* x      = (const float*)d_in[0];
    const float* gn_w   = (const float*)d_in[1];
    const float* gn_b   = (const float*)d_in[2];
    const float* qkv_w  = (const float*)d_in[3];
    const float* qkv_b  = (const float*)d_in[4];
    const float* proj_w = (const float*)d_in[5];
    const float* proj_b = (const float*)d_in[6];
    char* ws = (char*)d_ws;
    float*    qkv = (float*)(ws + QKV_OFF);
    __bf16*   hT  = (__bf16*)(ws + HT_OFF);   // hT, later reused as aT
    __bf16*   wq  = (__bf16*)(ws + WQ_OFF);
    __bf16*   wp  = (__bf16*)(ws + WP_OFF);
    unsigned* mm  = (unsigned*)(ws + MM_OFF);
    __bf16*   ki  = (__bf16*)(ws + KI_OFF);
    __bf16*   vi  = (__bf16*)(ws + VI_OFF);
    float* out = (float*)d_out;

    prep<<<1024, 256, 0, stream>>>(qkv_w, wq, proj_w, wp, mm);
    gn_kernel<<<256, 256, 0, stream>>>(x, gn_w, gn_b, hT);
    mgemm<true, false><<<dim3(12, 8, 8), 256, 0, stream>>>(wq, hT, qkv_b, nullptr, qkv, 1536, mm);
    if (ws_size >= NEED_NEW) {
        quant_kv<<<dim3(64, 16), 256, 0, stream>>>(qkv, mm, ki, vi);
        attn2<<<1024, 256, 0, stream>>>(qkv, ki, vi, mm, hT);
    } else {
        attn_mfma<<<1024, 256, 0, stream>>>(qkv, mm, hT);
    }
    mgemm<false, true><<<dim3(4, 8, 8), 256, 0, stream>>>(wp, hT, proj_b, x, out, 512, nullptr);
}

// Round 4
// 120.891 us; speedup vs baseline: 1.6224x; 1.6224x over previous
//
#include <hip/hip_runtime.h>

typedef __attribute__((ext_vector_type(8))) __bf16 bf16x8;
typedef __attribute__((ext_vector_type(4))) __bf16 bf16x4;
typedef __attribute__((ext_vector_type(4))) float  f32x4;

// Problem: x (8,512,32,32) fp32 -> B=8, C=512, T=1024; 32 groups; 8 heads (ch=64)

// ws layout (bytes)
static constexpr size_t QKV_OFF = 0;                     // fp32 (8,1536,1024) 48MB [gemm1..attn]
static constexpr size_t HT_OFF  = 50331648;              // bf16 (8,1024,512) 8MB: hT [gn..gemm1], aT [attn..gemm2]
static constexpr size_t WQ_OFF  = HT_OFF + 8388608;      // bf16 (1536,512) 1.5MB
static constexpr size_t WP_OFF  = WQ_OFF + 1572864;      // bf16 (512,512) 0.5MB
static constexpr size_t MM_OFF  = WP_OFF + 524288;       // 6 x u32
static constexpr size_t KI_OFF  = MM_OFF + 4096;         // bf16 (64,1024,64) 8MB
static constexpr size_t VI_OFF  = KI_OFF + 8388608;      // bf16 (64,64,1024) 8MB
static constexpr size_t NEED_NEW = VI_OFF + 8388608;

__device__ __forceinline__ unsigned encf(float f) {
    unsigned u = __float_as_uint(f);
    return (u & 0x80000000u) ? ~u : (u | 0x80000000u);
}
__device__ __forceinline__ float decf(unsigned e) {
    unsigned u = (e & 0x80000000u) ? (e & 0x7fffffffu) : ~e;
    return __uint_as_float(u);
}
// integer-valued dequant core: clip(rint(x/s)+zp,0,255)-zp == clip(rint(x/s), -zp, 255-zp)
__device__ __forceinline__ float dqi(float x, float inv_s, float zp) {
    float y = rintf(x * inv_s);
    return fminf(fmaxf(y, -zp), 255.0f - zp);
}
__device__ __forceinline__ f32x4 mfma16(bf16x8 a, bf16x8 b, f32x4 c) {
    return __builtin_amdgcn_mfma_f32_16x16x32_bf16(a, b, c, 0, 0, 0);
}

// ---------------- prep: weight fp32->bf16 (both) + mm init ----------------
__global__ __launch_bounds__(256) void prep(const float* __restrict__ qw,
                                            __bf16* __restrict__ wq,
                                            const float* __restrict__ pw,
                                            __bf16* __restrict__ wp,
                                            unsigned* __restrict__ mm) {
    int bid = blockIdx.x, tid = threadIdx.x;
    if (bid == 0 && tid < 3) { mm[2 * tid] = 0xFFFFFFFFu; mm[2 * tid + 1] = 0u; }
    if (bid < 768) {
        int i = bid * 256 + tid;
        float4 v = ((const float4*)qw)[i];
        bf16x4 o = {(__bf16)v.x, (__bf16)v.y, (__bf16)v.z, (__bf16)v.w};
        ((bf16x4*)wq)[i] = o;
    } else {
        int i = (bid - 768) * 256 + tid;
        float4 v = ((const float4*)pw)[i];
        bf16x4 o = {(__bf16)v.x, (__bf16)v.y, (__bf16)v.z, (__bf16)v.w};
        ((bf16x4*)wp)[i] = o;
    }
}

// ---------------- GroupNorm -> hT bf16 (B,T,C) ----------------
__global__ __launch_bounds__(256) void gn_kernel(const float* __restrict__ x,
                                                 const float* __restrict__ w,
                                                 const float* __restrict__ bv,
                                                 __bf16* __restrict__ hT) {
    int blk = blockIdx.x;
    int b = blk >> 5, g = blk & 31;
    const float* xp = x + (size_t)(b * 512 + g * 16) * 1024;
    int tid = threadIdx.x;

    float sum = 0.f, ss = 0.f;
#pragma unroll
    for (int i = 0; i < 16; ++i) {
        float4 v = *(const float4*)(xp + (size_t)i * 1024 + tid * 4);
        sum += v.x + v.y + v.z + v.w;
        ss  += v.x * v.x + v.y * v.y + v.z * v.z + v.w * v.w;
    }
#pragma unroll
    for (int m = 1; m < 64; m <<= 1) {
        sum += __shfl_xor(sum, m);
        ss  += __shfl_xor(ss, m);
    }
    __shared__ float s1[4], s2[4];
    int wid = tid >> 6;
    if ((tid & 63) == 0) { s1[wid] = sum; s2[wid] = ss; }
    __syncthreads();
    sum = s1[0] + s1[1] + s1[2] + s1[3];
    ss  = s2[0] + s2[1] + s2[2] + s2[3];
    float mean = sum * (1.0f / 16384.0f);
    float var  = ss * (1.0f / 16384.0f) - mean * mean;
    float rstd = rsqrtf(var + 1e-5f);

    int cl = ((tid >> 4) & 3) * 4;
    int tb = (tid & 15) + ((tid >> 6) << 4);
    float wc[4], bc[4];
#pragma unroll
    for (int j = 0; j < 4; ++j) { wc[j] = w[g * 16 + cl + j]; bc[j] = bv[g * 16 + cl + j]; }
    __bf16* hp = hT + (size_t)b * 1024 * 512 + g * 16 + cl;
#pragma unroll
    for (int r = 0; r < 16; ++r) {
        int t = tb + r * 64;
        float o0 = (xp[(size_t)(cl + 0) * 1024 + t] - mean) * rstd * wc[0] + bc[0];
        float o1 = (xp[(size_t)(cl + 1) * 1024 + t] - mean) * rstd * wc[1] + bc[1];
        float o2 = (xp[(size_t)(cl + 2) * 1024 + t] - mean) * rstd * wc[2] + bc[2];
        float o3 = (xp[(size_t)(cl + 3) * 1024 + t] - mean) * rstd * wc[3] + bc[3];
        bf16x4 ob = {(__bf16)o0, (__bf16)o1, (__bf16)o2, (__bf16)o3};
        *(bf16x4*)(hp + (size_t)t * 512) = ob;
    }
}

// ---------------- MFMA GEMM (both operands row-major, k-fastest) ----------------
template <bool MINMAX, bool RESID>
__global__ __launch_bounds__(256) void mgemm(const __bf16* __restrict__ A,   // [M][512]
                                             const __bf16* __restrict__ Bt,  // [8][1024][512]
                                             const float* __restrict__ bias,
                                             const float* __restrict__ resid,
                                             float* __restrict__ out,
                                             int M, unsigned* __restrict__ mm) {
    __shared__ __bf16 sA[128][72];
    __shared__ __bf16 sB[128][72];
    __shared__ float smn[4], smx[4];
    int tid = threadIdx.x;
    int l = tid & 63, w = tid >> 6;
    int lo = l & 15, hi = l >> 4;
    int mo = blockIdx.x, nt = blockIdx.y, b = blockIdx.z;
    const __bf16* Ap = A + (size_t)mo * 128 * 512;
    const __bf16* Bp = Bt + ((size_t)b * 1024 + (size_t)nt * 128) * 512;
    int m0 = (w >> 1) * 64, n0 = (w & 1) * 64;
    f32x4 acc[4][4] = {};

    for (int k0 = 0; k0 < 512; k0 += 64) {
        __syncthreads();
#pragma unroll
        for (int p = 0; p < 4; ++p) {
            int s = tid + p * 256;
            int row = s >> 3, ch = (s & 7) * 8;
            *(bf16x8*)&sA[row][ch] = *(const bf16x8*)(Ap + (size_t)row * 512 + k0 + ch);
            *(bf16x8*)&sB[row][ch] = *(const bf16x8*)(Bp + (size_t)row * 512 + k0 + ch);
        }
        __syncthreads();
#pragma unroll
        for (int kk = 0; kk < 2; ++kk) {
            int co = kk * 32 + hi * 8;
            bf16x8 af[4], bfr[4];
#pragma unroll
            for (int i = 0; i < 4; ++i) af[i]  = *(const bf16x8*)&sA[m0 + 16 * i + lo][co];
#pragma unroll
            for (int j = 0; j < 4; ++j) bfr[j] = *(const bf16x8*)&sB[n0 + 16 * j + lo][co];
#pragma unroll
            for (int i = 0; i < 4; ++i)
#pragma unroll
                for (int j = 0; j < 4; ++j) acc[i][j] = mfma16(af[i], bfr[j], acc[i][j]);
        }
    }

    float mn = 1e30f, mx = -1e30f;
    int gcol = nt * 128 + n0 + lo;
#pragma unroll
    for (int i = 0; i < 4; ++i) {
#pragma unroll
        for (int r = 0; r < 4; ++r) {
            int grow = mo * 128 + m0 + 16 * i + hi * 4 + r;
            float bi = bias[grow];
            size_t base = ((size_t)b * M + grow) * 1024 + gcol;
#pragma unroll
            for (int j = 0; j < 4; ++j) {
                float v = acc[i][j][r] + bi;
                if (MINMAX) { mn = fminf(mn, v); mx = fmaxf(mx, v); }
                if (RESID) v += resid[base + 16 * j];
                out[base + 16 * j] = v;
            }
        }
    }

    if (MINMAX) {
#pragma unroll
        for (int msk = 1; msk < 64; msk <<= 1) {
            mn = fminf(mn, __shfl_xor(mn, msk));
            mx = fmaxf(mx, __shfl_xor(mx, msk));
        }
        if (l == 0) { smn[w] = mn; smx[w] = mx; }
        __syncthreads();
        if (tid == 0) {
            mn = fminf(fminf(smn[0], smn[1]), fminf(smn[2], smn[3]));
            mx = fmaxf(fmaxf(smx[0], smx[1]), fmaxf(smx[2], smx[3]));
            int id = mo >> 2;
            atomicMin(&mm[2 * id], encf(mn));
            atomicMax(&mm[2 * id + 1], encf(mx));
        }
    }
}

// ---------------- quant K/V pass ----------------
// grid (64 bh, 16 tile); writes integer-valued bf16: ki (bh,s,c), vi (bh,c,s)
__global__ __launch_bounds__(256) void quant_kv(const float* __restrict__ qkv,
                                                const unsigned* __restrict__ mm,
                                                __bf16* __restrict__ ki,
                                                __bf16* __restrict__ vi) {
    int bh = blockIdx.x, tt = blockIdx.y;
    int b = bh >> 3, hh = bh & 7;
    int t0 = tt * 64;
    const float* kg = qkv + ((size_t)(b * 1536 + hh * 192) + 64) * 1024;
    const float* vg = kg + (size_t)64 * 1024;

    float mn1 = fminf(decf(mm[2]), 0.f), mx1 = fmaxf(decf(mm[3]), 0.f);
    float ksc = fmaxf((mx1 - mn1) * (1.f / 255.f), 1e-8f), kzp = rintf(-mn1 / ksc);
    float mn2 = fminf(decf(mm[4]), 0.f), mx2 = fmaxf(decf(mm[5]), 0.f);
    float vsc = fmaxf((mx2 - mn2) * (1.f / 255.f), 1e-8f), vzp = rintf(-mn2 / vsc);
    float inv_k = 1.f / ksc, inv_v = 1.f / vsc;

    __shared__ __bf16 sT[64][68];
    int tid = threadIdx.x;

    // V stream (layout unchanged)
    __bf16* vd = vi + (size_t)bh * 64 * 1024;
#pragma unroll
    for (int r = 0; r < 4; ++r) {
        int c = 16 * r + (tid >> 4), t4 = tid & 15;
        float4 v = *(const float4*)(vg + (size_t)c * 1024 + t0 + t4 * 4);
        bf16x4 o = {(__bf16)dqi(v.x, inv_v, vzp), (__bf16)dqi(v.y, inv_v, vzp),
                    (__bf16)dqi(v.z, inv_v, vzp), (__bf16)dqi(v.w, inv_v, vzp)};
        *(bf16x4*)(vd + (size_t)c * 1024 + t0 + t4 * 4) = o;
    }

    // K transpose via LDS -> (s, c)
#pragma unroll
    for (int r = 0; r < 4; ++r) {
        int c = 16 * r + (tid >> 4), t4 = tid & 15;
        float4 v = *(const float4*)(kg + (size_t)c * 1024 + t0 + t4 * 4);
        sT[t4 * 4 + 0][c] = (__bf16)dqi(v.x, inv_k, kzp);
        sT[t4 * 4 + 1][c] = (__bf16)dqi(v.y, inv_k, kzp);
        sT[t4 * 4 + 2][c] = (__bf16)dqi(v.z, inv_k, kzp);
        sT[t4 * 4 + 3][c] = (__bf16)dqi(v.w, inv_k, kzp);
    }
    __syncthreads();
    int s = tid >> 2, c0 = (tid & 3) * 16;
    bf16x8 a0 = *(const bf16x8*)&sT[s][c0];
    bf16x8 a1 = *(const bf16x8*)&sT[s][c0 + 8];
    __bf16* kd = ki + ((size_t)bh * 1024 + t0 + s) * 64 + c0;
    *(bf16x8*)kd = a0;
    *(bf16x8*)(kd + 8) = a1;
}

// ---------------- attention v3: LDS-staged bf16 K/V (XOR-swizzled), prefetch ----------------
__global__ __launch_bounds__(256) void attn3(const float* __restrict__ qkv,
                                             const __bf16* __restrict__ ki,
                                             const __bf16* __restrict__ vi,
                                             const unsigned* __restrict__ mm,
                                             __bf16* __restrict__ aT) {
    int f = blockIdx.x;
    int bh = (f & 7) * 8 + ((f >> 3) & 7);  // 8 heads x 16 t-tiles per XCD
    int tt = f >> 6;
    int b = bh >> 3, hh = bh & 7;
    int t0 = tt * 64;
    const float* qg = qkv + (size_t)(b * 1536 + hh * 192) * 1024;
    const __bf16* kb = ki + (size_t)bh * 1024 * 64;
    const __bf16* vb = vi + (size_t)bh * 64 * 1024;

    float mn0 = fminf(decf(mm[0]), 0.f), mx0 = fmaxf(decf(mm[1]), 0.f);
    float qsc = fmaxf((mx0 - mn0) * (1.f / 255.f), 1e-8f), qzp = rintf(-mn0 / qsc);
    float mn1 = fminf(decf(mm[2]), 0.f), mx1 = fmaxf(decf(mm[3]), 0.f);
    float ksc = fmaxf((mx1 - mn1) * (1.f / 255.f), 1e-8f);
    float mn2 = fminf(decf(mm[4]), 0.f), mx2 = fmaxf(decf(mm[5]), 0.f);
    float vsc = fmaxf((mx2 - mn2) * (1.f / 255.f), 1e-8f);
    float inv_q = 1.f / qsc;
    float alpha = qsc * ksc * 0.125f;

    __shared__ __bf16 sh[64][72];    // q stage -> per-wave P -> output stage
    __shared__ __bf16 kS[64 * 64];   // K tile (s,c), chunk-swizzled
    __shared__ __bf16 vS[64 * 64];   // V tile (c,s), chunk-swizzled
    int tid = threadIdx.x;
    int l = tid & 63, w = tid >> 6;
    int lo = l & 15, hi = l >> 4;

    // stage q tile transposed (integer-valued bf16)
    {
        int c0 = (tid >> 4) * 4, tl = tid & 15;
#pragma unroll
        for (int r = 0; r < 4; ++r) {
            int t = tl + 16 * r;
            float y0 = dqi(qg[(size_t)(c0 + 0) * 1024 + t0 + t], inv_q, qzp);
            float y1 = dqi(qg[(size_t)(c0 + 1) * 1024 + t0 + t], inv_q, qzp);
            float y2 = dqi(qg[(size_t)(c0 + 2) * 1024 + t0 + t], inv_q, qzp);
            float y3 = dqi(qg[(size_t)(c0 + 3) * 1024 + t0 + t], inv_q, qzp);
            bf16x4 o = {(__bf16)y0, (__bf16)y1, (__bf16)y2, (__bf16)y3};
            *(bf16x4*)&sh[t][c0] = o;
        }
    }
    __syncthreads();
    bf16x8 qf0 = *(const bf16x8*)&sh[16 * w + lo][hi * 8];
    bf16x8 qf1 = *(const bf16x8*)&sh[16 * w + lo][32 + hi * 8];
    // wave w's P region (rows 16w..16w+15) is wave-private; no barrier needed before P writes

    // staging geometry: thread -> row (0..63), two 16B chunks
    int srow = tid >> 2, sc2 = (tid & 3) * 2;
    int swz0 = (sc2 ^ (srow & 7)) << 3;        // swizzled elem offset of chunk sc2
    int swz1 = ((sc2 + 1) ^ (srow & 7)) << 3;
    const __bf16* kROW = kb + (size_t)srow * 64;          // + st*4096
    const __bf16* vROW = vb + (size_t)srow * 1024;        // + st*64
    // frag-read swizzled chunk offsets (row&7 == lo&7 for rows 16*sm+lo)
    int lx = lo & 7;
    int rc0 = (hi ^ lx) << 3;          // kk=0 chunk
    int rc1 = ((4 + hi) ^ lx) << 3;    // kk=1 chunk

    // prefetch tile 0
    bf16x8 kr0 = *(const bf16x8*)(kROW + sc2 * 8);
    bf16x8 kr1 = *(const bf16x8*)(kROW + sc2 * 8 + 8);
    bf16x8 vr0 = *(const bf16x8*)(vROW + sc2 * 8);
    bf16x8 vr1 = *(const bf16x8*)(vROW + sc2 * 8 + 8);

    f32x4 acc0 = {}, acc1 = {}, acc2 = {}, acc3 = {};
    float m_run = -1e30f, l_run = 0.f;

    for (int st = 0; st < 16; ++st) {
        __syncthreads();   // previous tile's LDS reads done
        *(bf16x8*)(kS + srow * 64 + swz0) = kr0;
        *(bf16x8*)(kS + srow * 64 + swz1) = kr1;
        *(bf16x8*)(vS + srow * 64 + swz0) = vr0;
        *(bf16x8*)(vS + srow * 64 + swz1) = vr1;
        __syncthreads();   // tile staged
        if (st < 15) {     // prefetch next tile during compute
            kr0 = *(const bf16x8*)(kROW + (st + 1) * 4096 + sc2 * 8);
            kr1 = *(const bf16x8*)(kROW + (st + 1) * 4096 + sc2 * 8 + 8);
            vr0 = *(const bf16x8*)(vROW + (st + 1) * 64 + sc2 * 8);
            vr1 = *(const bf16x8*)(vROW + (st + 1) * 64 + sc2 * 8 + 8);
        }

        // scores: D[s][t] = K·Q
        f32x4 sf[4] = {};
#pragma unroll
        for (int sm = 0; sm < 4; ++sm)
            sf[sm] = mfma16(*(const bf16x8*)(kS + (16 * sm + lo) * 64 + rc0), qf0, sf[sm]);
#pragma unroll
        for (int sm = 0; sm < 4; ++sm)
            sf[sm] = mfma16(*(const bf16x8*)(kS + (16 * sm + lo) * 64 + rc1), qf1, sf[sm]);

        // online softmax (t = lane-local)
        float tm = -1e30f;
#pragma unroll
        for (int sm = 0; sm < 4; ++sm)
#pragma unroll
            for (int r = 0; r < 4; ++r) { sf[sm][r] *= alpha; tm = fmaxf(tm, sf[sm][r]); }
        tm = fmaxf(tm, __shfl_xor(tm, 16));
        tm = fmaxf(tm, __shfl_xor(tm, 32));
        float mnew = fmaxf(m_run, tm);
        float ts = 0.f;
#pragma unroll
        for (int sm = 0; sm < 4; ++sm)
#pragma unroll
            for (int r = 0; r < 4; ++r) {
                float p = __expf(sf[sm][r] - mnew);
                sf[sm][r] = p;
                ts += p;
            }
        ts += __shfl_xor(ts, 16);
        ts += __shfl_xor(ts, 32);
        float fr = __expf(m_run - mnew);
        l_run = l_run * fr + ts;
        m_run = mnew;
        acc0 *= fr; acc1 *= fr; acc2 *= fr; acc3 *= fr;

        // P -> LDS (wave-private rows)
#pragma unroll
        for (int sm = 0; sm < 4; ++sm) {
            bf16x4 pb = {(__bf16)sf[sm][0], (__bf16)sf[sm][1], (__bf16)sf[sm][2], (__bf16)sf[sm][3]};
            *(bf16x4*)&sh[16 * w + lo][16 * sm + hi * 4] = pb;
        }
        bf16x8 pf0 = *(const bf16x8*)&sh[16 * w + lo][hi * 8];
        bf16x8 pf1 = *(const bf16x8*)&sh[16 * w + lo][32 + hi * 8];

        // PV: D[c][t] += V·P
        acc0 = mfma16(*(const bf16x8*)(vS + (lo) * 64 + rc0), pf0, acc0);
        acc1 = mfma16(*(const bf16x8*)(vS + (16 + lo) * 64 + rc0), pf0, acc1);
        acc2 = mfma16(*(const bf16x8*)(vS + (32 + lo) * 64 + rc0), pf0, acc2);
        acc3 = mfma16(*(const bf16x8*)(vS + (48 + lo) * 64 + rc0), pf0, acc3);
        acc0 = mfma16(*(const bf16x8*)(vS + (lo) * 64 + rc1), pf1, acc0);
        acc1 = mfma16(*(const bf16x8*)(vS + (16 + lo) * 64 + rc1), pf1, acc1);
        acc2 = mfma16(*(const bf16x8*)(vS + (32 + lo) * 64 + rc1), pf1, acc2);
        acc3 = mfma16(*(const bf16x8*)(vS + (48 + lo) * 64 + rc1), pf1, acc3);
    }

    float rl = vsc / l_run;
    __syncthreads();
    {
        bf16x4 o0 = {(__bf16)(acc0[0] * rl), (__bf16)(acc0[1] * rl), (__bf16)(acc0[2] * rl), (__bf16)(acc0[3] * rl)};
        bf16x4 o1 = {(__bf16)(acc1[0] * rl), (__bf16)(acc1[1] * rl), (__bf16)(acc1[2] * rl), (__bf16)(acc1[3] * rl)};
        bf16x4 o2 = {(__bf16)(acc2[0] * rl), (__bf16)(acc2[1] * rl), (__bf16)(acc2[2] * rl), (__bf16)(acc2[3] * rl)};
        bf16x4 o3 = {(__bf16)(acc3[0] * rl), (__bf16)(acc3[1] * rl), (__bf16)(acc3[2] * rl), (__bf16)(acc3[3] * rl)};
        *(bf16x4*)&sh[16 * w + lo][0  + hi * 4] = o0;
        *(bf16x4*)&sh[16 * w + lo][16 + hi * 4] = o1;
        *(bf16x4*)&sh[16 * w + lo][32 + hi * 4] = o2;
        *(bf16x4*)&sh[16 * w + lo][48 + hi * 4] = o3;
    }
    __syncthreads();
    __bf16* ap = aT + ((size_t)b * 1024 + t0 + (tid >> 2)) * 512 + hh * 64;
    bf16x8 v0 = *(const bf16x8*)&sh[tid >> 2][(tid & 3) * 8];
    bf16x8 v1 = *(const bf16x8*)&sh[tid >> 2][32 + (tid & 3) * 8];
    *(bf16x8*)(ap + (tid & 3) * 8) = v0;
    *(bf16x8*)(ap + 32 + (tid & 3) * 8) = v1;
}

// ---------------- fallback attention (round-2, used if ws too small) ----------------
__global__ __launch_bounds__(256) void attn_mfma(const float* __restrict__ qkv,
                                                 const unsigned* __restrict__ mm,
                                                 __bf16* __restrict__ aT) {
    int f = blockIdx.x;
    int bh = (f & 7) * 8 + ((f >> 3) & 7);
    int tt = f >> 6;
    int b = bh >> 3, hh = bh & 7;
    int t0 = tt * 64;
    const float* qg = qkv + (size_t)(b * 1536 + hh * 192) * 1024;
    const float* kg = qg + (size_t)64 * 1024;
    const float* vg = qg + (size_t)128 * 1024;

    float mn0 = fminf(decf(mm[0]), 0.f), mx0 = fmaxf(decf(mm[1]), 0.f);
    float qsc = fmaxf((mx0 - mn0) * (1.f / 255.f), 1e-8f), qzp = rintf(-mn0 / qsc);
    float mn1 = fminf(decf(mm[2]), 0.f), mx1 = fmaxf(decf(mm[3]), 0.f);
    float ksc = fmaxf((mx1 - mn1) * (1.f / 255.f), 1e-8f), kzp = rintf(-mn1 / ksc);
    float mn2 = fminf(decf(mm[4]), 0.f), mx2 = fmaxf(decf(mm[5]), 0.f);
    float vsc = fmaxf((mx2 - mn2) * (1.f / 255.f), 1e-8f), vzp = rintf(-mn2 / vsc);
    float inv_q = 1.f / qsc, inv_k = 1.f / ksc, inv_v = 1.f / vsc;
    float alpha = qsc * ksc * 0.125f;

    __shared__ __bf16 qT[64][72];
    __shared__ __bf16 kT[64][72];
    __shared__ __bf16 vL[64][72];
    __shared__ __bf16 pL[4][16][72];

    int tid = threadIdx.x;
    int l = tid & 63, w = tid >> 6;
    int lo = l & 15, hi = l >> 4;
    int c0 = (tid >> 4) * 4;
    int tl = tid & 15;

#pragma unroll
    for (int r = 0; r < 4; ++r) {
        int t = tl + 16 * r;
        float y0 = dqi(qg[(size_t)(c0 + 0) * 1024 + t0 + t], inv_q, qzp);
        float y1 = dqi(qg[(size_t)(c0 + 1) * 1024 + t0 + t], inv_q, qzp);
        float y2 = dqi(qg[(size_t)(c0 + 2) * 1024 + t0 + t], inv_q, qzp);
        float y3 = dqi(qg[(size_t)(c0 + 3) * 1024 + t0 + t], inv_q, qzp);
        bf16x4 o = {(__bf16)y0, (__bf16)y1, (__bf16)y2, (__bf16)y3};
        *(bf16x4*)&qT[t][c0] = o;
    }
    __syncthreads();
    bf16x8 qf0 = *(const bf16x8*)&qT[16 * w + lo][hi * 8];
    bf16x8 qf1 = *(const bf16x8*)&qT[16 * w + lo][32 + hi * 8];

    f32x4 acc0 = {}, acc1 = {}, acc2 = {}, acc3 = {};
    float m_run = -1e30f, l_run = 0.f;

    for (int st = 0; st < 16; ++st) {
        int s0 = st * 64;
        __syncthreads();
#pragma unroll
        for (int r = 0; r < 4; ++r) {
            int srow = tl + 16 * r;
            float y0 = dqi(kg[(size_t)(c0 + 0) * 1024 + s0 + srow], inv_k, kzp);
            float y1 = dqi(kg[(size_t)(c0 + 1) * 1024 + s0 + srow], inv_k, kzp);
            float y2 = dqi(kg[(size_t)(c0 + 2) * 1024 + s0 + srow], inv_k, kzp);
            float y3 = dqi(kg[(size_t)(c0 + 3) * 1024 + s0 + srow], inv_k, kzp);
            bf16x4 ok = {(__bf16)y0, (__bf16)y1, (__bf16)y2, (__bf16)y3};
            *(bf16x4*)&kT[srow][c0] = ok;
            int c = (tid >> 4) + 16 * r;
            float4 vv = *(const float4*)(vg + (size_t)c * 1024 + s0 + (tid & 15) * 4);
            bf16x4 ov = {(__bf16)dqi(vv.x, inv_v, vzp), (__bf16)dqi(vv.y, inv_v, vzp),
                         (__bf16)dqi(vv.z, inv_v, vzp), (__bf16)dqi(vv.w, inv_v, vzp)};
            *(bf16x4*)&vL[c][(tid & 15) * 4] = ov;
        }
        __syncthreads();

        f32x4 sf[4] = {};
#pragma unroll
        for (int sm = 0; sm < 4; ++sm)
            sf[sm] = mfma16(*(const bf16x8*)&kT[16 * sm + lo][hi * 8], qf0, sf[sm]);
#pragma unroll
        for (int sm = 0; sm < 4; ++sm)
            sf[sm] = mfma16(*(const bf16x8*)&kT[16 * sm + lo][32 + hi * 8], qf1, sf[sm]);

        float tm = -1e30f;
#pragma unroll
        for (int sm = 0; sm < 4; ++sm)
#pragma unroll
            for (int r = 0; r < 4; ++r) { sf[sm][r] *= alpha; tm = fmaxf(tm, sf[sm][r]); }
        tm = fmaxf(tm, __shfl_xor(tm, 16));
        tm = fmaxf(tm, __shfl_xor(tm, 32));
        float mnew = fmaxf(m_run, tm);
        float ts = 0.f;
#pragma unroll
        for (int sm = 0; sm < 4; ++sm)
#pragma unroll
            for (int r = 0; r < 4; ++r) {
                float p = __expf(sf[sm][r] - mnew);
                sf[sm][r] = p;
                ts += p;
            }
        ts += __shfl_xor(ts, 16);
        ts += __shfl_xor(ts, 32);
        float fr = __expf(m_run - mnew);
        l_run = l_run * fr + ts;
        m_run = mnew;
        acc0 *= fr; acc1 *= fr; acc2 *= fr; acc3 *= fr;

#pragma unroll
        for (int sm = 0; sm < 4; ++sm) {
            bf16x4 pb = {(__bf16)sf[sm][0], (__bf16)sf[sm][1], (__bf16)sf[sm][2], (__bf16)sf[sm][3]};
            *(bf16x4*)&pL[w][lo][16 * sm + hi * 4] = pb;
        }
        bf16x8 pf0 = *(const bf16x8*)&pL[w][lo][hi * 8];
        bf16x8 pf1 = *(const bf16x8*)&pL[w][lo][32 + hi * 8];
        acc0 = mfma16(*(const bf16x8*)&vL[lo][hi * 8], pf0, acc0);
        acc1 = mfma16(*(const bf16x8*)&vL[16 + lo][hi * 8], pf0, acc1);
        acc2 = mfma16(*(const bf16x8*)&vL[32 + lo][hi * 8], pf0, acc2);
        acc3 = mfma16(*(const bf16x8*)&vL[48 + lo][hi * 8], pf0, acc3);
        acc0 = mfma16(*(const bf16x8*)&vL[lo][32 + hi * 8], pf1, acc0);
        acc1 = mfma16(*(const bf16x8*)&vL[16 + lo][32 + hi * 8], pf1, acc1);
        acc2 = mfma16(*(const bf16x8*)&vL[32 + lo][32 + hi * 8], pf1, acc2);
        acc3 = mfma16(*(const bf16x8*)&vL[48 + lo][32 + hi * 8], pf1, acc3);
    }

    float rl = vsc / l_run;
    __syncthreads();
    {
        bf16x4 o0 = {(__bf16)(acc0[0] * rl), (__bf16)(acc0[1] * rl), (__bf16)(acc0[2] * rl), (__bf16)(acc0[3] * rl)};
        bf16x4 o1 = {(__bf16)(acc1[0] * rl), (__bf16)(acc1[1] * rl), (__bf16)(acc1[2] * rl), (__bf16)(acc1[3] * rl)};
        bf16x4 o2 = {(__bf16)(acc2[0] * rl), (__bf16)(acc2[1] * rl), (__bf16)(acc2[2] * rl), (__bf16)(acc2[3] * rl)};
        bf16x4 o3 = {(__bf16)(acc3[0] * rl), (__bf16)(acc3[1] * rl), (__bf16)(acc3[2] * rl), (__bf16)(acc3[3] * rl)};
        *(bf16x4*)&qT[16 * w + lo][0  + hi * 4] = o0;
        *(bf16x4*)&qT[16 * w + lo][16 + hi * 4] = o1;
        *(bf16x4*)&qT[16 * w + lo][32 + hi * 4] = o2;
        *(bf16x4*)&qT[16 * w + lo][48 + hi * 4] = o3;
    }
    __syncthreads();
    __bf16* ap = aT + ((size_t)b * 1024 + t0 + (tid >> 2)) * 512 + hh * 64;
    bf16x8 v0 = *(const bf16x8*)&qT[tid >> 2][(tid & 3) * 8];
    bf16x8 v1 = *(const bf16x8*)&qT[tid >> 2][32 + (tid & 3) * 8];
    *(bf16x8*)(ap + (tid & 3) * 8) = v0;
    *(bf16x8*)(ap + 32 + (tid & 3) * 8) = v1;
}

extern "C" void kernel_launch(void* const* d_in, const int* in_sizes, int n_in,
                              void* d_out, int out_size, void* d_ws, size_t ws_size,
                              hipStream_t stream) {
    const float* x      = (const float*)d_in[0];
    const float* gn_w   = (const float*)d_in[1];
    const float* gn_b   = (const float*)d_in[2];
    const float* qkv_w  = (const float*)d_in[3];
    const float* qkv_b  = (const float*)d_in[4];
    const float* proj_w = (const float*)d_in[5];
    const float* proj_b = (const float*)d_in[6];
    char* ws = (char*)d_ws;
    float*    qkv = (float*)(ws + QKV_OFF);
    __bf16*   hT  = (__bf16*)(ws + HT_OFF);   // hT, later reused as aT
    __bf16*   wq  = (__bf16*)(ws + WQ_OFF);
    __bf16*   wp  = (__bf16*)(ws + WP_OFF);
    unsigned* mm  = (unsigned*)(ws + MM_OFF);
    __bf16*   ki  = (__bf16*)(ws + KI_OFF);
    __bf16*   vi  = (__bf16*)(ws + VI_OFF);
    float* out = (float*)d_out;

    prep<<<1024, 256, 0, stream>>>(qkv_w, wq, proj_w, wp, mm);
    gn_kernel<<<256, 256, 0, stream>>>(x, gn_w, gn_b, hT);
    mgemm<true, false><<<dim3(12, 8, 8), 256, 0, stream>>>(wq, hT, qkv_b, nullptr, qkv, 1536, mm);
    if (ws_size >= NEED_NEW) {
        quant_kv<<<dim3(64, 16), 256, 0, stream>>>(qkv, mm, ki, vi);
        attn3<<<1024, 256, 0, stream>>>(qkv, ki, vi, mm, hT);
    } else {
        attn_mfma<<<1024, 256, 0, stream>>>(qkv, mm, hT);
    }
    mgemm<false, true><<<dim3(4, 8, 8), 256, 0, stream>>>(wp, hT, proj_b, x, out, 512, nullptr);
}

// Round 5
// 113.288 us; speedup vs baseline: 1.7312x; 1.0671x over previous
//
#include <hip/hip_runtime.h>

typedef __attribute__((ext_vector_type(8))) __bf16 bf16x8;
typedef __attribute__((ext_vector_type(4))) __bf16 bf16x4;
typedef __attribute__((ext_vector_type(4))) float  f32x4;

// Problem: x (8,512,32,32) fp32 -> B=8, C=512, T=1024; 32 groups; 8 heads (ch=64)

// ws layout (bytes)
static constexpr size_t QKV_OFF = 0;                     // fp32 (8,1536,1024) 48MB
static constexpr size_t HT_OFF  = 50331648;              // bf16 (8,1024,512) 8MB: hT then aT
static constexpr size_t WQ_OFF  = HT_OFF + 8388608;      // bf16 (1536,512)
static constexpr size_t WP_OFF  = WQ_OFF + 1572864;      // bf16 (512,512)
static constexpr size_t MM_OFF  = WP_OFF + 524288;       // 6 x u32
static constexpr size_t KI_OFF  = MM_OFF + 4096;         // bf16 (64,1024,64) 8MB
static constexpr size_t VI_OFF  = KI_OFF + 8388608;      // bf16 (64,64,1024) 8MB
static constexpr size_t NEED_NEW = VI_OFF + 8388608;

__device__ __forceinline__ unsigned encf(float f) {
    unsigned u = __float_as_uint(f);
    return (u & 0x80000000u) ? ~u : (u | 0x80000000u);
}
__device__ __forceinline__ float decf(unsigned e) {
    unsigned u = (e & 0x80000000u) ? (e & 0x7fffffffu) : ~e;
    return __uint_as_float(u);
}
// integer-valued dequant core: clip(rint(x/s)+zp,0,255)-zp == clip(rint(x/s), -zp, 255-zp)
__device__ __forceinline__ float dqi(float x, float inv_s, float zp) {
    float y = rintf(x * inv_s);
    return fminf(fmaxf(y, -zp), 255.0f - zp);
}
__device__ __forceinline__ f32x4 mfma16(bf16x8 a, bf16x8 b, f32x4 c) {
    return __builtin_amdgcn_mfma_f32_16x16x32_bf16(a, b, c, 0, 0, 0);
}
__device__ __forceinline__ float exp2i(float x) {  // raw v_exp_f32 (2^x)
    float r;
    asm("v_exp_f32 %0, %1" : "=v"(r) : "v"(x));
    return r;
}
__device__ __forceinline__ void glds16(const __bf16* g, __bf16* l) {
    __builtin_amdgcn_global_load_lds((const __attribute__((address_space(1))) void*)g,
                                     (__attribute__((address_space(3))) void*)l, 16, 0, 0);
}

// ---------------- prep: weight fp32->bf16 (both) + mm init ----------------
__global__ __launch_bounds__(256) void prep(const float* __restrict__ qw,
                                            __bf16* __restrict__ wq,
                                            const float* __restrict__ pw,
                                            __bf16* __restrict__ wp,
                                            unsigned* __restrict__ mm) {
    int bid = blockIdx.x, tid = threadIdx.x;
    if (bid == 0 && tid < 3) { mm[2 * tid] = 0xFFFFFFFFu; mm[2 * tid + 1] = 0u; }
    if (bid < 768) {
        int i = bid * 256 + tid;
        float4 v = ((const float4*)qw)[i];
        bf16x4 o = {(__bf16)v.x, (__bf16)v.y, (__bf16)v.z, (__bf16)v.w};
        ((bf16x4*)wq)[i] = o;
    } else {
        int i = (bid - 768) * 256 + tid;
        float4 v = ((const float4*)pw)[i];
        bf16x4 o = {(__bf16)v.x, (__bf16)v.y, (__bf16)v.z, (__bf16)v.w};
        ((bf16x4*)wp)[i] = o;
    }
}

// ---------------- GroupNorm -> hT bf16 (B,T,C) ----------------
// x kept in registers between the two passes; transposed 16B stores.
__global__ __launch_bounds__(256) void gn_kernel(const float* __restrict__ x,
                                                 const float* __restrict__ w,
                                                 const float* __restrict__ bv,
                                                 __bf16* __restrict__ hT) {
    int blk = blockIdx.x;
    int b = blk >> 5, g = blk & 31;
    const float* xp = x + (size_t)(b * 512 + g * 16) * 1024;
    int tid = threadIdx.x;

    float4 v[16];
    float sum = 0.f, ss = 0.f;
#pragma unroll
    for (int i = 0; i < 16; ++i) {
        v[i] = *(const float4*)(xp + (size_t)i * 1024 + tid * 4);
        sum += v[i].x + v[i].y + v[i].z + v[i].w;
        ss  += v[i].x * v[i].x + v[i].y * v[i].y + v[i].z * v[i].z + v[i].w * v[i].w;
    }
#pragma unroll
    for (int m = 1; m < 64; m <<= 1) {
        sum += __shfl_xor(sum, m);
        ss  += __shfl_xor(ss, m);
    }
    __shared__ float s1[4], s2[4];
    int wid = tid >> 6;
    if ((tid & 63) == 0) { s1[wid] = sum; s2[wid] = ss; }
    __syncthreads();
    sum = s1[0] + s1[1] + s1[2] + s1[3];
    ss  = s2[0] + s2[1] + s2[2] + s2[3];
    float mean = sum * (1.0f / 16384.0f);
    float var  = ss * (1.0f / 16384.0f) - mean * mean;
    float rstd = rsqrtf(var + 1e-5f);

    float wc[16], bc[16];
#pragma unroll
    for (int c = 0; c < 16; ++c) { wc[c] = w[g * 16 + c] * rstd; bc[c] = bv[g * 16 + c]; }

#pragma unroll
    for (int j = 0; j < 4; ++j) {
        int t = tid * 4 + j;
        bf16x8 o0, o1;
#pragma unroll
        for (int c = 0; c < 8; ++c)
            o0[c] = (__bf16)(((&v[c].x)[j] - mean) * wc[c] + bc[c]);
#pragma unroll
        for (int c = 0; c < 8; ++c)
            o1[c] = (__bf16)(((&v[c + 8].x)[j] - mean) * wc[c + 8] + bc[c + 8]);
        __bf16* hp = hT + ((size_t)b * 1024 + t) * 512 + g * 16;
        *(bf16x8*)hp = o0;
        *(bf16x8*)(hp + 8) = o1;
    }
}

// ---------------- MFMA GEMM, m97 structure (global_load_lds + XOR swizzle) ----------------
// out[b][m][n] = sum_c A[m][c] * Bt[b][n][c] + bias[m] (+resid)(+minmax)
template <int MTILE, bool MINMAX, bool RESID>
__global__ __launch_bounds__(256) void mgemm2(const __bf16* __restrict__ A,   // [M][512]
                                              const __bf16* __restrict__ Bt,  // [8][1024][512]
                                              const float* __restrict__ bias,
                                              const float* __restrict__ resid,
                                              float* __restrict__ out,
                                              int M, unsigned* __restrict__ mm) {
    constexpr int NF = (MTILE == 128) ? 4 : 2;
    __shared__ __bf16 sA[MTILE * 64];
    __shared__ __bf16 sB[128 * 64];
    __shared__ float smn[4], smx[4];
    int tid = threadIdx.x;
    int l = tid & 63, w = tid >> 6;
    int lo = l & 15, hi = l >> 4;
    int mo = blockIdx.x, nt = blockIdx.y, b = blockIdx.z;
    const __bf16* Ap = A + (size_t)mo * MTILE * 512;
    const __bf16* Bp = Bt + ((size_t)b * 1024 + (size_t)nt * 128) * 512;
    int m0 = (MTILE == 128) ? (w >> 1) * 64 : 0;
    int n0 = (MTILE == 128) ? (w & 1) * 64 : w * 32;
    f32x4 acc[4][NF] = {};

    // staging geometry (shared by A and B): lane writes LDS lin = p*2048 + tid*8,
    // i.e. (row = lin>>6, chunk = tid&7); source chunk pre-swizzled so that
    // LDS[row][cd] = G[row][cd ^ (row&7)].
    int scd = tid & 7;

    for (int k0 = 0; k0 < 512; k0 += 64) {
        __syncthreads();
#pragma unroll
        for (int p = 0; p < MTILE / 32; ++p) {
            int lin = p * 2048 + tid * 8;
            int row = lin >> 6;
            glds16(Ap + (size_t)row * 512 + k0 + ((scd ^ (row & 7)) << 3), &sA[lin]);
        }
#pragma unroll
        for (int p = 0; p < 4; ++p) {
            int lin = p * 2048 + tid * 8;
            int row = lin >> 6;
            glds16(Bp + (size_t)row * 512 + k0 + ((scd ^ (row & 7)) << 3), &sB[lin]);
        }
        __syncthreads();  // compiler drains vmcnt before barrier
#pragma unroll
        for (int kk = 0; kk < 2; ++kk) {
            int rch = ((kk * 4 + hi) ^ (lo & 7)) << 3;  // swizzled chunk (row&7 == lo&7)
            bf16x8 af[4], bfr[NF];
#pragma unroll
            for (int i = 0; i < 4; ++i)
                af[i] = *(const bf16x8*)&sA[(m0 + 16 * i + lo) * 64 + rch];
#pragma unroll
            for (int j = 0; j < NF; ++j)
                bfr[j] = *(const bf16x8*)&sB[(n0 + 16 * j + lo) * 64 + rch];
#pragma unroll
            for (int i = 0; i < 4; ++i)
#pragma unroll
                for (int j = 0; j < NF; ++j) acc[i][j] = mfma16(af[i], bfr[j], acc[i][j]);
        }
    }

    float mn = 1e30f, mx = -1e30f;
    int gcol = nt * 128 + n0 + lo;
#pragma unroll
    for (int i = 0; i < 4; ++i) {
#pragma unroll
        for (int r = 0; r < 4; ++r) {
            int grow = mo * MTILE + m0 + 16 * i + hi * 4 + r;
            float bi = bias[grow];
            size_t base = ((size_t)b * M + grow) * 1024 + gcol;
#pragma unroll
            for (int j = 0; j < NF; ++j) {
                float v = acc[i][j][r] + bi;
                if (MINMAX) { mn = fminf(mn, v); mx = fmaxf(mx, v); }
                if (RESID) v += resid[base + 16 * j];
                out[base + 16 * j] = v;
            }
        }
    }

    if (MINMAX) {
#pragma unroll
        for (int msk = 1; msk < 64; msk <<= 1) {
            mn = fminf(mn, __shfl_xor(mn, msk));
            mx = fmaxf(mx, __shfl_xor(mx, msk));
        }
        if (l == 0) { smn[w] = mn; smx[w] = mx; }
        __syncthreads();
        if (tid == 0) {
            mn = fminf(fminf(smn[0], smn[1]), fminf(smn[2], smn[3]));
            mx = fmaxf(fmaxf(smx[0], smx[1]), fmaxf(smx[2], smx[3]));
            int id = mo >> 2;  // 4 x 128-row tiles per tensor (q,k,v)
            atomicMin(&mm[2 * id], encf(mn));
            atomicMax(&mm[2 * id + 1], encf(mx));
        }
    }
}

// ---------------- quant K/V pass ----------------
// grid (64 bh, 16 tile); writes integer-valued bf16: ki (bh,s,c), vi (bh,c,s)
__global__ __launch_bounds__(256) void quant_kv(const float* __restrict__ qkv,
                                                const unsigned* __restrict__ mm,
                                                __bf16* __restrict__ ki,
                                                __bf16* __restrict__ vi) {
    int bh = blockIdx.x, tt = blockIdx.y;
    int b = bh >> 3, hh = bh & 7;
    int t0 = tt * 64;
    const float* kg = qkv + ((size_t)(b * 1536 + hh * 192) + 64) * 1024;
    const float* vg = kg + (size_t)64 * 1024;

    float mn1 = fminf(decf(mm[2]), 0.f), mx1 = fmaxf(decf(mm[3]), 0.f);
    float ksc = fmaxf((mx1 - mn1) * (1.f / 255.f), 1e-8f), kzp = rintf(-mn1 / ksc);
    float mn2 = fminf(decf(mm[4]), 0.f), mx2 = fmaxf(decf(mm[5]), 0.f);
    float vsc = fmaxf((mx2 - mn2) * (1.f / 255.f), 1e-8f), vzp = rintf(-mn2 / vsc);
    float inv_k = 1.f / ksc, inv_v = 1.f / vsc;

    __shared__ __bf16 sT[64][68];
    int tid = threadIdx.x;

    // V stream (layout unchanged)
    __bf16* vd = vi + (size_t)bh * 64 * 1024;
#pragma unroll
    for (int r = 0; r < 4; ++r) {
        int c = 16 * r + (tid >> 4), t4 = tid & 15;
        float4 v = *(const float4*)(vg + (size_t)c * 1024 + t0 + t4 * 4);
        bf16x4 o = {(__bf16)dqi(v.x, inv_v, vzp), (__bf16)dqi(v.y, inv_v, vzp),
                    (__bf16)dqi(v.z, inv_v, vzp), (__bf16)dqi(v.w, inv_v, vzp)};
        *(bf16x4*)(vd + (size_t)c * 1024 + t0 + t4 * 4) = o;
    }

    // K transpose via LDS -> (s, c)
#pragma unroll
    for (int r = 0; r < 4; ++r) {
        int c = 16 * r + (tid >> 4), t4 = tid & 15;
        float4 v = *(const float4*)(kg + (size_t)c * 1024 + t0 + t4 * 4);
        sT[t4 * 4 + 0][c] = (__bf16)dqi(v.x, inv_k, kzp);
        sT[t4 * 4 + 1][c] = (__bf16)dqi(v.y, inv_k, kzp);
        sT[t4 * 4 + 2][c] = (__bf16)dqi(v.z, inv_k, kzp);
        sT[t4 * 4 + 3][c] = (__bf16)dqi(v.w, inv_k, kzp);
    }
    __syncthreads();
    int s = tid >> 2, c0 = (tid & 3) * 16;
    bf16x8 a0 = *(const bf16x8*)&sT[s][c0];
    bf16x8 a1 = *(const bf16x8*)&sT[s][c0 + 8];
    __bf16* kd = ki + ((size_t)bh * 1024 + t0 + s) * 64 + c0;
    *(bf16x8*)kd = a0;
    *(bf16x8*)(kd + 8) = a1;
}

// ---------------- attention v4: LDS-staged K/V + exp2 softmax + defer-max ----------------
__global__ __launch_bounds__(256) void attn3(const float* __restrict__ qkv,
                                             const __bf16* __restrict__ ki,
                                             const __bf16* __restrict__ vi,
                                             const unsigned* __restrict__ mm,
                                             __bf16* __restrict__ aT) {
    int f = blockIdx.x;
    int bh = (f & 7) * 8 + ((f >> 3) & 7);  // 8 heads x 16 t-tiles per XCD
    int tt = f >> 6;
    int b = bh >> 3, hh = bh & 7;
    int t0 = tt * 64;
    const float* qg = qkv + (size_t)(b * 1536 + hh * 192) * 1024;
    const __bf16* kb = ki + (size_t)bh * 1024 * 64;
    const __bf16* vb = vi + (size_t)bh * 64 * 1024;

    float mn0 = fminf(decf(mm[0]), 0.f), mx0 = fmaxf(decf(mm[1]), 0.f);
    float qsc = fmaxf((mx0 - mn0) * (1.f / 255.f), 1e-8f), qzp = rintf(-mn0 / qsc);
    float mn1 = fminf(decf(mm[2]), 0.f), mx1 = fmaxf(decf(mm[3]), 0.f);
    float ksc = fmaxf((mx1 - mn1) * (1.f / 255.f), 1e-8f);
    float mn2 = fminf(decf(mm[4]), 0.f), mx2 = fmaxf(decf(mm[5]), 0.f);
    float vsc = fmaxf((mx2 - mn2) * (1.f / 255.f), 1e-8f);
    float inv_q = 1.f / qsc;
    float alpha2 = qsc * ksc * 0.125f * 1.4426950408889634f;  // alpha * log2(e)
    float thr = 11.5415603f / alpha2;                          // 8 nats in raw-score units

    __shared__ __bf16 sh[64][72];    // q stage -> per-wave P -> output stage
    __shared__ __bf16 kS[64 * 64];   // K tile (s,c), chunk-swizzled
    __shared__ __bf16 vS[64 * 64];   // V tile (c,s), chunk-swizzled
    int tid = threadIdx.x;
    int l = tid & 63, w = tid >> 6;
    int lo = l & 15, hi = l >> 4;

    // stage q tile transposed (integer-valued bf16)
    {
        int c0 = (tid >> 4) * 4, tl = tid & 15;
#pragma unroll
        for (int r = 0; r < 4; ++r) {
            int t = tl + 16 * r;
            float y0 = dqi(qg[(size_t)(c0 + 0) * 1024 + t0 + t], inv_q, qzp);
            float y1 = dqi(qg[(size_t)(c0 + 1) * 1024 + t0 + t], inv_q, qzp);
            float y2 = dqi(qg[(size_t)(c0 + 2) * 1024 + t0 + t], inv_q, qzp);
            float y3 = dqi(qg[(size_t)(c0 + 3) * 1024 + t0 + t], inv_q, qzp);
            bf16x4 o = {(__bf16)y0, (__bf16)y1, (__bf16)y2, (__bf16)y3};
            *(bf16x4*)&sh[t][c0] = o;
        }
    }
    __syncthreads();
    bf16x8 qf0 = *(const bf16x8*)&sh[16 * w + lo][hi * 8];
    bf16x8 qf1 = *(const bf16x8*)&sh[16 * w + lo][32 + hi * 8];
    // wave w's P region (rows 16w..16w+15) is wave-private; no barrier needed before P writes

    // staging geometry: thread -> row (0..63), two 16B chunks
    int srow = tid >> 2, sc2 = (tid & 3) * 2;
    int swz0 = (sc2 ^ (srow & 7)) << 3;
    int swz1 = ((sc2 + 1) ^ (srow & 7)) << 3;
    const __bf16* kROW = kb + (size_t)srow * 64;          // + st*4096
    const __bf16* vROW = vb + (size_t)srow * 1024;        // + st*64
    int lx = lo & 7;
    int rc0 = (hi ^ lx) << 3;          // kk=0 chunk
    int rc1 = ((4 + hi) ^ lx) << 3;    // kk=1 chunk

    // prefetch tile 0
    bf16x8 kr0 = *(const bf16x8*)(kROW + sc2 * 8);
    bf16x8 kr1 = *(const bf16x8*)(kROW + sc2 * 8 + 8);
    bf16x8 vr0 = *(const bf16x8*)(vROW + sc2 * 8);
    bf16x8 vr1 = *(const bf16x8*)(vROW + sc2 * 8 + 8);

    f32x4 acc0 = {}, acc1 = {}, acc2 = {}, acc3 = {};
    float m_run = -1e30f, l_run = 0.f;

    for (int st = 0; st < 16; ++st) {
        __syncthreads();   // previous tile's LDS reads done
        *(bf16x8*)(kS + srow * 64 + swz0) = kr0;
        *(bf16x8*)(kS + srow * 64 + swz1) = kr1;
        *(bf16x8*)(vS + srow * 64 + swz0) = vr0;
        *(bf16x8*)(vS + srow * 64 + swz1) = vr1;
        __syncthreads();   // tile staged
        if (st < 15) {     // prefetch next tile during compute
            kr0 = *(const bf16x8*)(kROW + (st + 1) * 4096 + sc2 * 8);
            kr1 = *(const bf16x8*)(kROW + (st + 1) * 4096 + sc2 * 8 + 8);
            vr0 = *(const bf16x8*)(vROW + (st + 1) * 64 + sc2 * 8);
            vr1 = *(const bf16x8*)(vROW + (st + 1) * 64 + sc2 * 8 + 8);
        }

        // scores: D[s][t] = K·Q (raw integer dot products)
        f32x4 sf[4] = {};
        __builtin_amdgcn_s_setprio(1);
#pragma unroll
        for (int sm = 0; sm < 4; ++sm)
            sf[sm] = mfma16(*(const bf16x8*)(kS + (16 * sm + lo) * 64 + rc0), qf0, sf[sm]);
#pragma unroll
        for (int sm = 0; sm < 4; ++sm)
            sf[sm] = mfma16(*(const bf16x8*)(kS + (16 * sm + lo) * 64 + rc1), qf1, sf[sm]);
        __builtin_amdgcn_s_setprio(0);

        // online softmax in exp2 space (t = lane-local)
        float tm = -1e30f;
#pragma unroll
        for (int sm = 0; sm < 4; ++sm) {
            float a = fmaxf(sf[sm][0], sf[sm][1]);
            float c = fmaxf(sf[sm][2], sf[sm][3]);
            tm = fmaxf(tm, fmaxf(a, c));
        }
        tm = fmaxf(tm, __shfl_xor(tm, 16));
        tm = fmaxf(tm, __shfl_xor(tm, 32));
        if (!__all(tm <= m_run + thr)) {   // defer-max: skip rescale when growth small
            float mnew = fmaxf(m_run, tm);
            float fr = exp2i(alpha2 * (m_run - mnew));
            acc0 *= fr; acc1 *= fr; acc2 *= fr; acc3 *= fr;
            l_run *= fr;
            m_run = mnew;
        }
        float cc = -alpha2 * m_run;
        float ts = 0.f;
#pragma unroll
        for (int sm = 0; sm < 4; ++sm)
#pragma unroll
            for (int r = 0; r < 4; ++r) {
                float p = exp2i(fmaf(sf[sm][r], alpha2, cc));
                sf[sm][r] = p;
                ts += p;
            }
        ts += __shfl_xor(ts, 16);
        ts += __shfl_xor(ts, 32);
        l_run += ts;

        // P -> LDS (wave-private rows)
#pragma unroll
        for (int sm = 0; sm < 4; ++sm) {
            bf16x4 pb = {(__bf16)sf[sm][0], (__bf16)sf[sm][1], (__bf16)sf[sm][2], (__bf16)sf[sm][3]};
            *(bf16x4*)&sh[16 * w + lo][16 * sm + hi * 4] = pb;
        }
        bf16x8 pf0 = *(const bf16x8*)&sh[16 * w + lo][hi * 8];
        bf16x8 pf1 = *(const bf16x8*)&sh[16 * w + lo][32 + hi * 8];

        // PV: D[c][t] += V·P
        __builtin_amdgcn_s_setprio(1);
        acc0 = mfma16(*(const bf16x8*)(vS + (lo) * 64 + rc0), pf0, acc0);
        acc1 = mfma16(*(const bf16x8*)(vS + (16 + lo) * 64 + rc0), pf0, acc1);
        acc2 = mfma16(*(const bf16x8*)(vS + (32 + lo) * 64 + rc0), pf0, acc2);
        acc3 = mfma16(*(const bf16x8*)(vS + (48 + lo) * 64 + rc0), pf0, acc3);
        acc0 = mfma16(*(const bf16x8*)(vS + (lo) * 64 + rc1), pf1, acc0);
        acc1 = mfma16(*(const bf16x8*)(vS + (16 + lo) * 64 + rc1), pf1, acc1);
        acc2 = mfma16(*(const bf16x8*)(vS + (32 + lo) * 64 + rc1), pf1, acc2);
        acc3 = mfma16(*(const bf16x8*)(vS + (48 + lo) * 64 + rc1), pf1, acc3);
        __builtin_amdgcn_s_setprio(0);
    }

    float rl = vsc / l_run;
    __syncthreads();
    {
        bf16x4 o0 = {(__bf16)(acc0[0] * rl), (__bf16)(acc0[1] * rl), (__bf16)(acc0[2] * rl), (__bf16)(acc0[3] * rl)};
        bf16x4 o1 = {(__bf16)(acc1[0] * rl), (__bf16)(acc1[1] * rl), (__bf16)(acc1[2] * rl), (__bf16)(acc1[3] * rl)};
        bf16x4 o2 = {(__bf16)(acc2[0] * rl), (__bf16)(acc2[1] * rl), (__bf16)(acc2[2] * rl), (__bf16)(acc2[3] * rl)};
        bf16x4 o3 = {(__bf16)(acc3[0] * rl), (__bf16)(acc3[1] * rl), (__bf16)(acc3[2] * rl), (__bf16)(acc3[3] * rl)};
        *(bf16x4*)&sh[16 * w + lo][0  + hi * 4] = o0;
        *(bf16x4*)&sh[16 * w + lo][16 + hi * 4] = o1;
        *(bf16x4*)&sh[16 * w + lo][32 + hi * 4] = o2;
        *(bf16x4*)&sh[16 * w + lo][48 + hi * 4] = o3;
    }
    __syncthreads();
    __bf16* ap = aT + ((size_t)b * 1024 + t0 + (tid >> 2)) * 512 + hh * 64;
    bf16x8 v0 = *(const bf16x8*)&sh[tid >> 2][(tid & 3) * 8];
    bf16x8 v1 = *(const bf16x8*)&sh[tid >> 2][32 + (tid & 3) * 8];
    *(bf16x8*)(ap + (tid & 3) * 8) = v0;
    *(bf16x8*)(ap + 32 + (tid & 3) * 8) = v1;
}

// ---------------- fallback attention (round-2 style, used if ws too small) ----------------
__global__ __launch_bounds__(256) void attn_mfma(const float* __restrict__ qkv,
                                                 const unsigned* __restrict__ mm,
                                                 __bf16* __restrict__ aT) {
    int f = blockIdx.x;
    int bh = (f & 7) * 8 + ((f >> 3) & 7);
    int tt = f >> 6;
    int b = bh >> 3, hh = bh & 7;
    int t0 = tt * 64;
    const float* qg = qkv + (size_t)(b * 1536 + hh * 192) * 1024;
    const float* kg = qg + (size_t)64 * 1024;
    const float* vg = qg + (size_t)128 * 1024;

    float mn0 = fminf(decf(mm[0]), 0.f), mx0 = fmaxf(decf(mm[1]), 0.f);
    float qsc = fmaxf((mx0 - mn0) * (1.f / 255.f), 1e-8f), qzp = rintf(-mn0 / qsc);
    float mn1 = fminf(decf(mm[2]), 0.f), mx1 = fmaxf(decf(mm[3]), 0.f);
    float ksc = fmaxf((mx1 - mn1) * (1.f / 255.f), 1e-8f), kzp = rintf(-mn1 / ksc);
    float mn2 = fminf(decf(mm[4]), 0.f), mx2 = fmaxf(decf(mm[5]), 0.f);
    float vsc = fmaxf((mx2 - mn2) * (1.f / 255.f), 1e-8f), vzp = rintf(-mn2 / vsc);
    float inv_q = 1.f / qsc, inv_k = 1.f / ksc, inv_v = 1.f / vsc;
    float alpha = qsc * ksc * 0.125f;

    __shared__ __bf16 qT[64][72];
    __shared__ __bf16 kT[64][72];
    __shared__ __bf16 vL[64][72];
    __shared__ __bf16 pL[4][16][72];

    int tid = threadIdx.x;
    int l = tid & 63, w = tid >> 6;
    int lo = l & 15, hi = l >> 4;
    int c0 = (tid >> 4) * 4;
    int tl = tid & 15;

#pragma unroll
    for (int r = 0; r < 4; ++r) {
        int t = tl + 16 * r;
        float y0 = dqi(qg[(size_t)(c0 + 0) * 1024 + t0 + t], inv_q, qzp);
        float y1 = dqi(qg[(size_t)(c0 + 1) * 1024 + t0 + t], inv_q, qzp);
        float y2 = dqi(qg[(size_t)(c0 + 2) * 1024 + t0 + t], inv_q, qzp);
        float y3 = dqi(qg[(size_t)(c0 + 3) * 1024 + t0 + t], inv_q, qzp);
        bf16x4 o = {(__bf16)y0, (__bf16)y1, (__bf16)y2, (__bf16)y3};
        *(bf16x4*)&qT[t][c0] = o;
    }
    __syncthreads();
    bf16x8 qf0 = *(const bf16x8*)&qT[16 * w + lo][hi * 8];
    bf16x8 qf1 = *(const bf16x8*)&qT[16 * w + lo][32 + hi * 8];

    f32x4 acc0 = {}, acc1 = {}, acc2 = {}, acc3 = {};
    float m_run = -1e30f, l_run = 0.f;

    for (int st = 0; st < 16; ++st) {
        int s0 = st * 64;
        __syncthreads();
#pragma unroll
        for (int r = 0; r < 4; ++r) {
            int srow = tl + 16 * r;
            float y0 = dqi(kg[(size_t)(c0 + 0) * 1024 + s0 + srow], inv_k, kzp);
            float y1 = dqi(kg[(size_t)(c0 + 1) * 1024 + s0 + srow], inv_k, kzp);
            float y2 = dqi(kg[(size_t)(c0 + 2) * 1024 + s0 + srow], inv_k, kzp);
            float y3 = dqi(kg[(size_t)(c0 + 3) * 1024 + s0 + srow], inv_k, kzp);
            bf16x4 ok = {(__bf16)y0, (__bf16)y1, (__bf16)y2, (__bf16)y3};
            *(bf16x4*)&kT[srow][c0] = ok;
            int c = (tid >> 4) + 16 * r;
            float4 vv = *(const float4*)(vg + (size_t)c * 1024 + s0 + (tid & 15) * 4);
            bf16x4 ov = {(__bf16)dqi(vv.x, inv_v, vzp), (__bf16)dqi(vv.y, inv_v, vzp),
                         (__bf16)dqi(vv.z, inv_v, vzp), (__bf16)dqi(vv.w, inv_v, vzp)};
            *(bf16x4*)&vL[c][(tid & 15) * 4] = ov;
        }
        __syncthreads();

        f32x4 sf[4] = {};
#pragma unroll
        for (int sm = 0; sm < 4; ++sm)
            sf[sm] = mfma16(*(const bf16x8*)&kT[16 * sm + lo][hi * 8], qf0, sf[sm]);
#pragma unroll
        for (int sm = 0; sm < 4; ++sm)
            sf[sm] = mfma16(*(const bf16x8*)&kT[16 * sm + lo][32 + hi * 8], qf1, sf[sm]);

        float tm = -1e30f;
#pragma unroll
        for (int sm = 0; sm < 4; ++sm)
#pragma unroll
            for (int r = 0; r < 4; ++r) { sf[sm][r] *= alpha; tm = fmaxf(tm, sf[sm][r]); }
        tm = fmaxf(tm, __shfl_xor(tm, 16));
        tm = fmaxf(tm, __shfl_xor(tm, 32));
        float mnew = fmaxf(m_run, tm);
        float ts = 0.f;
#pragma unroll
        for (int sm = 0; sm < 4; ++sm)
#pragma unroll
            for (int r = 0; r < 4; ++r) {
                float p = __expf(sf[sm][r] - mnew);
                sf[sm][r] = p;
                ts += p;
            }
        ts += __shfl_xor(ts, 16);
        ts += __shfl_xor(ts, 32);
        float fr = __expf(m_run - mnew);
        l_run = l_run * fr + ts;
        m_run = mnew;
        acc0 *= fr; acc1 *= fr; acc2 *= fr; acc3 *= fr;

#pragma unroll
        for (int sm = 0; sm < 4; ++sm) {
            bf16x4 pb = {(__bf16)sf[sm][0], (__bf16)sf[sm][1], (__bf16)sf[sm][2], (__bf16)sf[sm][3]};
            *(bf16x4*)&pL[w][lo][16 * sm + hi * 4] = pb;
        }
        bf16x8 pf0 = *(const bf16x8*)&pL[w][lo][hi * 8];
        bf16x8 pf1 = *(const bf16x8*)&pL[w][lo][32 + hi * 8];
        acc0 = mfma16(*(const bf16x8*)&vL[lo][hi * 8], pf0, acc0);
        acc1 = mfma16(*(const bf16x8*)&vL[16 + lo][hi * 8], pf0, acc1);
        acc2 = mfma16(*(const bf16x8*)&vL[32 + lo][hi * 8], pf0, acc2);
        acc3 = mfma16(*(const bf16x8*)&vL[48 + lo][hi * 8], pf0, acc3);
        acc0 = mfma16(*(const bf16x8*)&vL[lo][32 + hi * 8], pf1, acc0);
        acc1 = mfma16(*(const bf16x8*)&vL[16 + lo][32 + hi * 8], pf1, acc1);
        acc2 = mfma16(*(const bf16x8*)&vL[32 + lo][32 + hi * 8], pf1, acc2);
        acc3 = mfma16(*(const bf16x8*)&vL[48 + lo][32 + hi * 8], pf1, acc3);
    }

    float rl = vsc / l_run;
    __syncthreads();
    {
        bf16x4 o0 = {(__bf16)(acc0[0] * rl), (__bf16)(acc0[1] * rl), (__bf16)(acc0[2] * rl), (__bf16)(acc0[3] * rl)};
        bf16x4 o1 = {(__bf16)(acc1[0] * rl), (__bf16)(acc1[1] * rl), (__bf16)(acc1[2] * rl), (__bf16)(acc1[3] * rl)};
        bf16x4 o2 = {(__bf16)(acc2[0] * rl), (__bf16)(acc2[1] * rl), (__bf16)(acc2[2] * rl), (__bf16)(acc2[3] * rl)};
        bf16x4 o3 = {(__bf16)(acc3[0] * rl), (__bf16)(acc3[1] * rl), (__bf16)(acc3[2] * rl), (__bf16)(acc3[3] * rl)};
        *(bf16x4*)&qT[16 * w + lo][0  + hi * 4] = o0;
        *(bf16x4*)&qT[16 * w + lo][16 + hi * 4] = o1;
        *(bf16x4*)&qT[16 * w + lo][32 + hi * 4] = o2;
        *(bf16x4*)&qT[16 * w + lo][48 + hi * 4] = o3;
    }
    __syncthreads();
    __bf16* ap = aT + ((size_t)b * 1024 + t0 + (tid >> 2)) * 512 + hh * 64;
    bf16x8 v0 = *(const bf16x8*)&qT[tid >> 2][(tid & 3) * 8];
    bf16x8 v1 = *(const bf16x8*)&qT[tid >> 2][32 + (tid & 3) * 8];
    *(bf16x8*)(ap + (tid & 3) * 8) = v0;
    *(bf16x8*)(ap + 32 + (tid & 3) * 8) = v1;
}

extern "C" void kernel_launch(void* const* d_in, const int* in_sizes, int n_in,
                              void* d_out, int out_size, void* d_ws, size_t ws_size,
                              hipStream_t stream) {
    const float* x      = (const float*)d_in[0];
    const float* gn_w   = (const float*)d_in[1];
    const float* gn_b   = (const float*)d_in[2];
    const float* qkv_w  = (const float*)d_in[3];
    const float* qkv_b  = (const float*)d_in[4];
    const float* proj_w = (const float*)d_in[5];
    const float* proj_b = (const float*)d_in[6];
    char* ws = (char*)d_ws;
    float*    qkv = (float*)(ws + QKV_OFF);
    __bf16*   hT  = (__bf16*)(ws + HT_OFF);   // hT, later reused as aT
    __bf16*   wq  = (__bf16*)(ws + WQ_OFF);
    __bf16*   wp  = (__bf16*)(ws + WP_OFF);
    unsigned* mm  = (unsigned*)(ws + MM_OFF);
    __bf16*   ki  = (__bf16*)(ws + KI_OFF);
    __bf16*   vi  = (__bf16*)(ws + VI_OFF);
    float* out = (float*)d_out;

    prep<<<1024, 256, 0, stream>>>(qkv_w, wq, proj_w, wp, mm);
    gn_kernel<<<256, 256, 0, stream>>>(x, gn_w, gn_b, hT);
    mgemm2<128, true, false><<<dim3(12, 8, 8), 256, 0, stream>>>(wq, hT, qkv_b, nullptr, qkv, 1536, mm);
    if (ws_size >= NEED_NEW) {
        quant_kv<<<dim3(64, 16), 256, 0, stream>>>(qkv, mm, ki, vi);
        attn3<<<1024, 256, 0, stream>>>(qkv, ki, vi, mm, hT);
    } else {
        attn_mfma<<<1024, 256, 0, stream>>>(qkv, mm, hT);
    }
    mgemm2<64, false, true><<<dim3(8, 8, 8), 256, 0, stream>>>(wp, hT, proj_b, x, out, 512, nullptr);
}

// Round 6
// 111.650 us; speedup vs baseline: 1.7566x; 1.0147x over previous
//
#include <hip/hip_runtime.h>

typedef __attribute__((ext_vector_type(8))) __bf16 bf16x8;
typedef __attribute__((ext_vector_type(4))) __bf16 bf16x4;
typedef __attribute__((ext_vector_type(4))) float  f32x4;

// Problem: x (8,512,32,32) fp32 -> B=8, C=512, T=1024; 32 groups; 8 heads (ch=64)

// ws layout (bytes)
static constexpr size_t QKV_OFF = 0;                     // fp32 (8,1536,1024) 48MB
static constexpr size_t HT_OFF  = 50331648;              // bf16 (8,1024,512) 8MB: hT then aT
static constexpr size_t WQ_OFF  = HT_OFF + 8388608;      // bf16 (1536,512)
static constexpr size_t WP_OFF  = WQ_OFF + 1572864;      // bf16 (512,512)
static constexpr size_t MM_OFF  = WP_OFF + 524288;       // 6 x u32
static constexpr size_t KI_OFF  = MM_OFF + 4096;         // bf16 (64,1024,64) 8MB
static constexpr size_t VI_OFF  = KI_OFF + 8388608;      // bf16 (64,64,1024) 8MB
static constexpr size_t QI_OFF  = VI_OFF + 8388608;      // bf16 (64,1024,64) 8MB
static constexpr size_t NEED_NEW = QI_OFF + 8388608;

__device__ __forceinline__ unsigned encf(float f) {
    unsigned u = __float_as_uint(f);
    return (u & 0x80000000u) ? ~u : (u | 0x80000000u);
}
__device__ __forceinline__ float decf(unsigned e) {
    unsigned u = (e & 0x80000000u) ? (e & 0x7fffffffu) : ~e;
    return __uint_as_float(u);
}
// integer-valued dequant core: clip(rint(x/s)+zp,0,255)-zp == clip(rint(x/s), -zp, 255-zp)
__device__ __forceinline__ float dqi(float x, float inv_s, float zp) {
    float y = rintf(x * inv_s);
    return fminf(fmaxf(y, -zp), 255.0f - zp);
}
__device__ __forceinline__ f32x4 mfma16(bf16x8 a, bf16x8 b, f32x4 c) {
    return __builtin_amdgcn_mfma_f32_16x16x32_bf16(a, b, c, 0, 0, 0);
}
__device__ __forceinline__ float exp2i(float x) {  // raw v_exp_f32 (2^x)
    float r;
    asm("v_exp_f32 %0, %1" : "=v"(r) : "v"(x));
    return r;
}
__device__ __forceinline__ void glds16(const __bf16* g, __bf16* l) {
    __builtin_amdgcn_global_load_lds((const __attribute__((address_space(1))) void*)g,
                                     (__attribute__((address_space(3))) void*)l, 16, 0, 0);
}

// ---------------- prep: weight fp32->bf16 (both) + mm init ----------------
__global__ __launch_bounds__(256) void prep(const float* __restrict__ qw,
                                            __bf16* __restrict__ wq,
                                            const float* __restrict__ pw,
                                            __bf16* __restrict__ wp,
                                            unsigned* __restrict__ mm) {
    int bid = blockIdx.x, tid = threadIdx.x;
    if (bid == 0 && tid < 3) { mm[2 * tid] = 0xFFFFFFFFu; mm[2 * tid + 1] = 0u; }
    if (bid < 768) {
        int i = bid * 256 + tid;
        float4 v = ((const float4*)qw)[i];
        bf16x4 o = {(__bf16)v.x, (__bf16)v.y, (__bf16)v.z, (__bf16)v.w};
        ((bf16x4*)wq)[i] = o;
    } else {
        int i = (bid - 768) * 256 + tid;
        float4 v = ((const float4*)pw)[i];
        bf16x4 o = {(__bf16)v.x, (__bf16)v.y, (__bf16)v.z, (__bf16)v.w};
        ((bf16x4*)wp)[i] = o;
    }
}

// ---------------- GroupNorm -> hT bf16 (B,T,C) ----------------
__global__ __launch_bounds__(256) void gn_kernel(const float* __restrict__ x,
                                                 const float* __restrict__ w,
                                                 const float* __restrict__ bv,
                                                 __bf16* __restrict__ hT) {
    int blk = blockIdx.x;
    int b = blk >> 5, g = blk & 31;
    const float* xp = x + (size_t)(b * 512 + g * 16) * 1024;
    int tid = threadIdx.x;

    float4 v[16];
    float sum = 0.f, ss = 0.f;
#pragma unroll
    for (int i = 0; i < 16; ++i) {
        v[i] = *(const float4*)(xp + (size_t)i * 1024 + tid * 4);
        sum += v[i].x + v[i].y + v[i].z + v[i].w;
        ss  += v[i].x * v[i].x + v[i].y * v[i].y + v[i].z * v[i].z + v[i].w * v[i].w;
    }
#pragma unroll
    for (int m = 1; m < 64; m <<= 1) {
        sum += __shfl_xor(sum, m);
        ss  += __shfl_xor(ss, m);
    }
    __shared__ float s1[4], s2[4];
    int wid = tid >> 6;
    if ((tid & 63) == 0) { s1[wid] = sum; s2[wid] = ss; }
    __syncthreads();
    sum = s1[0] + s1[1] + s1[2] + s1[3];
    ss  = s2[0] + s2[1] + s2[2] + s2[3];
    float mean = sum * (1.0f / 16384.0f);
    float var  = ss * (1.0f / 16384.0f) - mean * mean;
    float rstd = rsqrtf(var + 1e-5f);

    float wc[16], bc[16];
#pragma unroll
    for (int c = 0; c < 16; ++c) { wc[c] = w[g * 16 + c] * rstd; bc[c] = bv[g * 16 + c]; }

#pragma unroll
    for (int j = 0; j < 4; ++j) {
        int t = tid * 4 + j;
        bf16x8 o0, o1;
#pragma unroll
        for (int c = 0; c < 8; ++c)
            o0[c] = (__bf16)(((&v[c].x)[j] - mean) * wc[c] + bc[c]);
#pragma unroll
        for (int c = 0; c < 8; ++c)
            o1[c] = (__bf16)(((&v[c + 8].x)[j] - mean) * wc[c + 8] + bc[c + 8]);
        __bf16* hp = hT + ((size_t)b * 1024 + t) * 512 + g * 16;
        *(bf16x8*)hp = o0;
        *(bf16x8*)(hp + 8) = o1;
    }
}

// ---------------- MFMA GEMM v3: 2-phase glds pipeline + XCD swizzle + LDS C-stage ----------------
// out[b][m][n] = sum_c A[m][c] * Bt[b][n][c] + bias[m] (+resid)(+minmax)
template <int MTILE, int MOT, bool MINMAX, bool RESID>
__global__ __launch_bounds__(256) void mgemm3(const __bf16* __restrict__ A,   // [M][512]
                                              const __bf16* __restrict__ Bt,  // [8][1024][512]
                                              const float* __restrict__ bias,
                                              const float* __restrict__ resid,
                                              float* __restrict__ out,
                                              int M, unsigned* __restrict__ mm) {
    constexpr int NF = (MTILE == 128) ? 4 : 2;
    constexpr int ASZ = MTILE * 64;
    constexpr int BSZ = 128 * 64;
    __shared__ __attribute__((aligned(16))) char smem_raw[2 * (ASZ + BSZ) * 2];
    __bf16* sA0 = (__bf16*)smem_raw;
    __bf16* sA1 = sA0 + ASZ;
    __bf16* sB0 = sA1 + ASZ;
    __bf16* sB1 = sB0 + BSZ;
    __shared__ float smn[4], smx[4];

    int tid = threadIdx.x;
    int l = tid & 63, w = tid >> 6;
    int lo = l & 15, hi = l >> 4;

    // XCD-chunked swizzle: consecutive wg within a chunk share (nt,b) -> B-panel L2-local
    int f = blockIdx.x;
    constexpr int NWG = MOT * 64;
    int wg = (f & 7) * (NWG / 8) + (f >> 3);
    int mo = wg % MOT, nb = wg / MOT;
    int nt = nb & 7, b = nb >> 3;

    const __bf16* Ap = A + (size_t)mo * MTILE * 512;
    const __bf16* Bp = Bt + ((size_t)b * 1024 + (size_t)nt * 128) * 512;
    int m0 = (MTILE == 128) ? (w >> 1) * 64 : 0;
    int n0 = (MTILE == 128) ? (w & 1) * 64 : w * 32;
    f32x4 acc[4][NF] = {};
    int scd = tid & 7;

    auto STAGE = [&](__bf16* dA, __bf16* dB, int k0) {
#pragma unroll
        for (int p = 0; p < MTILE / 32; ++p) {
            int lin = p * 2048 + tid * 8;
            int row = lin >> 6;
            glds16(Ap + (size_t)row * 512 + k0 + ((scd ^ (row & 7)) << 3), dA + lin);
        }
#pragma unroll
        for (int p = 0; p < 4; ++p) {
            int lin = p * 2048 + tid * 8;
            int row = lin >> 6;
            glds16(Bp + (size_t)row * 512 + k0 + ((scd ^ (row & 7)) << 3), dB + lin);
        }
    };
    auto COMPUTE = [&](const __bf16* cA, const __bf16* cB) {
#pragma unroll
        for (int kk = 0; kk < 2; ++kk) {
            int rch = ((kk * 4 + hi) ^ (lo & 7)) << 3;
            bf16x8 af[4], bfr[NF];
#pragma unroll
            for (int i = 0; i < 4; ++i) af[i] = *(const bf16x8*)&cA[(m0 + 16 * i + lo) * 64 + rch];
#pragma unroll
            for (int j = 0; j < NF; ++j) bfr[j] = *(const bf16x8*)&cB[(n0 + 16 * j + lo) * 64 + rch];
#pragma unroll
            for (int i = 0; i < 4; ++i)
#pragma unroll
                for (int j = 0; j < NF; ++j) acc[i][j] = mfma16(af[i], bfr[j], acc[i][j]);
        }
    };

    STAGE(sA0, sB0, 0);
    __syncthreads();              // drain stage 0
#pragma unroll
    for (int kp = 0; kp < 4; ++kp) {
        STAGE(sA1, sB1, kp * 128 + 64);   // issue next before compute
        COMPUTE(sA0, sB0);
        __syncthreads();                  // one drain per K-step
        if (kp < 3) STAGE(sA0, sB0, kp * 128 + 128);
        COMPUTE(sA1, sB1);
        __syncthreads();
    }

    // ---- epilogue: C through LDS, coalesced float4 stores ----
    float* cs = (float*)smem_raw;   // stride 132
    float mn = 1e30f, mx = -1e30f;
    constexpr int NH = (MTILE == 128) ? 2 : 1;
#pragma unroll
    for (int h = 0; h < NH; ++h) {
        __syncthreads();
        if (MTILE == 64 || (w >> 1) == h) {
#pragma unroll
            for (int i = 0; i < 4; ++i)
#pragma unroll
                for (int r = 0; r < 4; ++r) {
                    int rl = 16 * i + hi * 4 + r;
                    float bi = bias[mo * MTILE + h * 64 + rl];
#pragma unroll
                    for (int j = 0; j < NF; ++j)
                        cs[rl * 132 + n0 + 16 * j + lo] = acc[i][j][r] + bi;
                }
        }
        __syncthreads();
#pragma unroll
        for (int it = 0; it < 8; ++it) {
            int lin = it * 256 + tid;
            int rr = lin >> 5, cc = (lin & 31) << 2;
            float4 v = *(const float4*)&cs[rr * 132 + cc];
            if (MINMAX) {
                mn = fminf(mn, fminf(fminf(v.x, v.y), fminf(v.z, v.w)));
                mx = fmaxf(mx, fmaxf(fmaxf(v.x, v.y), fmaxf(v.z, v.w)));
            }
            int grow = mo * MTILE + h * 64 + rr;
            size_t gaddr = ((size_t)b * M + grow) * 1024 + nt * 128 + cc;
            if (RESID) {
                float4 rv = *(const float4*)&resid[gaddr];
                v.x += rv.x; v.y += rv.y; v.z += rv.z; v.w += rv.w;
            }
            *(float4*)&out[gaddr] = v;
        }
    }

    if (MINMAX) {
#pragma unroll
        for (int msk = 1; msk < 64; msk <<= 1) {
            mn = fminf(mn, __shfl_xor(mn, msk));
            mx = fmaxf(mx, __shfl_xor(mx, msk));
        }
        if (l == 0) { smn[w] = mn; smx[w] = mx; }
        __syncthreads();
        if (tid == 0) {
            mn = fminf(fminf(smn[0], smn[1]), fminf(smn[2], smn[3]));
            mx = fmaxf(fmaxf(smx[0], smx[1]), fmaxf(smx[2], smx[3]));
            int id = mo >> 2;  // 4 x 128-row tiles per tensor (q,k,v)
            atomicMin(&mm[2 * id], encf(mn));
            atomicMax(&mm[2 * id + 1], encf(mx));
        }
    }
}

// ---------------- quant Q/K/V pass ----------------
// grid (64 bh, 16 tile); integer-valued bf16: qi (bh,t,c), ki (bh,s,c), vi (bh,c,s)
__global__ __launch_bounds__(256) void quant_qkv(const float* __restrict__ qkv,
                                                 const unsigned* __restrict__ mm,
                                                 __bf16* __restrict__ qi,
                                                 __bf16* __restrict__ ki,
                                                 __bf16* __restrict__ vi) {
    int bh = blockIdx.x, tt = blockIdx.y;
    int b = bh >> 3, hh = bh & 7;
    int t0 = tt * 64;
    const float* qg = qkv + (size_t)(b * 1536 + hh * 192) * 1024;
    const float* kg = qg + 65536;
    const float* vg = qg + 131072;

    float mn0 = fminf(decf(mm[0]), 0.f), mx0 = fmaxf(decf(mm[1]), 0.f);
    float qsc = fmaxf((mx0 - mn0) * (1.f / 255.f), 1e-8f), qzp = rintf(-mn0 / qsc);
    float mn1 = fminf(decf(mm[2]), 0.f), mx1 = fmaxf(decf(mm[3]), 0.f);
    float ksc = fmaxf((mx1 - mn1) * (1.f / 255.f), 1e-8f), kzp = rintf(-mn1 / ksc);
    float mn2 = fminf(decf(mm[4]), 0.f), mx2 = fmaxf(decf(mm[5]), 0.f);
    float vsc = fmaxf((mx2 - mn2) * (1.f / 255.f), 1e-8f), vzp = rintf(-mn2 / vsc);
    float inv_q = 1.f / qsc, inv_k = 1.f / ksc, inv_v = 1.f / vsc;

    __shared__ __bf16 sT[64][68];
    int tid = threadIdx.x;
    int cr = tid >> 4, t4 = tid & 15;
    int s = tid >> 2, c0 = (tid & 3) * 16;

    // V stream
    __bf16* vd = vi + (size_t)bh * 65536;
#pragma unroll
    for (int r = 0; r < 4; ++r) {
        int c = 16 * r + cr;
        float4 v = *(const float4*)(vg + (size_t)c * 1024 + t0 + t4 * 4);
        bf16x4 o = {(__bf16)dqi(v.x, inv_v, vzp), (__bf16)dqi(v.y, inv_v, vzp),
                    (__bf16)dqi(v.z, inv_v, vzp), (__bf16)dqi(v.w, inv_v, vzp)};
        *(bf16x4*)(vd + (size_t)c * 1024 + t0 + t4 * 4) = o;
    }

    // K transpose -> (s, c)
#pragma unroll
    for (int r = 0; r < 4; ++r) {
        int c = 16 * r + cr;
        float4 v = *(const float4*)(kg + (size_t)c * 1024 + t0 + t4 * 4);
        sT[t4 * 4 + 0][c] = (__bf16)dqi(v.x, inv_k, kzp);
        sT[t4 * 4 + 1][c] = (__bf16)dqi(v.y, inv_k, kzp);
        sT[t4 * 4 + 2][c] = (__bf16)dqi(v.z, inv_k, kzp);
        sT[t4 * 4 + 3][c] = (__bf16)dqi(v.w, inv_k, kzp);
    }
    __syncthreads();
    {
        bf16x8 a0 = *(const bf16x8*)&sT[s][c0];
        bf16x8 a1 = *(const bf16x8*)&sT[s][c0 + 8];
        __bf16* kd = ki + ((size_t)bh * 1024 + t0 + s) * 64 + c0;
        *(bf16x8*)kd = a0;
        *(bf16x8*)(kd + 8) = a1;
    }
    __syncthreads();

    // Q transpose -> (t, c)
#pragma unroll
    for (int r = 0; r < 4; ++r) {
        int c = 16 * r + cr;
        float4 v = *(const float4*)(qg + (size_t)c * 1024 + t0 + t4 * 4);
        sT[t4 * 4 + 0][c] = (__bf16)dqi(v.x, inv_q, qzp);
        sT[t4 * 4 + 1][c] = (__bf16)dqi(v.y, inv_q, qzp);
        sT[t4 * 4 + 2][c] = (__bf16)dqi(v.z, inv_q, qzp);
        sT[t4 * 4 + 3][c] = (__bf16)dqi(v.w, inv_q, qzp);
    }
    __syncthreads();
    {
        bf16x8 a0 = *(const bf16x8*)&sT[s][c0];
        bf16x8 a1 = *(const bf16x8*)&sT[s][c0 + 8];
        __bf16* qd = qi + ((size_t)bh * 1024 + t0 + s) * 64 + c0;
        *(bf16x8*)qd = a0;
        *(bf16x8*)(qd + 8) = a1;
    }
}

// ---------------- attention v5: all-bf16 inputs, LDS K/V, exp2 softmax, defer-max ----------------
__global__ __launch_bounds__(256) void attn4(const __bf16* __restrict__ qi,
                                             const __bf16* __restrict__ ki,
                                             const __bf16* __restrict__ vi,
                                             const unsigned* __restrict__ mm,
                                             __bf16* __restrict__ aT) {
    int f = blockIdx.x;
    int bh = (f & 7) * 8 + ((f >> 3) & 7);  // 8 heads x 16 t-tiles per XCD
    int tt = f >> 6;
    int b = bh >> 3, hh = bh & 7;
    int t0 = tt * 64;
    const __bf16* kb = ki + (size_t)bh * 65536;
    const __bf16* vb = vi + (size_t)bh * 65536;

    float mn0 = fminf(decf(mm[0]), 0.f), mx0 = fmaxf(decf(mm[1]), 0.f);
    float qsc = fmaxf((mx0 - mn0) * (1.f / 255.f), 1e-8f);
    float mn1 = fminf(decf(mm[2]), 0.f), mx1 = fmaxf(decf(mm[3]), 0.f);
    float ksc = fmaxf((mx1 - mn1) * (1.f / 255.f), 1e-8f);
    float mn2 = fminf(decf(mm[4]), 0.f), mx2 = fmaxf(decf(mm[5]), 0.f);
    float vsc = fmaxf((mx2 - mn2) * (1.f / 255.f), 1e-8f);
    float alpha2 = qsc * ksc * 0.125f * 1.4426950408889634f;  // alpha * log2(e)
    float thr = 11.5415603f / alpha2;                          // 8 nats in raw-score units

    __shared__ __bf16 sh[64][72];    // per-wave P -> output stage
    __shared__ __bf16 kS[64 * 64];   // K tile (s,c), chunk-swizzled
    __shared__ __bf16 vS[64 * 64];   // V tile (c,s), chunk-swizzled
    int tid = threadIdx.x;
    int l = tid & 63, w = tid >> 6;
    int lo = l & 15, hi = l >> 4;

    // q frags straight from qi (integer-valued, pre-transposed)
    const __bf16* qrow = qi + ((size_t)bh * 1024 + t0 + 16 * w + lo) * 64;
    bf16x8 qf0 = *(const bf16x8*)(qrow + hi * 8);
    bf16x8 qf1 = *(const bf16x8*)(qrow + 32 + hi * 8);

    // staging geometry: thread -> row (0..63), two 16B chunks
    int srow = tid >> 2, sc2 = (tid & 3) * 2;
    int swz0 = (sc2 ^ (srow & 7)) << 3;
    int swz1 = ((sc2 + 1) ^ (srow & 7)) << 3;
    const __bf16* kROW = kb + (size_t)srow * 64;          // + st*4096
    const __bf16* vROW = vb + (size_t)srow * 1024;        // + st*64
    int lx = lo & 7;
    int rc0 = (hi ^ lx) << 3;          // kk=0 chunk
    int rc1 = ((4 + hi) ^ lx) << 3;    // kk=1 chunk

    // prefetch tile 0
    bf16x8 kr0 = *(const bf16x8*)(kROW + sc2 * 8);
    bf16x8 kr1 = *(const bf16x8*)(kROW + sc2 * 8 + 8);
    bf16x8 vr0 = *(const bf16x8*)(vROW + sc2 * 8);
    bf16x8 vr1 = *(const bf16x8*)(vROW + sc2 * 8 + 8);

    f32x4 acc0 = {}, acc1 = {}, acc2 = {}, acc3 = {};
    float m_run = -1e30f, l_run = 0.f;

    for (int st = 0; st < 16; ++st) {
        __syncthreads();   // previous tile's LDS reads done
        *(bf16x8*)(kS + srow * 64 + swz0) = kr0;
        *(bf16x8*)(kS + srow * 64 + swz1) = kr1;
        *(bf16x8*)(vS + srow * 64 + swz0) = vr0;
        *(bf16x8*)(vS + srow * 64 + swz1) = vr1;
        __syncthreads();   // tile staged
        if (st < 15) {     // prefetch next tile during compute
            kr0 = *(const bf16x8*)(kROW + (st + 1) * 4096 + sc2 * 8);
            kr1 = *(const bf16x8*)(kROW + (st + 1) * 4096 + sc2 * 8 + 8);
            vr0 = *(const bf16x8*)(vROW + (st + 1) * 64 + sc2 * 8);
            vr1 = *(const bf16x8*)(vROW + (st + 1) * 64 + sc2 * 8 + 8);
        }

        // scores: D[s][t] = K·Q (raw integer dot products)
        f32x4 sf[4] = {};
        __builtin_amdgcn_s_setprio(1);
#pragma unroll
        for (int sm = 0; sm < 4; ++sm)
            sf[sm] = mfma16(*(const bf16x8*)(kS + (16 * sm + lo) * 64 + rc0), qf0, sf[sm]);
#pragma unroll
        for (int sm = 0; sm < 4; ++sm)
            sf[sm] = mfma16(*(const bf16x8*)(kS + (16 * sm + lo) * 64 + rc1), qf1, sf[sm]);
        __builtin_amdgcn_s_setprio(0);

        // online softmax in exp2 space (t = lane-local)
        float tm = -1e30f;
#pragma unroll
        for (int sm = 0; sm < 4; ++sm) {
            float a = fmaxf(sf[sm][0], sf[sm][1]);
            float c = fmaxf(sf[sm][2], sf[sm][3]);
            tm = fmaxf(tm, fmaxf(a, c));
        }
        tm = fmaxf(tm, __shfl_xor(tm, 16));
        tm = fmaxf(tm, __shfl_xor(tm, 32));
        if (!__all(tm <= m_run + thr)) {   // defer-max
            float mnew = fmaxf(m_run, tm);
            float fr = exp2i(alpha2 * (m_run - mnew));
            acc0 *= fr; acc1 *= fr; acc2 *= fr; acc3 *= fr;
            l_run *= fr;
            m_run = mnew;
        }
        float cc = -alpha2 * m_run;
        float ts = 0.f;
#pragma unroll
        for (int sm = 0; sm < 4; ++sm)
#pragma unroll
            for (int r = 0; r < 4; ++r) {
                float p = exp2i(fmaf(sf[sm][r], alpha2, cc));
                sf[sm][r] = p;
                ts += p;
            }
        ts += __shfl_xor(ts, 16);
        ts += __shfl_xor(ts, 32);
        l_run += ts;

        // P -> LDS (wave-private rows)
#pragma unroll
        for (int sm = 0; sm < 4; ++sm) {
            bf16x4 pb = {(__bf16)sf[sm][0], (__bf16)sf[sm][1], (__bf16)sf[sm][2], (__bf16)sf[sm][3]};
            *(bf16x4*)&sh[16 * w + lo][16 * sm + hi * 4] = pb;
        }
        bf16x8 pf0 = *(const bf16x8*)&sh[16 * w + lo][hi * 8];
        bf16x8 pf1 = *(const bf16x8*)&sh[16 * w + lo][32 + hi * 8];

        // PV: D[c][t] += V·P
        __builtin_amdgcn_s_setprio(1);
        acc0 = mfma16(*(const bf16x8*)(vS + (lo) * 64 + rc0), pf0, acc0);
        acc1 = mfma16(*(const bf16x8*)(vS + (16 + lo) * 64 + rc0), pf0, acc1);
        acc2 = mfma16(*(const bf16x8*)(vS + (32 + lo) * 64 + rc0), pf0, acc2);
        acc3 = mfma16(*(const bf16x8*)(vS + (48 + lo) * 64 + rc0), pf0, acc3);
        acc0 = mfma16(*(const bf16x8*)(vS + (lo) * 64 + rc1), pf1, acc0);
        acc1 = mfma16(*(const bf16x8*)(vS + (16 + lo) * 64 + rc1), pf1, acc1);
        acc2 = mfma16(*(const bf16x8*)(vS + (32 + lo) * 64 + rc1), pf1, acc2);
        acc3 = mfma16(*(const bf16x8*)(vS + (48 + lo) * 64 + rc1), pf1, acc3);
        __builtin_amdgcn_s_setprio(0);
    }

    float rl = vsc / l_run;
    __syncthreads();
    {
        bf16x4 o0 = {(__bf16)(acc0[0] * rl), (__bf16)(acc0[1] * rl), (__bf16)(acc0[2] * rl), (__bf16)(acc0[3] * rl)};
        bf16x4 o1 = {(__bf16)(acc1[0] * rl), (__bf16)(acc1[1] * rl), (__bf16)(acc1[2] * rl), (__bf16)(acc1[3] * rl)};
        bf16x4 o2 = {(__bf16)(acc2[0] * rl), (__bf16)(acc2[1] * rl), (__bf16)(acc2[2] * rl), (__bf16)(acc2[3] * rl)};
        bf16x4 o3 = {(__bf16)(acc3[0] * rl), (__bf16)(acc3[1] * rl), (__bf16)(acc3[2] * rl), (__bf16)(acc3[3] * rl)};
        *(bf16x4*)&sh[16 * w + lo][0  + hi * 4] = o0;
        *(bf16x4*)&sh[16 * w + lo][16 + hi * 4] = o1;
        *(bf16x4*)&sh[16 * w + lo][32 + hi * 4] = o2;
        *(bf16x4*)&sh[16 * w + lo][48 + hi * 4] = o3;
    }
    __syncthreads();
    __bf16* ap = aT + ((size_t)b * 1024 + t0 + (tid >> 2)) * 512 + hh * 64;
    bf16x8 v0 = *(const bf16x8*)&sh[tid >> 2][(tid & 3) * 8];
    bf16x8 v1 = *(const bf16x8*)&sh[tid >> 2][32 + (tid & 3) * 8];
    *(bf16x8*)(ap + (tid & 3) * 8) = v0;
    *(bf16x8*)(ap + 32 + (tid & 3) * 8) = v1;
}

// ---------------- fallback attention (fp32 qkv, used if ws too small) ----------------
__global__ __launch_bounds__(256) void attn_mfma(const float* __restrict__ qkv,
                                                 const unsigned* __restrict__ mm,
                                                 __bf16* __restrict__ aT) {
    int f = blockIdx.x;
    int bh = (f & 7) * 8 + ((f >> 3) & 7);
    int tt = f >> 6;
    int b = bh >> 3, hh = bh & 7;
    int t0 = tt * 64;
    const float* qg = qkv + (size_t)(b * 1536 + hh * 192) * 1024;
    const float* kg = qg + (size_t)64 * 1024;
    const float* vg = qg + (size_t)128 * 1024;

    float mn0 = fminf(decf(mm[0]), 0.f), mx0 = fmaxf(decf(mm[1]), 0.f);
    float qsc = fmaxf((mx0 - mn0) * (1.f / 255.f), 1e-8f), qzp = rintf(-mn0 / qsc);
    float mn1 = fminf(decf(mm[2]), 0.f), mx1 = fmaxf(decf(mm[3]), 0.f);
    float ksc = fmaxf((mx1 - mn1) * (1.f / 255.f), 1e-8f), kzp = rintf(-mn1 / ksc);
    float mn2 = fminf(decf(mm[4]), 0.f), mx2 = fmaxf(decf(mm[5]), 0.f);
    float vsc = fmaxf((mx2 - mn2) * (1.f / 255.f), 1e-8f), vzp = rintf(-mn2 / vsc);
    float inv_q = 1.f / qsc, inv_k = 1.f / ksc, inv_v = 1.f / vsc;
    float alpha = qsc * ksc * 0.125f;

    __shared__ __bf16 qT[64][72];
    __shared__ __bf16 kT[64][72];
    __shared__ __bf16 vL[64][72];
    __shared__ __bf16 pL[4][16][72];

    int tid = threadIdx.x;
    int l = tid & 63, w = tid >> 6;
    int lo = l & 15, hi = l >> 4;
    int c0 = (tid >> 4) * 4;
    int tl = tid & 15;

#pragma unroll
    for (int r = 0; r < 4; ++r) {
        int t = tl + 16 * r;
        float y0 = dqi(qg[(size_t)(c0 + 0) * 1024 + t0 + t], inv_q, qzp);
        float y1 = dqi(qg[(size_t)(c0 + 1) * 1024 + t0 + t], inv_q, qzp);
        float y2 = dqi(qg[(size_t)(c0 + 2) * 1024 + t0 + t], inv_q, qzp);
        float y3 = dqi(qg[(size_t)(c0 + 3) * 1024 + t0 + t], inv_q, qzp);
        bf16x4 o = {(__bf16)y0, (__bf16)y1, (__bf16)y2, (__bf16)y3};
        *(bf16x4*)&qT[t][c0] = o;
    }
    __syncthreads();
    bf16x8 qf0 = *(const bf16x8*)&qT[16 * w + lo][hi * 8];
    bf16x8 qf1 = *(const bf16x8*)&qT[16 * w + lo][32 + hi * 8];

    f32x4 acc0 = {}, acc1 = {}, acc2 = {}, acc3 = {};
    float m_run = -1e30f, l_run = 0.f;

    for (int st = 0; st < 16; ++st) {
        int s0 = st * 64;
        __syncthreads();
#pragma unroll
        for (int r = 0; r < 4; ++r) {
            int srow = tl + 16 * r;
            float y0 = dqi(kg[(size_t)(c0 + 0) * 1024 + s0 + srow], inv_k, kzp);
            float y1 = dqi(kg[(size_t)(c0 + 1) * 1024 + s0 + srow], inv_k, kzp);
            float y2 = dqi(kg[(size_t)(c0 + 2) * 1024 + s0 + srow], inv_k, kzp);
            float y3 = dqi(kg[(size_t)(c0 + 3) * 1024 + s0 + srow], inv_k, kzp);
            bf16x4 ok = {(__bf16)y0, (__bf16)y1, (__bf16)y2, (__bf16)y3};
            *(bf16x4*)&kT[srow][c0] = ok;
            int c = (tid >> 4) + 16 * r;
            float4 vv = *(const float4*)(vg + (size_t)c * 1024 + s0 + (tid & 15) * 4);
            bf16x4 ov = {(__bf16)dqi(vv.x, inv_v, vzp), (__bf16)dqi(vv.y, inv_v, vzp),
                         (__bf16)dqi(vv.z, inv_v, vzp), (__bf16)dqi(vv.w, inv_v, vzp)};
            *(bf16x4*)&vL[c][(tid & 15) * 4] = ov;
        }
        __syncthreads();

        f32x4 sf[4] = {};
#pragma unroll
        for (int sm = 0; sm < 4; ++sm)
            sf[sm] = mfma16(*(const bf16x8*)&kT[16 * sm + lo][hi * 8], qf0, sf[sm]);
#pragma unroll
        for (int sm = 0; sm < 4; ++sm)
            sf[sm] = mfma16(*(const bf16x8*)&kT[16 * sm + lo][32 + hi * 8], qf1, sf[sm]);

        float tm = -1e30f;
#pragma unroll
        for (int sm = 0; sm < 4; ++sm)
#pragma unroll
            for (int r = 0; r < 4; ++r) { sf[sm][r] *= alpha; tm = fmaxf(tm, sf[sm][r]); }
        tm = fmaxf(tm, __shfl_xor(tm, 16));
        tm = fmaxf(tm, __shfl_xor(tm, 32));
        float mnew = fmaxf(m_run, tm);
        float ts = 0.f;
#pragma unroll
        for (int sm = 0; sm < 4; ++sm)
#pragma unroll
            for (int r = 0; r < 4; ++r) {
                float p = __expf(sf[sm][r] - mnew);
                sf[sm][r] = p;
                ts += p;
            }
        ts += __shfl_xor(ts, 16);
        ts += __shfl_xor(ts, 32);
        float fr = __expf(m_run - mnew);
        l_run = l_run * fr + ts;
        m_run = mnew;
        acc0 *= fr; acc1 *= fr; acc2 *= fr; acc3 *= fr;

#pragma unroll
        for (int sm = 0; sm < 4; ++sm) {
            bf16x4 pb = {(__bf16)sf[sm][0], (__bf16)sf[sm][1], (__bf16)sf[sm][2], (__bf16)sf[sm][3]};
            *(bf16x4*)&pL[w][lo][16 * sm + hi * 4] = pb;
        }
        bf16x8 pf0 = *(const bf16x8*)&pL[w][lo][hi * 8];
        bf16x8 pf1 = *(const bf16x8*)&pL[w][lo][32 + hi * 8];
        acc0 = mfma16(*(const bf16x8*)&vL[lo][hi * 8], pf0, acc0);
        acc1 = mfma16(*(const bf16x8*)&vL[16 + lo][hi * 8], pf0, acc1);
        acc2 = mfma16(*(const bf16x8*)&vL[32 + lo][hi * 8], pf0, acc2);
        acc3 = mfma16(*(const bf16x8*)&vL[48 + lo][hi * 8], pf0, acc3);
        acc0 = mfma16(*(const bf16x8*)&vL[lo][32 + hi * 8], pf1, acc0);
        acc1 = mfma16(*(const bf16x8*)&vL[16 + lo][32 + hi * 8], pf1, acc1);
        acc2 = mfma16(*(const bf16x8*)&vL[32 + lo][32 + hi * 8], pf1, acc2);
        acc3 = mfma16(*(const bf16x8*)&vL[48 + lo][32 + hi * 8], pf1, acc3);
    }

    float rl = vsc / l_run;
    __syncthreads();
    {
        bf16x4 o0 = {(__bf16)(acc0[0] * rl), (__bf16)(acc0[1] * rl), (__bf16)(acc0[2] * rl), (__bf16)(acc0[3] * rl)};
        bf16x4 o1 = {(__bf16)(acc1[0] * rl), (__bf16)(acc1[1] * rl), (__bf16)(acc1[2] * rl), (__bf16)(acc1[3] * rl)};
        bf16x4 o2 = {(__bf16)(acc2[0] * rl), (__bf16)(acc2[1] * rl), (__bf16)(acc2[2] * rl), (__bf16)(acc2[3] * rl)};
        bf16x4 o3 = {(__bf16)(acc3[0] * rl), (__bf16)(acc3[1] * rl), (__bf16)(acc3[2] * rl), (__bf16)(acc3[3] * rl)};
        *(bf16x4*)&qT[16 * w + lo][0  + hi * 4] = o0;
        *(bf16x4*)&qT[16 * w + lo][16 + hi * 4] = o1;
        *(bf16x4*)&qT[16 * w + lo][32 + hi * 4] = o2;
        *(bf16x4*)&qT[16 * w + lo][48 + hi * 4] = o3;
    }
    __syncthreads();
    __bf16* ap = aT + ((size_t)b * 1024 + t0 + (tid >> 2)) * 512 + hh * 64;
    bf16x8 v0 = *(const bf16x8*)&qT[tid >> 2][(tid & 3) * 8];
    bf16x8 v1 = *(const bf16x8*)&qT[tid >> 2][32 + (tid & 3) * 8];
    *(bf16x8*)(ap + (tid & 3) * 8) = v0;
    *(bf16x8*)(ap + 32 + (tid & 3) * 8) = v1;
}

extern "C" void kernel_launch(void* const* d_in, const int* in_sizes, int n_in,
                              void* d_out, int out_size, void* d_ws, size_t ws_size,
                              hipStream_t stream) {
    const float* x      = (const float*)d_in[0];
    const float* gn_w   = (const float*)d_in[1];
    const float* gn_b   = (const float*)d_in[2];
    const float* qkv_w  = (const float*)d_in[3];
    const float* qkv_b  = (const float*)d_in[4];
    const float* proj_w = (const float*)d_in[5];
    const float* proj_b = (const float*)d_in[6];
    char* ws = (char*)d_ws;
    float*    qkv = (float*)(ws + QKV_OFF);
    __bf16*   hT  = (__bf16*)(ws + HT_OFF);   // hT, later reused as aT
    __bf16*   wq  = (__bf16*)(ws + WQ_OFF);
    __bf16*   wp  = (__bf16*)(ws + WP_OFF);
    unsigned* mm  = (unsigned*)(ws + MM_OFF);
    __bf16*   ki  = (__bf16*)(ws + KI_OFF);
    __bf16*   vi  = (__bf16*)(ws + VI_OFF);
    __bf16*   qi  = (__bf16*)(ws + QI_OFF);
    float* out = (float*)d_out;

    prep<<<1024, 256, 0, stream>>>(qkv_w, wq, proj_w, wp, mm);
    gn_kernel<<<256, 256, 0, stream>>>(x, gn_w, gn_b, hT);
    mgemm3<128, 12, true, false><<<768, 256, 0, stream>>>(wq, hT, qkv_b, nullptr, qkv, 1536, mm);
    if (ws_size >= NEED_NEW) {
        quant_qkv<<<dim3(64, 16), 256, 0, stream>>>(qkv, mm, qi, ki, vi);
        attn4<<<1024, 256, 0, stream>>>(qi, ki, vi, mm, hT);
    } else {
        attn_mfma<<<1024, 256, 0, stream>>>(qkv, mm, hT);
    }
    mgemm3<64, 8, false, true><<<512, 256, 0, stream>>>(wp, hT, proj_b, x, out, 512, nullptr);
}

// Round 7
// 106.225 us; speedup vs baseline: 1.8464x; 1.0511x over previous
//
#include <hip/hip_runtime.h>

typedef __attribute__((ext_vector_type(8))) __bf16 bf16x8;
typedef __attribute__((ext_vector_type(4))) __bf16 bf16x4;
typedef __attribute__((ext_vector_type(4))) float  f32x4;

// Problem: x (8,512,32,32) fp32 -> B=8, C=512, T=1024; 32 groups; 8 heads (ch=64)

// ws layout (bytes)
static constexpr size_t QKV_OFF = 0;                     // fp32 (8,1536,1024) 48MB
static constexpr size_t HT_OFF  = 50331648;              // bf16 (8,1024,512) 8MB: hT then aT
static constexpr size_t WQ_OFF  = HT_OFF + 8388608;      // bf16 (1536,512)
static constexpr size_t WP_OFF  = WQ_OFF + 1572864;      // bf16 (512,512)
static constexpr size_t MM_OFF  = WP_OFF + 524288;       // 6 x u32
static constexpr size_t KI_OFF  = MM_OFF + 4096;         // bf16 (64,1024,64) 8MB
static constexpr size_t VI_OFF  = KI_OFF + 8388608;      // bf16 (64,64,1024) 8MB
static constexpr size_t QI_OFF  = VI_OFF + 8388608;      // bf16 (64,1024,64) 8MB
static constexpr size_t NEED_NEW = QI_OFF + 8388608;

__device__ __forceinline__ unsigned encf(float f) {
    unsigned u = __float_as_uint(f);
    return (u & 0x80000000u) ? ~u : (u | 0x80000000u);
}
__device__ __forceinline__ float decf(unsigned e) {
    unsigned u = (e & 0x80000000u) ? (e & 0x7fffffffu) : ~e;
    return __uint_as_float(u);
}
// integer-valued dequant core: clip(rint(x/s)+zp,0,255)-zp == clip(rint(x/s), -zp, 255-zp)
__device__ __forceinline__ float dqi(float x, float inv_s, float zp) {
    float y = rintf(x * inv_s);
    return fminf(fmaxf(y, -zp), 255.0f - zp);
}
__device__ __forceinline__ f32x4 mfma16(bf16x8 a, bf16x8 b, f32x4 c) {
    return __builtin_amdgcn_mfma_f32_16x16x32_bf16(a, b, c, 0, 0, 0);
}
__device__ __forceinline__ float exp2i(float x) {  // raw v_exp_f32 (2^x)
    float r;
    asm("v_exp_f32 %0, %1" : "=v"(r) : "v"(x));
    return r;
}
__device__ __forceinline__ void glds16(const __bf16* g, __bf16* l) {
    __builtin_amdgcn_global_load_lds((const __attribute__((address_space(1))) void*)g,
                                     (__attribute__((address_space(3))) void*)l, 16, 0, 0);
}
template <int N> __device__ __forceinline__ void waitv() {
    asm volatile("s_waitcnt vmcnt(%0)" :: "n"(N) : "memory");
}
__device__ __forceinline__ void bar_raw() {
    asm volatile("s_barrier" ::: "memory");
}

// ---------------- fused prep (weights fp32->bf16, mm init) + GroupNorm ----------------
__global__ __launch_bounds__(256) void gnprep(const float* __restrict__ x,
                                              const float* __restrict__ w,
                                              const float* __restrict__ bv,
                                              __bf16* __restrict__ hT,
                                              const float* __restrict__ qw,
                                              __bf16* __restrict__ wq,
                                              const float* __restrict__ pw,
                                              __bf16* __restrict__ wp,
                                              unsigned* __restrict__ mm) {
    int bid = blockIdx.x, tid = threadIdx.x;
    if (bid < 1024) {
        if (bid == 0 && tid < 3) { mm[2 * tid] = 0xFFFFFFFFu; mm[2 * tid + 1] = 0u; }
        if (bid < 768) {
            int i = bid * 256 + tid;
            float4 v = ((const float4*)qw)[i];
            bf16x4 o = {(__bf16)v.x, (__bf16)v.y, (__bf16)v.z, (__bf16)v.w};
            ((bf16x4*)wq)[i] = o;
        } else {
            int i = (bid - 768) * 256 + tid;
            float4 v = ((const float4*)pw)[i];
            bf16x4 o = {(__bf16)v.x, (__bf16)v.y, (__bf16)v.z, (__bf16)v.w};
            ((bf16x4*)wp)[i] = o;
        }
        return;
    }
    int blk = bid - 1024;
    int b = blk >> 5, g = blk & 31;
    const float* xp = x + (size_t)(b * 512 + g * 16) * 1024;

    float4 v[16];
    float sum = 0.f, ss = 0.f;
#pragma unroll
    for (int i = 0; i < 16; ++i) {
        v[i] = *(const float4*)(xp + (size_t)i * 1024 + tid * 4);
        sum += v[i].x + v[i].y + v[i].z + v[i].w;
        ss  += v[i].x * v[i].x + v[i].y * v[i].y + v[i].z * v[i].z + v[i].w * v[i].w;
    }
#pragma unroll
    for (int m = 1; m < 64; m <<= 1) {
        sum += __shfl_xor(sum, m);
        ss  += __shfl_xor(ss, m);
    }
    __shared__ float s1[4], s2[4];
    int wid = tid >> 6;
    if ((tid & 63) == 0) { s1[wid] = sum; s2[wid] = ss; }
    __syncthreads();
    sum = s1[0] + s1[1] + s1[2] + s1[3];
    ss  = s2[0] + s2[1] + s2[2] + s2[3];
    float mean = sum * (1.0f / 16384.0f);
    float var  = ss * (1.0f / 16384.0f) - mean * mean;
    float rstd = rsqrtf(var + 1e-5f);

    float wc[16], bc[16];
#pragma unroll
    for (int c = 0; c < 16; ++c) { wc[c] = w[g * 16 + c] * rstd; bc[c] = bv[g * 16 + c]; }

#pragma unroll
    for (int j = 0; j < 4; ++j) {
        int t = tid * 4 + j;
        bf16x8 o0, o1;
#pragma unroll
        for (int c = 0; c < 8; ++c)
            o0[c] = (__bf16)(((&v[c].x)[j] - mean) * wc[c] + bc[c]);
#pragma unroll
        for (int c = 0; c < 8; ++c)
            o1[c] = (__bf16)(((&v[c + 8].x)[j] - mean) * wc[c + 8] + bc[c + 8]);
        __bf16* hp = hT + ((size_t)b * 1024 + t) * 512 + g * 16;
        *(bf16x8*)hp = o0;
        *(bf16x8*)(hp + 8) = o1;
    }
}

// ---------------- MFMA GEMM v4: counted-vmcnt pipeline (T4), BK=32, 4 blocks/CU ----------------
// out[b][m][n] = sum_c A[m][c] * Bt[b][n][c] + bias[m] (+resid)(+minmax)
template <int MTILE, int MOT, bool MINMAX, bool RESID>
__global__ __launch_bounds__(256, 4) void mgemm4(const __bf16* __restrict__ A,   // [M][512]
                                                 const __bf16* __restrict__ Bt,  // [8][1024][512]
                                                 const float* __restrict__ bias,
                                                 const float* __restrict__ resid,
                                                 float* __restrict__ out,
                                                 int M, unsigned* __restrict__ mm) {
    constexpr int NF  = (MTILE == 128) ? 4 : 2;
    constexpr int ASZ = MTILE * 32;           // elems per A buffer
    constexpr int BSZ = 128 * 32;
    constexpr int LA  = MTILE / 64;           // A glds16 per thread per stage
    constexpr int L   = LA + 2;               // total loads per stage
    constexpr int STG = 2 * (ASZ + BSZ) * 2;  // bytes, both double buffers
    constexpr int CSB = 64 * 132 * 4;         // epilogue C-stage bytes
    __shared__ __attribute__((aligned(16))) char smem_raw[(STG > CSB) ? STG : CSB];
    __bf16* sA0 = (__bf16*)smem_raw;
    __bf16* sA1 = sA0 + ASZ;
    __bf16* sB0 = sA1 + ASZ;
    __bf16* sB1 = sB0 + BSZ;
    __shared__ float smn[4], smx[4];

    int tid = threadIdx.x;
    int l = tid & 63, w = tid >> 6;
    int lo = l & 15, hi = l >> 4;

    // XCD-chunked swizzle: consecutive wg within a chunk share (nt,b) -> B-panel L2-local
    int f = blockIdx.x;
    constexpr int NWG = MOT * 64;
    int wg = (f & 7) * (NWG / 8) + (f >> 3);
    int mo = wg % MOT, nb = wg / MOT;
    int nt = nb & 7, b = nb >> 3;

    const __bf16* Ap = A + (size_t)mo * MTILE * 512;
    const __bf16* Bp = Bt + ((size_t)b * 1024 + (size_t)nt * 128) * 512;
    int m0 = (MTILE == 128) ? (w >> 1) * 64 : 0;
    int n0 = (MTILE == 128) ? (w & 1) * 64 : w * 32;
    f32x4 acc[4][NF] = {};

    // staging: LDS[row][c] = G[row][(c ^ (row&3))*8 ..]; wave-linear LDS dest
    auto STAGE = [&](__bf16* dA, __bf16* dB, int k0) {
#pragma unroll
        for (int p = 0; p < LA; ++p) {
            int lin = p * 2048 + tid * 8;
            int row = lin >> 5;
            int sc = ((tid & 3) ^ (row & 3)) << 3;
            glds16(Ap + (size_t)row * 512 + k0 + sc, dA + lin);
        }
#pragma unroll
        for (int p = 0; p < 2; ++p) {
            int lin = p * 2048 + tid * 8;
            int row = lin >> 5;
            int sc = ((tid & 3) ^ (row & 3)) << 3;
            glds16(Bp + (size_t)row * 512 + k0 + sc, dB + lin);
        }
    };
    auto COMPUTE = [&](const __bf16* cA, const __bf16* cB) {
        int rcoff = (hi ^ (lo & 3)) << 3;   // row&3 == lo&3 for all frag rows
        bf16x8 af[4], bfr[NF];
#pragma unroll
        for (int i = 0; i < 4; ++i) af[i] = *(const bf16x8*)&cA[(m0 + 16 * i + lo) * 32 + rcoff];
#pragma unroll
        for (int j = 0; j < NF; ++j) bfr[j] = *(const bf16x8*)&cB[(n0 + 16 * j + lo) * 32 + rcoff];
#pragma unroll
        for (int i = 0; i < 4; ++i)
#pragma unroll
            for (int j = 0; j < NF; ++j) acc[i][j] = mfma16(af[i], bfr[j], acc[i][j]);
    };

    // counted-vmcnt pipeline: prefetch stays in flight across raw barriers (never drain mid-loop)
    STAGE(sA0, sB0, 0);
#pragma unroll
    for (int kp = 0; kp < 16; kp += 2) {
        if (kp + 1 < 16) { STAGE(sA1, sB1, (kp + 1) * 32); waitv<L>(); } else { waitv<0>(); }
        bar_raw();                 // buf0 ready for all waves
        COMPUTE(sA0, sB0);
        bar_raw();                 // all waves done reading buf0
        if (kp + 2 < 16) { STAGE(sA0, sB0, (kp + 2) * 32); waitv<L>(); } else { waitv<0>(); }
        bar_raw();
        COMPUTE(sA1, sB1);
        bar_raw();
    }

    // ---- epilogue: C through LDS, coalesced float4 stores ----
    float* cs = (float*)smem_raw;   // stride 132
    float mn = 1e30f, mx = -1e30f;
    constexpr int NH = (MTILE == 128) ? 2 : 1;
#pragma unroll
    for (int h = 0; h < NH; ++h) {
        __syncthreads();
        if (MTILE == 64 || (w >> 1) == h) {
#pragma unroll
            for (int i = 0; i < 4; ++i)
#pragma unroll
                for (int r = 0; r < 4; ++r) {
                    int rl = 16 * i + hi * 4 + r;
                    float bi = bias[mo * MTILE + h * 64 + rl];
#pragma unroll
                    for (int j = 0; j < NF; ++j)
                        cs[rl * 132 + n0 + 16 * j + lo] = acc[i][j][r] + bi;
                }
        }
        __syncthreads();
#pragma unroll
        for (int it = 0; it < 8; ++it) {
            int lin = it * 256 + tid;
            int rr = lin >> 5, cc = (lin & 31) << 2;
            float4 v = *(const float4*)&cs[rr * 132 + cc];
            if (MINMAX) {
                mn = fminf(mn, fminf(fminf(v.x, v.y), fminf(v.z, v.w)));
                mx = fmaxf(mx, fmaxf(fmaxf(v.x, v.y), fmaxf(v.z, v.w)));
            }
            int grow = mo * MTILE + h * 64 + rr;
            size_t gaddr = ((size_t)b * M + grow) * 1024 + nt * 128 + cc;
            if (RESID) {
                float4 rv = *(const float4*)&resid[gaddr];
                v.x += rv.x; v.y += rv.y; v.z += rv.z; v.w += rv.w;
            }
            *(float4*)&out[gaddr] = v;
        }
    }

    if (MINMAX) {
#pragma unroll
        for (int msk = 1; msk < 64; msk <<= 1) {
            mn = fminf(mn, __shfl_xor(mn, msk));
            mx = fmaxf(mx, __shfl_xor(mx, msk));
        }
        if (l == 0) { smn[w] = mn; smx[w] = mx; }
        __syncthreads();
        if (tid == 0) {
            mn = fminf(fminf(smn[0], smn[1]), fminf(smn[2], smn[3]));
            mx = fmaxf(fmaxf(smx[0], smx[1]), fmaxf(smx[2], smx[3]));
            int id = mo >> 2;  // 4 x 128-row tiles per tensor (q,k,v)
            atomicMin(&mm[2 * id], encf(mn));
            atomicMax(&mm[2 * id + 1], encf(mx));
        }
    }
}

// ---------------- quant Q/K/V pass ----------------
// grid (64 bh, 16 tile); integer-valued bf16: qi (bh,t,c), ki (bh,s,c), vi (bh,c,s)
__global__ __launch_bounds__(256) void quant_qkv(const float* __restrict__ qkv,
                                                 const unsigned* __restrict__ mm,
                                                 __bf16* __restrict__ qi,
                                                 __bf16* __restrict__ ki,
                                                 __bf16* __restrict__ vi) {
    int bh = blockIdx.x, tt = blockIdx.y;
    int b = bh >> 3, hh = bh & 7;
    int t0 = tt * 64;
    const float* qg = qkv + (size_t)(b * 1536 + hh * 192) * 1024;
    const float* kg = qg + 65536;
    const float* vg = qg + 131072;

    float mn0 = fminf(decf(mm[0]), 0.f), mx0 = fmaxf(decf(mm[1]), 0.f);
    float qsc = fmaxf((mx0 - mn0) * (1.f / 255.f), 1e-8f), qzp = rintf(-mn0 / qsc);
    float mn1 = fminf(decf(mm[2]), 0.f), mx1 = fmaxf(decf(mm[3]), 0.f);
    float ksc = fmaxf((mx1 - mn1) * (1.f / 255.f), 1e-8f), kzp = rintf(-mn1 / ksc);
    float mn2 = fminf(decf(mm[4]), 0.f), mx2 = fmaxf(decf(mm[5]), 0.f);
    float vsc = fmaxf((mx2 - mn2) * (1.f / 255.f), 1e-8f), vzp = rintf(-mn2 / vsc);
    float inv_q = 1.f / qsc, inv_k = 1.f / ksc, inv_v = 1.f / vsc;

    __shared__ __bf16 sT[64][68];
    int tid = threadIdx.x;
    int cr = tid >> 4, t4 = tid & 15;
    int s = tid >> 2, c0 = (tid & 3) * 16;

    // V stream
    __bf16* vd = vi + (size_t)bh * 65536;
#pragma unroll
    for (int r = 0; r < 4; ++r) {
        int c = 16 * r + cr;
        float4 v = *(const float4*)(vg + (size_t)c * 1024 + t0 + t4 * 4);
        bf16x4 o = {(__bf16)dqi(v.x, inv_v, vzp), (__bf16)dqi(v.y, inv_v, vzp),
                    (__bf16)dqi(v.z, inv_v, vzp), (__bf16)dqi(v.w, inv_v, vzp)};
        *(bf16x4*)(vd + (size_t)c * 1024 + t0 + t4 * 4) = o;
    }

    // K transpose -> (s, c)
#pragma unroll
    for (int r = 0; r < 4; ++r) {
        int c = 16 * r + cr;
        float4 v = *(const float4*)(kg + (size_t)c * 1024 + t0 + t4 * 4);
        sT[t4 * 4 + 0][c] = (__bf16)dqi(v.x, inv_k, kzp);
        sT[t4 * 4 + 1][c] = (__bf16)dqi(v.y, inv_k, kzp);
        sT[t4 * 4 + 2][c] = (__bf16)dqi(v.z, inv_k, kzp);
        sT[t4 * 4 + 3][c] = (__bf16)dqi(v.w, inv_k, kzp);
    }
    __syncthreads();
    {
        bf16x8 a0 = *(const bf16x8*)&sT[s][c0];
        bf16x8 a1 = *(const bf16x8*)&sT[s][c0 + 8];
        __bf16* kd = ki + ((size_t)bh * 1024 + t0 + s) * 64 + c0;
        *(bf16x8*)kd = a0;
        *(bf16x8*)(kd + 8) = a1;
    }
    __syncthreads();

    // Q transpose -> (t, c)
#pragma unroll
    for (int r = 0; r < 4; ++r) {
        int c = 16 * r + cr;
        float4 v = *(const float4*)(qg + (size_t)c * 1024 + t0 + t4 * 4);
        sT[t4 * 4 + 0][c] = (__bf16)dqi(v.x, inv_q, qzp);
        sT[t4 * 4 + 1][c] = (__bf16)dqi(v.y, inv_q, qzp);
        sT[t4 * 4 + 2][c] = (__bf16)dqi(v.z, inv_q, qzp);
        sT[t4 * 4 + 3][c] = (__bf16)dqi(v.w, inv_q, qzp);
    }
    __syncthreads();
    {
        bf16x8 a0 = *(const bf16x8*)&sT[s][c0];
        bf16x8 a1 = *(const bf16x8*)&sT[s][c0 + 8];
        __bf16* qd = qi + ((size_t)bh * 1024 + t0 + s) * 64 + c0;
        *(bf16x8*)qd = a0;
        *(bf16x8*)(qd + 8) = a1;
    }
}

// ---------------- attention v5: all-bf16 inputs, LDS K/V, exp2 softmax, defer-max ----------------
__global__ __launch_bounds__(256) void attn4(const __bf16* __restrict__ qi,
                                             const __bf16* __restrict__ ki,
                                             const __bf16* __restrict__ vi,
                                             const unsigned* __restrict__ mm,
                                             __bf16* __restrict__ aT) {
    int f = blockIdx.x;
    int bh = (f & 7) * 8 + ((f >> 3) & 7);  // 8 heads x 16 t-tiles per XCD
    int tt = f >> 6;
    int b = bh >> 3, hh = bh & 7;
    int t0 = tt * 64;
    const __bf16* kb = ki + (size_t)bh * 65536;
    const __bf16* vb = vi + (size_t)bh * 65536;

    float mn0 = fminf(decf(mm[0]), 0.f), mx0 = fmaxf(decf(mm[1]), 0.f);
    float qsc = fmaxf((mx0 - mn0) * (1.f / 255.f), 1e-8f);
    float mn1 = fminf(decf(mm[2]), 0.f), mx1 = fmaxf(decf(mm[3]), 0.f);
    float ksc = fmaxf((mx1 - mn1) * (1.f / 255.f), 1e-8f);
    float mn2 = fminf(decf(mm[4]), 0.f), mx2 = fmaxf(decf(mm[5]), 0.f);
    float vsc = fmaxf((mx2 - mn2) * (1.f / 255.f), 1e-8f);
    float alpha2 = qsc * ksc * 0.125f * 1.4426950408889634f;  // alpha * log2(e)
    float thr = 11.5415603f / alpha2;                          // 8 nats in raw-score units

    __shared__ __bf16 sh[64][72];    // per-wave P -> output stage
    __shared__ __bf16 kS[64 * 64];   // K tile (s,c), chunk-swizzled
    __shared__ __bf16 vS[64 * 64];   // V tile (c,s), chunk-swizzled
    int tid = threadIdx.x;
    int l = tid & 63, w = tid >> 6;
    int lo = l & 15, hi = l >> 4;

    // q frags straight from qi (integer-valued, pre-transposed)
    const __bf16* qrow = qi + ((size_t)bh * 1024 + t0 + 16 * w + lo) * 64;
    bf16x8 qf0 = *(const bf16x8*)(qrow + hi * 8);
    bf16x8 qf1 = *(const bf16x8*)(qrow + 32 + hi * 8);

    // staging geometry: thread -> row (0..63), two 16B chunks
    int srow = tid >> 2, sc2 = (tid & 3) * 2;
    int swz0 = (sc2 ^ (srow & 7)) << 3;
    int swz1 = ((sc2 + 1) ^ (srow & 7)) << 3;
    const __bf16* kROW = kb + (size_t)srow * 64;          // + st*4096
    const __bf16* vROW = vb + (size_t)srow * 1024;        // + st*64
    int lx = lo & 7;
    int rc0 = (hi ^ lx) << 3;          // kk=0 chunk
    int rc1 = ((4 + hi) ^ lx) << 3;    // kk=1 chunk

    // prefetch tile 0
    bf16x8 kr0 = *(const bf16x8*)(kROW + sc2 * 8);
    bf16x8 kr1 = *(const bf16x8*)(kROW + sc2 * 8 + 8);
    bf16x8 vr0 = *(const bf16x8*)(vROW + sc2 * 8);
    bf16x8 vr1 = *(const bf16x8*)(vROW + sc2 * 8 + 8);

    f32x4 acc0 = {}, acc1 = {}, acc2 = {}, acc3 = {};
    float m_run = -1e30f, l_run = 0.f;

    for (int st = 0; st < 16; ++st) {
        __syncthreads();   // previous tile's LDS reads done
        *(bf16x8*)(kS + srow * 64 + swz0) = kr0;
        *(bf16x8*)(kS + srow * 64 + swz1) = kr1;
        *(bf16x8*)(vS + srow * 64 + swz0) = vr0;
        *(bf16x8*)(vS + srow * 64 + swz1) = vr1;
        __syncthreads();   // tile staged
        if (st < 15) {     // prefetch next tile during compute
            kr0 = *(const bf16x8*)(kROW + (st + 1) * 4096 + sc2 * 8);
            kr1 = *(const bf16x8*)(kROW + (st + 1) * 4096 + sc2 * 8 + 8);
            vr0 = *(const bf16x8*)(vROW + (st + 1) * 64 + sc2 * 8);
            vr1 = *(const bf16x8*)(vROW + (st + 1) * 64 + sc2 * 8 + 8);
        }

        // scores: D[s][t] = K·Q (raw integer dot products)
        f32x4 sf[4] = {};
        __builtin_amdgcn_s_setprio(1);
#pragma unroll
        for (int sm = 0; sm < 4; ++sm)
            sf[sm] = mfma16(*(const bf16x8*)(kS + (16 * sm + lo) * 64 + rc0), qf0, sf[sm]);
#pragma unroll
        for (int sm = 0; sm < 4; ++sm)
            sf[sm] = mfma16(*(const bf16x8*)(kS + (16 * sm + lo) * 64 + rc1), qf1, sf[sm]);
        __builtin_amdgcn_s_setprio(0);

        // online softmax in exp2 space (t = lane-local)
        float tm = -1e30f;
#pragma unroll
        for (int sm = 0; sm < 4; ++sm) {
            float a = fmaxf(sf[sm][0], sf[sm][1]);
            float c = fmaxf(sf[sm][2], sf[sm][3]);
            tm = fmaxf(tm, fmaxf(a, c));
        }
        tm = fmaxf(tm, __shfl_xor(tm, 16));
        tm = fmaxf(tm, __shfl_xor(tm, 32));
        if (!__all(tm <= m_run + thr)) {   // defer-max
            float mnew = fmaxf(m_run, tm);
            float fr = exp2i(alpha2 * (m_run - mnew));
            acc0 *= fr; acc1 *= fr; acc2 *= fr; acc3 *= fr;
            l_run *= fr;
            m_run = mnew;
        }
        float cc = -alpha2 * m_run;
        float ts = 0.f;
#pragma unroll
        for (int sm = 0; sm < 4; ++sm)
#pragma unroll
            for (int r = 0; r < 4; ++r) {
                float p = exp2i(fmaf(sf[sm][r], alpha2, cc));
                sf[sm][r] = p;
                ts += p;
            }
        ts += __shfl_xor(ts, 16);
        ts += __shfl_xor(ts, 32);
        l_run += ts;

        // P -> LDS (wave-private rows)
#pragma unroll
        for (int sm = 0; sm < 4; ++sm) {
            bf16x4 pb = {(__bf16)sf[sm][0], (__bf16)sf[sm][1], (__bf16)sf[sm][2], (__bf16)sf[sm][3]};
            *(bf16x4*)&sh[16 * w + lo][16 * sm + hi * 4] = pb;
        }
        bf16x8 pf0 = *(const bf16x8*)&sh[16 * w + lo][hi * 8];
        bf16x8 pf1 = *(const bf16x8*)&sh[16 * w + lo][32 + hi * 8];

        // PV: D[c][t] += V·P
        __builtin_amdgcn_s_setprio(1);
        acc0 = mfma16(*(const bf16x8*)(vS + (lo) * 64 + rc0), pf0, acc0);
        acc1 = mfma16(*(const bf16x8*)(vS + (16 + lo) * 64 + rc0), pf0, acc1);
        acc2 = mfma16(*(const bf16x8*)(vS + (32 + lo) * 64 + rc0), pf0, acc2);
        acc3 = mfma16(*(const bf16x8*)(vS + (48 + lo) * 64 + rc0), pf0, acc3);
        acc0 = mfma16(*(const bf16x8*)(vS + (lo) * 64 + rc1), pf1, acc0);
        acc1 = mfma16(*(const bf16x8*)(vS + (16 + lo) * 64 + rc1), pf1, acc1);
        acc2 = mfma16(*(const bf16x8*)(vS + (32 + lo) * 64 + rc1), pf1, acc2);
        acc3 = mfma16(*(const bf16x8*)(vS + (48 + lo) * 64 + rc1), pf1, acc3);
        __builtin_amdgcn_s_setprio(0);
    }

    float rl = vsc / l_run;
    __syncthreads();
    {
        bf16x4 o0 = {(__bf16)(acc0[0] * rl), (__bf16)(acc0[1] * rl), (__bf16)(acc0[2] * rl), (__bf16)(acc0[3] * rl)};
        bf16x4 o1 = {(__bf16)(acc1[0] * rl), (__bf16)(acc1[1] * rl), (__bf16)(acc1[2] * rl), (__bf16)(acc1[3] * rl)};
        bf16x4 o2 = {(__bf16)(acc2[0] * rl), (__bf16)(acc2[1] * rl), (__bf16)(acc2[2] * rl), (__bf16)(acc2[3] * rl)};
        bf16x4 o3 = {(__bf16)(acc3[0] * rl), (__bf16)(acc3[1] * rl), (__bf16)(acc3[2] * rl), (__bf16)(acc3[3] * rl)};
        *(bf16x4*)&sh[16 * w + lo][0  + hi * 4] = o0;
        *(bf16x4*)&sh[16 * w + lo][16 + hi * 4] = o1;
        *(bf16x4*)&sh[16 * w + lo][32 + hi * 4] = o2;
        *(bf16x4*)&sh[16 * w + lo][48 + hi * 4] = o3;
    }
    __syncthreads();
    __bf16* ap = aT + ((size_t)b * 1024 + t0 + (tid >> 2)) * 512 + hh * 64;
    bf16x8 v0 = *(const bf16x8*)&sh[tid >> 2][(tid & 3) * 8];
    bf16x8 v1 = *(const bf16x8*)&sh[tid >> 2][32 + (tid & 3) * 8];
    *(bf16x8*)(ap + (tid & 3) * 8) = v0;
    *(bf16x8*)(ap + 32 + (tid & 3) * 8) = v1;
}

// ---------------- fallback attention (fp32 qkv, used if ws too small) ----------------
__global__ __launch_bounds__(256) void attn_mfma(const float* __restrict__ qkv,
                                                 const unsigned* __restrict__ mm,
                                                 __bf16* __restrict__ aT) {
    int f = blockIdx.x;
    int bh = (f & 7) * 8 + ((f >> 3) & 7);
    int tt = f >> 6;
    int b = bh >> 3, hh = bh & 7;
    int t0 = tt * 64;
    const float* qg = qkv + (size_t)(b * 1536 + hh * 192) * 1024;
    const float* kg = qg + (size_t)64 * 1024;
    const float* vg = qg + (size_t)128 * 1024;

    float mn0 = fminf(decf(mm[0]), 0.f), mx0 = fmaxf(decf(mm[1]), 0.f);
    float qsc = fmaxf((mx0 - mn0) * (1.f / 255.f), 1e-8f), qzp = rintf(-mn0 / qsc);
    float mn1 = fminf(decf(mm[2]), 0.f), mx1 = fmaxf(decf(mm[3]), 0.f);
    float ksc = fmaxf((mx1 - mn1) * (1.f / 255.f), 1e-8f), kzp = rintf(-mn1 / ksc);
    float mn2 = fminf(decf(mm[4]), 0.f), mx2 = fmaxf(decf(mm[5]), 0.f);
    float vsc = fmaxf((mx2 - mn2) * (1.f / 255.f), 1e-8f), vzp = rintf(-mn2 / vsc);
    float inv_q = 1.f / qsc, inv_k = 1.f / ksc, inv_v = 1.f / vsc;
    float alpha = qsc * ksc * 0.125f;

    __shared__ __bf16 qT[64][72];
    __shared__ __bf16 kT[64][72];
    __shared__ __bf16 vL[64][72];
    __shared__ __bf16 pL[4][16][72];

    int tid = threadIdx.x;
    int l = tid & 63, w = tid >> 6;
    int lo = l & 15, hi = l >> 4;
    int c0 = (tid >> 4) * 4;
    int tl = tid & 15;

#pragma unroll
    for (int r = 0; r < 4; ++r) {
        int t = tl + 16 * r;
        float y0 = dqi(qg[(size_t)(c0 + 0) * 1024 + t0 + t], inv_q, qzp);
        float y1 = dqi(qg[(size_t)(c0 + 1) * 1024 + t0 + t], inv_q, qzp);
        float y2 = dqi(qg[(size_t)(c0 + 2) * 1024 + t0 + t], inv_q, qzp);
        float y3 = dqi(qg[(size_t)(c0 + 3) * 1024 + t0 + t], inv_q, qzp);
        bf16x4 o = {(__bf16)y0, (__bf16)y1, (__bf16)y2, (__bf16)y3};
        *(bf16x4*)&qT[t][c0] = o;
    }
    __syncthreads();
    bf16x8 qf0 = *(const bf16x8*)&qT[16 * w + lo][hi * 8];
    bf16x8 qf1 = *(const bf16x8*)&qT[16 * w + lo][32 + hi * 8];

    f32x4 acc0 = {}, acc1 = {}, acc2 = {}, acc3 = {};
    float m_run = -1e30f, l_run = 0.f;

    for (int st = 0; st < 16; ++st) {
        int s0 = st * 64;
        __syncthreads();
#pragma unroll
        for (int r = 0; r < 4; ++r) {
            int srow = tl + 16 * r;
            float y0 = dqi(kg[(size_t)(c0 + 0) * 1024 + s0 + srow], inv_k, kzp);
            float y1 = dqi(kg[(size_t)(c0 + 1) * 1024 + s0 + srow], inv_k, kzp);
            float y2 = dqi(kg[(size_t)(c0 + 2) * 1024 + s0 + srow], inv_k, kzp);
            float y3 = dqi(kg[(size_t)(c0 + 3) * 1024 + s0 + srow], inv_k, kzp);
            bf16x4 ok = {(__bf16)y0, (__bf16)y1, (__bf16)y2, (__bf16)y3};
            *(bf16x4*)&kT[srow][c0] = ok;
            int c = (tid >> 4) + 16 * r;
            float4 vv = *(const float4*)(vg + (size_t)c * 1024 + s0 + (tid & 15) * 4);
            bf16x4 ov = {(__bf16)dqi(vv.x, inv_v, vzp), (__bf16)dqi(vv.y, inv_v, vzp),
                         (__bf16)dqi(vv.z, inv_v, vzp), (__bf16)dqi(vv.w, inv_v, vzp)};
            *(bf16x4*)&vL[c][(tid & 15) * 4] = ov;
        }
        __syncthreads();

        f32x4 sf[4] = {};
#pragma unroll
        for (int sm = 0; sm < 4; ++sm)
            sf[sm] = mfma16(*(const bf16x8*)&kT[16 * sm + lo][hi * 8], qf0, sf[sm]);
#pragma unroll
        for (int sm = 0; sm < 4; ++sm)
            sf[sm] = mfma16(*(const bf16x8*)&kT[16 * sm + lo][32 + hi * 8], qf1, sf[sm]);

        float tm = -1e30f;
#pragma unroll
        for (int sm = 0; sm < 4; ++sm)
#pragma unroll
            for (int r = 0; r < 4; ++r) { sf[sm][r] *= alpha; tm = fmaxf(tm, sf[sm][r]); }
        tm = fmaxf(tm, __shfl_xor(tm, 16));
        tm = fmaxf(tm, __shfl_xor(tm, 32));
        float mnew = fmaxf(m_run, tm);
        float ts = 0.f;
#pragma unroll
        for (int sm = 0; sm < 4; ++sm)
#pragma unroll
            for (int r = 0; r < 4; ++r) {
                float p = __expf(sf[sm][r] - mnew);
                sf[sm][r] = p;
                ts += p;
            }
        ts += __shfl_xor(ts, 16);
        ts += __shfl_xor(ts, 32);
        float fr = __expf(m_run - mnew);
        l_run = l_run * fr + ts;
        m_run = mnew;
        acc0 *= fr; acc1 *= fr; acc2 *= fr; acc3 *= fr;

#pragma unroll
        for (int sm = 0; sm < 4; ++sm) {
            bf16x4 pb = {(__bf16)sf[sm][0], (__bf16)sf[sm][1], (__bf16)sf[sm][2], (__bf16)sf[sm][3]};
            *(bf16x4*)&pL[w][lo][16 * sm + hi * 4] = pb;
        }
        bf16x8 pf0 = *(const bf16x8*)&pL[w][lo][hi * 8];
        bf16x8 pf1 = *(const bf16x8*)&pL[w][lo][32 + hi * 8];
        acc0 = mfma16(*(const bf16x8*)&vL[lo][hi * 8], pf0, acc0);
        acc1 = mfma16(*(const bf16x8*)&vL[16 + lo][hi * 8], pf0, acc1);
        acc2 = mfma16(*(const bf16x8*)&vL[32 + lo][hi * 8], pf0, acc2);
        acc3 = mfma16(*(const bf16x8*)&vL[48 + lo][hi * 8], pf0, acc3);
        acc0 = mfma16(*(const bf16x8*)&vL[lo][32 + hi * 8], pf1, acc0);
        acc1 = mfma16(*(const bf16x8*)&vL[16 + lo][32 + hi * 8], pf1, acc1);
        acc2 = mfma16(*(const bf16x8*)&vL[32 + lo][32 + hi * 8], pf1, acc2);
        acc3 = mfma16(*(const bf16x8*)&vL[48 + lo][32 + hi * 8], pf1, acc3);
    }

    float rl = vsc / l_run;
    __syncthreads();
    {
        bf16x4 o0 = {(__bf16)(acc0[0] * rl), (__bf16)(acc0[1] * rl), (__bf16)(acc0[2] * rl), (__bf16)(acc0[3] * rl)};
        bf16x4 o1 = {(__bf16)(acc1[0] * rl), (__bf16)(acc1[1] * rl), (__bf16)(acc1[2] * rl), (__bf16)(acc1[3] * rl)};
        bf16x4 o2 = {(__bf16)(acc2[0] * rl), (__bf16)(acc2[1] * rl), (__bf16)(acc2[2] * rl), (__bf16)(acc2[3] * rl)};
        bf16x4 o3 = {(__bf16)(acc3[0] * rl), (__bf16)(acc3[1] * rl), (__bf16)(acc3[2] * rl), (__bf16)(acc3[3] * rl)};
        *(bf16x4*)&qT[16 * w + lo][0  + hi * 4] = o0;
        *(bf16x4*)&qT[16 * w + lo][16 + hi * 4] = o1;
        *(bf16x4*)&qT[16 * w + lo][32 + hi * 4] = o2;
        *(bf16x4*)&qT[16 * w + lo][48 + hi * 4] = o3;
    }
    __syncthreads();
    __bf16* ap = aT + ((size_t)b * 1024 + t0 + (tid >> 2)) * 512 + hh * 64;
    bf16x8 v0 = *(const bf16x8*)&qT[tid >> 2][(tid & 3) * 8];
    bf16x8 v1 = *(const bf16x8*)&qT[tid >> 2][32 + (tid & 3) * 8];
    *(bf16x8*)(ap + (tid & 3) * 8) = v0;
    *(bf16x8*)(ap + 32 + (tid & 3) * 8) = v1;
}

extern "C" void kernel_launch(void* const* d_in, const int* in_sizes, int n_in,
                              void* d_out, int out_size, void* d_ws, size_t ws_size,
                              hipStream_t stream) {
    const float* x      = (const float*)d_in[0];
    const float* gn_w   = (const float*)d_in[1];
    const float* gn_b   = (const float*)d_in[2];
    const float* qkv_w  = (const float*)d_in[3];
    const float* qkv_b  = (const float*)d_in[4];
    const float* proj_w = (const float*)d_in[5];
    const float* proj_b = (const float*)d_in[6];
    char* ws = (char*)d_ws;
    float*    qkv = (float*)(ws + QKV_OFF);
    __bf16*   hT  = (__bf16*)(ws + HT_OFF);   // hT, later reused as aT
    __bf16*   wq  = (__bf16*)(ws + WQ_OFF);
    __bf16*   wp  = (__bf16*)(ws + WP_OFF);
    unsigned* mm  = (unsigned*)(ws + MM_OFF);
    __bf16*   ki  = (__bf16*)(ws + KI_OFF);
    __bf16*   vi  = (__bf16*)(ws + VI_OFF);
    __bf16*   qi  = (__bf16*)(ws + QI_OFF);
    float* out = (float*)d_out;

    gnprep<<<1280, 256, 0, stream>>>(x, gn_w, gn_b, hT, qkv_w, wq, proj_w, wp, mm);
    mgemm4<128, 12, true, false><<<768, 256, 0, stream>>>(wq, hT, qkv_b, nullptr, qkv, 1536, mm);
    if (ws_size >= NEED_NEW) {
        quant_qkv<<<dim3(64, 16), 256, 0, stream>>>(qkv, mm, qi, ki, vi);
        attn4<<<1024, 256, 0, stream>>>(qi, ki, vi, mm, hT);
    } else {
        attn_mfma<<<1024, 256, 0, stream>>>(qkv, mm, hT);
    }
    mgemm4<64, 8, false, true><<<512, 256, 0, stream>>>(wp, hT, proj_b, x, out, 512, nullptr);
}

// Round 8
// 104.806 us; speedup vs baseline: 1.8714x; 1.0135x over previous
//
#include <hip/hip_runtime.h>

typedef __attribute__((ext_vector_type(8))) __bf16 bf16x8;
typedef __attribute__((ext_vector_type(4))) __bf16 bf16x4;
typedef __attribute__((ext_vector_type(4))) float  f32x4;

// Problem: x (8,512,32,32) fp32 -> B=8, C=512, T=1024; 32 groups; 8 heads (ch=64)

// ws layout (bytes)
static constexpr size_t QKV_OFF = 0;                     // fp32 (8,1536,1024) 48MB
static constexpr size_t HT_OFF  = 50331648;              // bf16 (8,1024,512) 8MB: hT then aT
static constexpr size_t WQ_OFF  = HT_OFF + 8388608;      // bf16 (1536,512)
static constexpr size_t WP_OFF  = WQ_OFF + 1572864;      // bf16 (512,512)
static constexpr size_t MM_OFF  = WP_OFF + 524288;       // pmm partials: 3*256*2 f32 (8KB slot)
static constexpr size_t KI_OFF  = MM_OFF + 8192;         // bf16 (64,1024,64) 8MB
static constexpr size_t VI_OFF  = KI_OFF + 8388608;      // bf16 (64,64,1024) 8MB
static constexpr size_t QI_OFF  = VI_OFF + 8388608;      // bf16 (64,1024,64) 8MB
static constexpr size_t NEED_NEW = QI_OFF + 8388608;

// integer-valued dequant core: clip(rint(x/s)+zp,0,255)-zp == clip(rint(x/s), -zp, 255-zp)
__device__ __forceinline__ float dqi(float x, float inv_s, float zp) {
    float y = rintf(x * inv_s);
    return fminf(fmaxf(y, -zp), 255.0f - zp);
}
__device__ __forceinline__ f32x4 mfma16(bf16x8 a, bf16x8 b, f32x4 c) {
    return __builtin_amdgcn_mfma_f32_16x16x32_bf16(a, b, c, 0, 0, 0);
}
__device__ __forceinline__ float exp2i(float x) {  // raw v_exp_f32 (2^x)
    float r;
    asm("v_exp_f32 %0, %1" : "=v"(r) : "v"(x));
    return r;
}
__device__ __forceinline__ void glds16(const __bf16* g, __bf16* l) {
    __builtin_amdgcn_global_load_lds((const __attribute__((address_space(1))) void*)g,
                                     (__attribute__((address_space(3))) void*)l, 16, 0, 0);
}
template <int N> __device__ __forceinline__ void waitv() {
    asm volatile("s_waitcnt vmcnt(%0)" :: "n"(N) : "memory");
}
__device__ __forceinline__ void bar_raw() {
    asm volatile("s_barrier" ::: "memory");
}

// reduce pmm[id][256][2] partials -> (mn, mx) for one tensor id. Needs 256 threads.
// sred: >=8 floats of shared. Leaves sred reusable after the trailing syncthreads.
__device__ __forceinline__ void red_mm(const float* __restrict__ pmm, int id, int tid,
                                       float* sred, float& mn_out, float& mx_out) {
    float mn = pmm[id * 512 + tid * 2];
    float mx = pmm[id * 512 + tid * 2 + 1];
#pragma unroll
    for (int m = 1; m < 64; m <<= 1) {
        mn = fminf(mn, __shfl_xor(mn, m));
        mx = fmaxf(mx, __shfl_xor(mx, m));
    }
    if ((tid & 63) == 0) { sred[(tid >> 6) * 2] = mn; sred[(tid >> 6) * 2 + 1] = mx; }
    __syncthreads();
    mn = fminf(fminf(sred[0], sred[2]), fminf(sred[4], sred[6]));
    mx = fmaxf(fmaxf(sred[1], sred[3]), fmaxf(sred[5], sred[7]));
    __syncthreads();
    mn_out = fminf(mn, 0.0f);
    mx_out = fmaxf(mx, 0.0f);
}

// ---------------- fused prep (weights fp32->bf16) + GroupNorm ----------------
__global__ __launch_bounds__(256) void gnprep(const float* __restrict__ x,
                                              const float* __restrict__ w,
                                              const float* __restrict__ bv,
                                              __bf16* __restrict__ hT,
                                              const float* __restrict__ qw,
                                              __bf16* __restrict__ wq,
                                              const float* __restrict__ pw,
                                              __bf16* __restrict__ wp) {
    int bid = blockIdx.x, tid = threadIdx.x;
    if (bid < 1024) {
        if (bid < 768) {
            int i = bid * 256 + tid;
            float4 v = ((const float4*)qw)[i];
            bf16x4 o = {(__bf16)v.x, (__bf16)v.y, (__bf16)v.z, (__bf16)v.w};
            ((bf16x4*)wq)[i] = o;
        } else {
            int i = (bid - 768) * 256 + tid;
            float4 v = ((const float4*)pw)[i];
            bf16x4 o = {(__bf16)v.x, (__bf16)v.y, (__bf16)v.z, (__bf16)v.w};
            ((bf16x4*)wp)[i] = o;
        }
        return;
    }
    int blk = bid - 1024;
    int b = blk >> 5, g = blk & 31;
    const float* xp = x + (size_t)(b * 512 + g * 16) * 1024;

    float4 v[16];
    float sum = 0.f, ss = 0.f;
#pragma unroll
    for (int i = 0; i < 16; ++i) {
        v[i] = *(const float4*)(xp + (size_t)i * 1024 + tid * 4);
        sum += v[i].x + v[i].y + v[i].z + v[i].w;
        ss  += v[i].x * v[i].x + v[i].y * v[i].y + v[i].z * v[i].z + v[i].w * v[i].w;
    }
#pragma unroll
    for (int m = 1; m < 64; m <<= 1) {
        sum += __shfl_xor(sum, m);
        ss  += __shfl_xor(ss, m);
    }
    __shared__ float s1[4], s2[4];
    int wid = tid >> 6;
    if ((tid & 63) == 0) { s1[wid] = sum; s2[wid] = ss; }
    __syncthreads();
    sum = s1[0] + s1[1] + s1[2] + s1[3];
    ss  = s2[0] + s2[1] + s2[2] + s2[3];
    float mean = sum * (1.0f / 16384.0f);
    float var  = ss * (1.0f / 16384.0f) - mean * mean;
    float rstd = rsqrtf(var + 1e-5f);

    float wc[16], bc[16];
#pragma unroll
    for (int c = 0; c < 16; ++c) { wc[c] = w[g * 16 + c] * rstd; bc[c] = bv[g * 16 + c]; }

#pragma unroll
    for (int j = 0; j < 4; ++j) {
        int t = tid * 4 + j;
        bf16x8 o0, o1;
#pragma unroll
        for (int c = 0; c < 8; ++c)
            o0[c] = (__bf16)(((&v[c].x)[j] - mean) * wc[c] + bc[c]);
#pragma unroll
        for (int c = 0; c < 8; ++c)
            o1[c] = (__bf16)(((&v[c + 8].x)[j] - mean) * wc[c + 8] + bc[c + 8]);
        __bf16* hp = hT + ((size_t)b * 1024 + t) * 512 + g * 16;
        *(bf16x8*)hp = o0;
        *(bf16x8*)(hp + 8) = o1;
    }
}

// ---------------- MFMA GEMM v5: BK=64 conflict-free swizzle + counted-vmcnt dbuf, NO atomics ----------------
// out[b][m][n] = sum_c A[m][c] * Bt[b][n][c] + bias[m] (+resid)(+partial minmax to pmm)
template <int MTILE, int MOT, bool MINMAX, bool RESID>
__global__ __launch_bounds__(256, 2) void mgemm5(const __bf16* __restrict__ A,   // [M][512]
                                                 const __bf16* __restrict__ Bt,  // [8][1024][512]
                                                 const float* __restrict__ bias,
                                                 const float* __restrict__ resid,
                                                 float* __restrict__ out,
                                                 int M, float* __restrict__ pmm) {
    constexpr int NF  = (MTILE == 128) ? 4 : 2;
    constexpr int ASZ = MTILE * 64;           // elems per A buffer
    constexpr int BSZ = 128 * 64;
    constexpr int LA  = MTILE / 32;           // A glds16 per thread per stage
    constexpr int L   = LA + 4;               // loads per stage (per-thread vmcnt)
    constexpr int STG = 2 * (ASZ + BSZ) * 2;  // bytes, both double buffers
    constexpr int CSB = 64 * 132 * 4;         // epilogue C-stage bytes
    __shared__ __attribute__((aligned(16))) char smem_raw[(STG > CSB) ? STG : CSB];
    __bf16* sA0 = (__bf16*)smem_raw;
    __bf16* sA1 = sA0 + ASZ;
    __bf16* sB0 = sA1 + ASZ;
    __bf16* sB1 = sB0 + BSZ;
    __shared__ float smn[4], smx[4];

    int tid = threadIdx.x;
    int l = tid & 63, w = tid >> 6;
    int lo = l & 15, hi = l >> 4;

    // XCD-chunked swizzle: consecutive wg within a chunk share (nt,b) -> B-panel L2-local
    int f = blockIdx.x;
    constexpr int NWG = MOT * 64;
    int wg = (f & 7) * (NWG / 8) + (f >> 3);
    int mo = wg % MOT, nb = wg / MOT;
    int nt = nb & 7, b = nb >> 3;

    const __bf16* Ap = A + (size_t)mo * MTILE * 512;
    const __bf16* Bp = Bt + ((size_t)b * 1024 + (size_t)nt * 128) * 512;
    int m0 = (MTILE == 128) ? (w >> 1) * 64 : 0;
    int n0 = (MTILE == 128) ? (w & 1) * 64 : w * 32;
    f32x4 acc[4][NF] = {};
    int scd = tid & 7;

    // staging: LDS[row][cd] = G[row][cd ^ (row&7) chunks]; wave-linear LDS dest (128B rows)
    auto STAGE = [&](__bf16* dA, __bf16* dB, int k0) {
#pragma unroll
        for (int p = 0; p < LA; ++p) {
            int lin = p * 2048 + tid * 8;
            int row = lin >> 6;
            glds16(Ap + (size_t)row * 512 + k0 + ((scd ^ (row & 7)) << 3), dA + lin);
        }
#pragma unroll
        for (int p = 0; p < 4; ++p) {
            int lin = p * 2048 + tid * 8;
            int row = lin >> 6;
            glds16(Bp + (size_t)row * 512 + k0 + ((scd ^ (row & 7)) << 3), dB + lin);
        }
    };
    auto COMPUTE = [&](const __bf16* cA, const __bf16* cB) {
#pragma unroll
        for (int kk = 0; kk < 2; ++kk) {
            int rch = ((kk * 4 + hi) ^ (lo & 7)) << 3;  // row&7 == lo&7 for frag rows
            bf16x8 af[4], bfr[NF];
#pragma unroll
            for (int i = 0; i < 4; ++i) af[i] = *(const bf16x8*)&cA[(m0 + 16 * i + lo) * 64 + rch];
#pragma unroll
            for (int j = 0; j < NF; ++j) bfr[j] = *(const bf16x8*)&cB[(n0 + 16 * j + lo) * 64 + rch];
#pragma unroll
            for (int i = 0; i < 4; ++i)
#pragma unroll
                for (int j = 0; j < NF; ++j) acc[i][j] = mfma16(af[i], bfr[j], acc[i][j]);
        }
    };

    // counted-vmcnt pipeline: prefetch stays in flight across raw barriers
    STAGE(sA0, sB0, 0);
#pragma unroll
    for (int kp = 0; kp < 8; kp += 2) {
        if (kp + 1 < 8) { STAGE(sA1, sB1, (kp + 1) * 64); waitv<L>(); } else { waitv<0>(); }
        bar_raw();                 // buf0 ready for all waves
        COMPUTE(sA0, sB0);
        bar_raw();                 // all waves done reading buf0
        if (kp + 2 < 8) { STAGE(sA0, sB0, (kp + 2) * 64); waitv<L>(); } else { waitv<0>(); }
        bar_raw();
        COMPUTE(sA1, sB1);
        bar_raw();
    }

    // ---- epilogue: C through LDS, coalesced float4 stores ----
    float* cs = (float*)smem_raw;   // stride 132
    float mn = 1e30f, mx = -1e30f;
    constexpr int NH = (MTILE == 128) ? 2 : 1;
#pragma unroll
    for (int h = 0; h < NH; ++h) {
        __syncthreads();
        if (MTILE == 64 || (w >> 1) == h) {
#pragma unroll
            for (int i = 0; i < 4; ++i)
#pragma unroll
                for (int r = 0; r < 4; ++r) {
                    int rl = 16 * i + hi * 4 + r;
                    float bi = bias[mo * MTILE + h * 64 + rl];
#pragma unroll
                    for (int j = 0; j < NF; ++j)
                        cs[rl * 132 + n0 + 16 * j + lo] = acc[i][j][r] + bi;
                }
        }
        __syncthreads();
#pragma unroll
        for (int it = 0; it < 8; ++it) {
            int lin = it * 256 + tid;
            int rr = lin >> 5, cc = (lin & 31) << 2;
            float4 v = *(const float4*)&cs[rr * 132 + cc];
            if (MINMAX) {
                mn = fminf(mn, fminf(fminf(v.x, v.y), fminf(v.z, v.w)));
                mx = fmaxf(mx, fmaxf(fmaxf(v.x, v.y), fmaxf(v.z, v.w)));
            }
            int grow = mo * MTILE + h * 64 + rr;
            size_t gaddr = ((size_t)b * M + grow) * 1024 + nt * 128 + cc;
            if (RESID) {
                float4 rv = *(const float4*)&resid[gaddr];
                v.x += rv.x; v.y += rv.y; v.z += rv.z; v.w += rv.w;
            }
            *(float4*)&out[gaddr] = v;
        }
    }

    if (MINMAX) {
#pragma unroll
        for (int msk = 1; msk < 64; msk <<= 1) {
            mn = fminf(mn, __shfl_xor(mn, msk));
            mx = fmaxf(mx, __shfl_xor(mx, msk));
        }
        if (l == 0) { smn[w] = mn; smx[w] = mx; }
        __syncthreads();
        if (tid == 0) {
            mn = fminf(fminf(smn[0], smn[1]), fminf(smn[2], smn[3]));
            mx = fmaxf(fmaxf(smx[0], smx[1]), fmaxf(smx[2], smx[3]));
            // per-block private slot: no atomics, no init, no contention
            int id = mo >> 2;                      // q/k/v (4 x 128-row tiles each)
            int slot = nb * 4 + (mo & 3);          // 0..255, unique per (id, block)
            pmm[id * 512 + slot * 2]     = mn;
            pmm[id * 512 + slot * 2 + 1] = mx;
        }
    }
}

// ---------------- quant Q/K/V pass ----------------
// grid (64 bh, 16 tile); integer-valued bf16: qi (bh,t,c), ki (bh,s,c), vi (bh,c,s)
__global__ __launch_bounds__(256) void quant_qkv(const float* __restrict__ qkv,
                                                 const float* __restrict__ pmm,
                                                 __bf16* __restrict__ qi,
                                                 __bf16* __restrict__ ki,
                                                 __bf16* __restrict__ vi) {
    int bh = blockIdx.x, tt = blockIdx.y;
    int b = bh >> 3, hh = bh & 7;
    int t0 = tt * 64;
    const float* qg = qkv + (size_t)(b * 1536 + hh * 192) * 1024;
    const float* kg = qg + 65536;
    const float* vg = qg + 131072;
    int tid = threadIdx.x;

    __shared__ float sred[8];
    float mn0, mx0, mn1, mx1, mn2, mx2;
    red_mm(pmm, 0, tid, sred, mn0, mx0);
    red_mm(pmm, 1, tid, sred, mn1, mx1);
    red_mm(pmm, 2, tid, sred, mn2, mx2);
    float qsc = fmaxf((mx0 - mn0) * (1.f / 255.f), 1e-8f), qzp = rintf(-mn0 / qsc);
    float ksc = fmaxf((mx1 - mn1) * (1.f / 255.f), 1e-8f), kzp = rintf(-mn1 / ksc);
    float vsc = fmaxf((mx2 - mn2) * (1.f / 255.f), 1e-8f), vzp = rintf(-mn2 / vsc);
    float inv_q = 1.f / qsc, inv_k = 1.f / ksc, inv_v = 1.f / vsc;

    __shared__ __bf16 sT[64][68];
    int cr = tid >> 4, t4 = tid & 15;
    int s = tid >> 2, c0 = (tid & 3) * 16;

    // V stream
    __bf16* vd = vi + (size_t)bh * 65536;
#pragma unroll
    for (int r = 0; r < 4; ++r) {
        int c = 16 * r + cr;
        float4 v = *(const float4*)(vg + (size_t)c * 1024 + t0 + t4 * 4);
        bf16x4 o = {(__bf16)dqi(v.x, inv_v, vzp), (__bf16)dqi(v.y, inv_v, vzp),
                    (__bf16)dqi(v.z, inv_v, vzp), (__bf16)dqi(v.w, inv_v, vzp)};
        *(bf16x4*)(vd + (size_t)c * 1024 + t0 + t4 * 4) = o;
    }

    // K transpose -> (s, c)
#pragma unroll
    for (int r = 0; r < 4; ++r) {
        int c = 16 * r + cr;
        float4 v = *(const float4*)(kg + (size_t)c * 1024 + t0 + t4 * 4);
        sT[t4 * 4 + 0][c] = (__bf16)dqi(v.x, inv_k, kzp);
        sT[t4 * 4 + 1][c] = (__bf16)dqi(v.y, inv_k, kzp);
        sT[t4 * 4 + 2][c] = (__bf16)dqi(v.z, inv_k, kzp);
        sT[t4 * 4 + 3][c] = (__bf16)dqi(v.w, inv_k, kzp);
    }
    __syncthreads();
    {
        bf16x8 a0 = *(const bf16x8*)&sT[s][c0];
        bf16x8 a1 = *(const bf16x8*)&sT[s][c0 + 8];
        __bf16* kd = ki + ((size_t)bh * 1024 + t0 + s) * 64 + c0;
        *(bf16x8*)kd = a0;
        *(bf16x8*)(kd + 8) = a1;
    }
    __syncthreads();

    // Q transpose -> (t, c)
#pragma unroll
    for (int r = 0; r < 4; ++r) {
        int c = 16 * r + cr;
        float4 v = *(const float4*)(qg + (size_t)c * 1024 + t0 + t4 * 4);
        sT[t4 * 4 + 0][c] = (__bf16)dqi(v.x, inv_q, qzp);
        sT[t4 * 4 + 1][c] = (__bf16)dqi(v.y, inv_q, qzp);
        sT[t4 * 4 + 2][c] = (__bf16)dqi(v.z, inv_q, qzp);
        sT[t4 * 4 + 3][c] = (__bf16)dqi(v.w, inv_q, qzp);
    }
    __syncthreads();
    {
        bf16x8 a0 = *(const bf16x8*)&sT[s][c0];
        bf16x8 a1 = *(const bf16x8*)&sT[s][c0 + 8];
        __bf16* qd = qi + ((size_t)bh * 1024 + t0 + s) * 64 + c0;
        *(bf16x8*)qd = a0;
        *(bf16x8*)(qd + 8) = a1;
    }
}

// ---------------- attention: all-bf16 inputs, LDS K/V, exp2 softmax, defer-max ----------------
__global__ __launch_bounds__(256) void attn4(const __bf16* __restrict__ qi,
                                             const __bf16* __restrict__ ki,
                                             const __bf16* __restrict__ vi,
                                             const float* __restrict__ pmm,
                                             __bf16* __restrict__ aT) {
    int f = blockIdx.x;
    int bh = (f & 7) * 8 + ((f >> 3) & 7);  // 8 heads x 16 t-tiles per XCD
    int tt = f >> 6;
    int b = bh >> 3, hh = bh & 7;
    int t0 = tt * 64;
    const __bf16* kb = ki + (size_t)bh * 65536;
    const __bf16* vb = vi + (size_t)bh * 65536;
    int tid = threadIdx.x;

    __shared__ float sred[8];
    float mn0, mx0, mn1, mx1, mn2, mx2;
    red_mm(pmm, 0, tid, sred, mn0, mx0);
    red_mm(pmm, 1, tid, sred, mn1, mx1);
    red_mm(pmm, 2, tid, sred, mn2, mx2);
    float qsc = fmaxf((mx0 - mn0) * (1.f / 255.f), 1e-8f);
    float ksc = fmaxf((mx1 - mn1) * (1.f / 255.f), 1e-8f);
    float vsc = fmaxf((mx2 - mn2) * (1.f / 255.f), 1e-8f);
    float alpha2 = qsc * ksc * 0.125f * 1.4426950408889634f;  // alpha * log2(e)
    float thr = 11.5415603f / alpha2;                          // 8 nats in raw-score units

    __shared__ __bf16 sh[64][72];    // per-wave P -> output stage
    __shared__ __bf16 kS[64 * 64];   // K tile (s,c), chunk-swizzled
    __shared__ __bf16 vS[64 * 64];   // V tile (c,s), chunk-swizzled
    int l = tid & 63, w = tid >> 6;
    int lo = l & 15, hi = l >> 4;

    // q frags straight from qi (integer-valued, pre-transposed)
    const __bf16* qrow = qi + ((size_t)bh * 1024 + t0 + 16 * w + lo) * 64;
    bf16x8 qf0 = *(const bf16x8*)(qrow + hi * 8);
    bf16x8 qf1 = *(const bf16x8*)(qrow + 32 + hi * 8);

    // staging geometry: thread -> row (0..63), two 16B chunks
    int srow = tid >> 2, sc2 = (tid & 3) * 2;
    int swz0 = (sc2 ^ (srow & 7)) << 3;
    int swz1 = ((sc2 + 1) ^ (srow & 7)) << 3;
    const __bf16* kROW = kb + (size_t)srow * 64;          // + st*4096
    const __bf16* vROW = vb + (size_t)srow * 1024;        // + st*64
    int lx = lo & 7;
    int rc0 = (hi ^ lx) << 3;          // kk=0 chunk
    int rc1 = ((4 + hi) ^ lx) << 3;    // kk=1 chunk

    // prefetch tile 0
    bf16x8 kr0 = *(const bf16x8*)(kROW + sc2 * 8);
    bf16x8 kr1 = *(const bf16x8*)(kROW + sc2 * 8 + 8);
    bf16x8 vr0 = *(const bf16x8*)(vROW + sc2 * 8);
    bf16x8 vr1 = *(const bf16x8*)(vROW + sc2 * 8 + 8);

    f32x4 acc0 = {}, acc1 = {}, acc2 = {}, acc3 = {};
    float m_run = -1e30f, l_run = 0.f;

    for (int st = 0; st < 16; ++st) {
        __syncthreads();   // previous tile's LDS reads done
        *(bf16x8*)(kS + srow * 64 + swz0) = kr0;
        *(bf16x8*)(kS + srow * 64 + swz1) = kr1;
        *(bf16x8*)(vS + srow * 64 + swz0) = vr0;
        *(bf16x8*)(vS + srow * 64 + swz1) = vr1;
        __syncthreads();   // tile staged
        if (st < 15) {     // prefetch next tile during compute
            kr0 = *(const bf16x8*)(kROW + (st + 1) * 4096 + sc2 * 8);
            kr1 = *(const bf16x8*)(kROW + (st + 1) * 4096 + sc2 * 8 + 8);
            vr0 = *(const bf16x8*)(vROW + (st + 1) * 64 + sc2 * 8);
            vr1 = *(const bf16x8*)(vROW + (st + 1) * 64 + sc2 * 8 + 8);
        }

        // scores: D[s][t] = K·Q (raw integer dot products)
        f32x4 sf[4] = {};
        __builtin_amdgcn_s_setprio(1);
#pragma unroll
        for (int sm = 0; sm < 4; ++sm)
            sf[sm] = mfma16(*(const bf16x8*)(kS + (16 * sm + lo) * 64 + rc0), qf0, sf[sm]);
#pragma unroll
        for (int sm = 0; sm < 4; ++sm)
            sf[sm] = mfma16(*(const bf16x8*)(kS + (16 * sm + lo) * 64 + rc1), qf1, sf[sm]);
        __builtin_amdgcn_s_setprio(0);

        // online softmax in exp2 space (t = lane-local)
        float tm = -1e30f;
#pragma unroll
        for (int sm = 0; sm < 4; ++sm) {
            float a = fmaxf(sf[sm][0], sf[sm][1]);
            float c = fmaxf(sf[sm][2], sf[sm][3]);
            tm = fmaxf(tm, fmaxf(a, c));
        }
        tm = fmaxf(tm, __shfl_xor(tm, 16));
        tm = fmaxf(tm, __shfl_xor(tm, 32));
        if (!__all(tm <= m_run + thr)) {   // defer-max
            float mnew = fmaxf(m_run, tm);
            float fr = exp2i(alpha2 * (m_run - mnew));
            acc0 *= fr; acc1 *= fr; acc2 *= fr; acc3 *= fr;
            l_run *= fr;
            m_run = mnew;
        }
        float cc = -alpha2 * m_run;
        float ts = 0.f;
#pragma unroll
        for (int sm = 0; sm < 4; ++sm)
#pragma unroll
            for (int r = 0; r < 4; ++r) {
                float p = exp2i(fmaf(sf[sm][r], alpha2, cc));
                sf[sm][r] = p;
                ts += p;
            }
        ts += __shfl_xor(ts, 16);
        ts += __shfl_xor(ts, 32);
        l_run += ts;

        // P -> LDS (wave-private rows)
#pragma unroll
        for (int sm = 0; sm < 4; ++sm) {
            bf16x4 pb = {(__bf16)sf[sm][0], (__bf16)sf[sm][1], (__bf16)sf[sm][2], (__bf16)sf[sm][3]};
            *(bf16x4*)&sh[16 * w + lo][16 * sm + hi * 4] = pb;
        }
        bf16x8 pf0 = *(const bf16x8*)&sh[16 * w + lo][hi * 8];
        bf16x8 pf1 = *(const bf16x8*)&sh[16 * w + lo][32 + hi * 8];

        // PV: D[c][t] += V·P
        __builtin_amdgcn_s_setprio(1);
        acc0 = mfma16(*(const bf16x8*)(vS + (lo) * 64 + rc0), pf0, acc0);
        acc1 = mfma16(*(const bf16x8*)(vS + (16 + lo) * 64 + rc0), pf0, acc1);
        acc2 = mfma16(*(const bf16x8*)(vS + (32 + lo) * 64 + rc0), pf0, acc2);
        acc3 = mfma16(*(const bf16x8*)(vS + (48 + lo) * 64 + rc0), pf0, acc3);
        acc0 = mfma16(*(const bf16x8*)(vS + (lo) * 64 + rc1), pf1, acc0);
        acc1 = mfma16(*(const bf16x8*)(vS + (16 + lo) * 64 + rc1), pf1, acc1);
        acc2 = mfma16(*(const bf16x8*)(vS + (32 + lo) * 64 + rc1), pf1, acc2);
        acc3 = mfma16(*(const bf16x8*)(vS + (48 + lo) * 64 + rc1), pf1, acc3);
        __builtin_amdgcn_s_setprio(0);
    }

    float rl = vsc / l_run;
    __syncthreads();
    {
        bf16x4 o0 = {(__bf16)(acc0[0] * rl), (__bf16)(acc0[1] * rl), (__bf16)(acc0[2] * rl), (__bf16)(acc0[3] * rl)};
        bf16x4 o1 = {(__bf16)(acc1[0] * rl), (__bf16)(acc1[1] * rl), (__bf16)(acc1[2] * rl), (__bf16)(acc1[3] * rl)};
        bf16x4 o2 = {(__bf16)(acc2[0] * rl), (__bf16)(acc2[1] * rl), (__bf16)(acc2[2] * rl), (__bf16)(acc2[3] * rl)};
        bf16x4 o3 = {(__bf16)(acc3[0] * rl), (__bf16)(acc3[1] * rl), (__bf16)(acc3[2] * rl), (__bf16)(acc3[3] * rl)};
        *(bf16x4*)&sh[16 * w + lo][0  + hi * 4] = o0;
        *(bf16x4*)&sh[16 * w + lo][16 + hi * 4] = o1;
        *(bf16x4*)&sh[16 * w + lo][32 + hi * 4] = o2;
        *(bf16x4*)&sh[16 * w + lo][48 + hi * 4] = o3;
    }
    __syncthreads();
    __bf16* ap = aT + ((size_t)b * 1024 + t0 + (tid >> 2)) * 512 + hh * 64;
    bf16x8 v0 = *(const bf16x8*)&sh[tid >> 2][(tid & 3) * 8];
    bf16x8 v1 = *(const bf16x8*)&sh[tid >> 2][32 + (tid & 3) * 8];
    *(bf16x8*)(ap + (tid & 3) * 8) = v0;
    *(bf16x8*)(ap + 32 + (tid & 3) * 8) = v1;
}

// ---------------- fallback attention (fp32 qkv, used if ws too small) ----------------
__global__ __launch_bounds__(256) void attn_mfma(const float* __restrict__ qkv,
                                                 const float* __restrict__ pmm,
                                                 __bf16* __restrict__ aT) {
    int f = blockIdx.x;
    int bh = (f & 7) * 8 + ((f >> 3) & 7);
    int tt = f >> 6;
    int b = bh >> 3, hh = bh & 7;
    int t0 = tt * 64;
    const float* qg = qkv + (size_t)(b * 1536 + hh * 192) * 1024;
    const float* kg = qg + (size_t)64 * 1024;
    const float* vg = qg + (size_t)128 * 1024;
    int tid = threadIdx.x;

    __shared__ float sred[8];
    float mn0, mx0, mn1, mx1, mn2, mx2;
    red_mm(pmm, 0, tid, sred, mn0, mx0);
    red_mm(pmm, 1, tid, sred, mn1, mx1);
    red_mm(pmm, 2, tid, sred, mn2, mx2);
    float qsc = fmaxf((mx0 - mn0) * (1.f / 255.f), 1e-8f), qzp = rintf(-mn0 / qsc);
    float ksc = fmaxf((mx1 - mn1) * (1.f / 255.f), 1e-8f), kzp = rintf(-mn1 / ksc);
    float vsc = fmaxf((mx2 - mn2) * (1.f / 255.f), 1e-8f), vzp = rintf(-mn2 / vsc);
    float inv_q = 1.f / qsc, inv_k = 1.f / ksc, inv_v = 1.f / vsc;
    float alpha = qsc * ksc * 0.125f;

    __shared__ __bf16 qT[64][72];
    __shared__ __bf16 kT[64][72];
    __shared__ __bf16 vL[64][72];
    __shared__ __bf16 pL[4][16][72];

    int l = tid & 63, w = tid >> 6;
    int lo = l & 15, hi = l >> 4;
    int c0 = (tid >> 4) * 4;
    int tl = tid & 15;

#pragma unroll
    for (int r = 0; r < 4; ++r) {
        int t = tl + 16 * r;
        float y0 = dqi(qg[(size_t)(c0 + 0) * 1024 + t0 + t], inv_q, qzp);
        float y1 = dqi(qg[(size_t)(c0 + 1) * 1024 + t0 + t], inv_q, qzp);
        float y2 = dqi(qg[(size_t)(c0 + 2) * 1024 + t0 + t], inv_q, qzp);
        float y3 = dqi(qg[(size_t)(c0 + 3) * 1024 + t0 + t], inv_q, qzp);
        bf16x4 o = {(__bf16)y0, (__bf16)y1, (__bf16)y2, (__bf16)y3};
        *(bf16x4*)&qT[t][c0] = o;
    }
    __syncthreads();
    bf16x8 qf0 = *(const bf16x8*)&qT[16 * w + lo][hi * 8];
    bf16x8 qf1 = *(const bf16x8*)&qT[16 * w + lo][32 + hi * 8];

    f32x4 acc0 = {}, acc1 = {}, acc2 = {}, acc3 = {};
    float m_run = -1e30f, l_run = 0.f;

    for (int st = 0; st < 16; ++st) {
        int s0 = st * 64;
        __syncthreads();
#pragma unroll
        for (int r = 0; r < 4; ++r) {
            int srow = tl + 16 * r;
            float y0 = dqi(kg[(size_t)(c0 + 0) * 1024 + s0 + srow], inv_k, kzp);
            float y1 = dqi(kg[(size_t)(c0 + 1) * 1024 + s0 + srow], inv_k, kzp);
            float y2 = dqi(kg[(size_t)(c0 + 2) * 1024 + s0 + srow], inv_k, kzp);
            float y3 = dqi(kg[(size_t)(c0 + 3) * 1024 + s0 + srow], inv_k, kzp);
            bf16x4 ok = {(__bf16)y0, (__bf16)y1, (__bf16)y2, (__bf16)y3};
            *(bf16x4*)&kT[srow][c0] = ok;
            int c = (tid >> 4) + 16 * r;
            float4 vv = *(const float4*)(vg + (size_t)c * 1024 + s0 + (tid & 15) * 4);
            bf16x4 ov = {(__bf16)dqi(vv.x, inv_v, vzp), (__bf16)dqi(vv.y, inv_v, vzp),
                         (__bf16)dqi(vv.z, inv_v, vzp), (__bf16)dqi(vv.w, inv_v, vzp)};
            *(bf16x4*)&vL[c][(tid & 15) * 4] = ov;
        }
        __syncthreads();

        f32x4 sf[4] = {};
#pragma unroll
        for (int sm = 0; sm < 4; ++sm)
            sf[sm] = mfma16(*(const bf16x8*)&kT[16 * sm + lo][hi * 8], qf0, sf[sm]);
#pragma unroll
        for (int sm = 0; sm < 4; ++sm)
            sf[sm] = mfma16(*(const bf16x8*)&kT[16 * sm + lo][32 + hi * 8], qf1, sf[sm]);

        float tm = -1e30f;
#pragma unroll
        for (int sm = 0; sm < 4; ++sm)
#pragma unroll
            for (int r = 0; r < 4; ++r) { sf[sm][r] *= alpha; tm = fmaxf(tm, sf[sm][r]); }
        tm = fmaxf(tm, __shfl_xor(tm, 16));
        tm = fmaxf(tm, __shfl_xor(tm, 32));
        float mnew = fmaxf(m_run, tm);
        float ts = 0.f;
#pragma unroll
        for (int sm = 0; sm < 4; ++sm)
#pragma unroll
            for (int r = 0; r < 4; ++r) {
                float p = __expf(sf[sm][r] - mnew);
                sf[sm][r] = p;
                ts += p;
            }
        ts += __shfl_xor(ts, 16);
        ts += __shfl_xor(ts, 32);
        float fr = __expf(m_run - mnew);
        l_run = l_run * fr + ts;
        m_run = mnew;
        acc0 *= fr; acc1 *= fr; acc2 *= fr; acc3 *= fr;

#pragma unroll
        for (int sm = 0; sm < 4; ++sm) {
            bf16x4 pb = {(__bf16)sf[sm][0], (__bf16)sf[sm][1], (__bf16)sf[sm][2], (__bf16)sf[sm][3]};
            *(bf16x4*)&pL[w][lo][16 * sm + hi * 4] = pb;
        }
        bf16x8 pf0 = *(const bf16x8*)&pL[w][lo][hi * 8];
        bf16x8 pf1 = *(const bf16x8*)&pL[w][lo][32 + hi * 8];
        acc0 = mfma16(*(const bf16x8*)&vL[lo][hi * 8], pf0, acc0);
        acc1 = mfma16(*(const bf16x8*)&vL[16 + lo][hi * 8], pf0, acc1);
        acc2 = mfma16(*(const bf16x8*)&vL[32 + lo][hi * 8], pf0, acc2);
        acc3 = mfma16(*(const bf16x8*)&vL[48 + lo][hi * 8], pf0, acc3);
        acc0 = mfma16(*(const bf16x8*)&vL[lo][32 + hi * 8], pf1, acc0);
        acc1 = mfma16(*(const bf16x8*)&vL[16 + lo][32 + hi * 8], pf1, acc1);
        acc2 = mfma16(*(const bf16x8*)&vL[32 + lo][32 + hi * 8], pf1, acc2);
        acc3 = mfma16(*(const bf16x8*)&vL[48 + lo][32 + hi * 8], pf1, acc3);
    }

    float rl = vsc / l_run;
    __syncthreads();
    {
        bf16x4 o0 = {(__bf16)(acc0[0] * rl), (__bf16)(acc0[1] * rl), (__bf16)(acc0[2] * rl), (__bf16)(acc0[3] * rl)};
        bf16x4 o1 = {(__bf16)(acc1[0] * rl), (__bf16)(acc1[1] * rl), (__bf16)(acc1[2] * rl), (__bf16)(acc1[3] * rl)};
        bf16x4 o2 = {(__bf16)(acc2[0] * rl), (__bf16)(acc2[1] * rl), (__bf16)(acc2[2] * rl), (__bf16)(acc2[3] * rl)};
        bf16x4 o3 = {(__bf16)(acc3[0] * rl), (__bf16)(acc3[1] * rl), (__bf16)(acc3[2] * rl), (__bf16)(acc3[3] * rl)};
        *(bf16x4*)&qT[16 * w + lo][0  + hi * 4] = o0;
        *(bf16x4*)&qT[16 * w + lo][16 + hi * 4] = o1;
        *(bf16x4*)&qT[16 * w + lo][32 + hi * 4] = o2;
        *(bf16x4*)&qT[16 * w + lo][48 + hi * 4] = o3;
    }
    __syncthreads();
    __bf16* ap = aT + ((size_t)b * 1024 + t0 + (tid >> 2)) * 512 + hh * 64;
    bf16x8 v0 = *(const bf16x8*)&qT[tid >> 2][(tid & 3) * 8];
    bf16x8 v1 = *(const bf16x8*)&qT[tid >> 2][32 + (tid & 3) * 8];
    *(bf16x8*)(ap + (tid & 3) * 8) = v0;
    *(bf16x8*)(ap + 32 + (tid & 3) * 8) = v1;
}

extern "C" void kernel_launch(void* const* d_in, const int* in_sizes, int n_in,
                              void* d_out, int out_size, void* d_ws, size_t ws_size,
                              hipStream_t stream) {
    const float* x      = (const float*)d_in[0];
    const float* gn_w   = (const float*)d_in[1];
    const float* gn_b   = (const float*)d_in[2];
    const float* qkv_w  = (const float*)d_in[3];
    const float* qkv_b  = (const float*)d_in[4];
    const float* proj_w = (const float*)d_in[5];
    const float* proj_b = (const float*)d_in[6];
    char* ws = (char*)d_ws;
    float*    qkv = (float*)(ws + QKV_OFF);
    __bf16*   hT  = (__bf16*)(ws + HT_OFF);   // hT, later reused as aT
    __bf16*   wq  = (__bf16*)(ws + WQ_OFF);
    __bf16*   wp  = (__bf16*)(ws + WP_OFF);
    float*    pmm = (float*)(ws + MM_OFF);    // 3 x 256 x {mn,mx} partials
    __bf16*   ki  = (__bf16*)(ws + KI_OFF);
    __bf16*   vi  = (__bf16*)(ws + VI_OFF);
    __bf16*   qi  = (__bf16*)(ws + QI_OFF);
    float* out = (float*)d_out;

    gnprep<<<1280, 256, 0, stream>>>(x, gn_w, gn_b, hT, qkv_w, wq, proj_w, wp);
    mgemm5<128, 12, true, false><<<768, 256, 0, stream>>>(wq, hT, qkv_b, nullptr, qkv, 1536, pmm);
    if (ws_size >= NEED_NEW) {
        quant_qkv<<<dim3(64, 16), 256, 0, stream>>>(qkv, pmm, qi, ki, vi);
        attn4<<<1024, 256, 0, stream>>>(qi, ki, vi, pmm, hT);
    } else {
        attn_mfma<<<1024, 256, 0, stream>>>(qkv, pmm, hT);
    }
    mgemm5<64, 8, false, true><<<512, 256, 0, stream>>>(wp, hT, proj_b, x, out, 512, nullptr);
}

// Round 9
// 92.644 us; speedup vs baseline: 2.1170x; 1.1313x over previous
//
#include <hip/hip_runtime.h>

typedef __attribute__((ext_vector_type(8))) __bf16 bf16x8;
typedef __attribute__((ext_vector_type(4))) __bf16 bf16x4;
typedef __attribute__((ext_vector_type(4))) float  f32x4;

// Problem: x (8,512,32,32) fp32 -> B=8, C=512, T=1024; 32 groups; 8 heads (ch=64)

// ws layout (bytes)
static constexpr size_t QKV_OFF = 0;                     // fp32 (8,1536,1024) 48MB
static constexpr size_t HT_OFF  = 50331648;              // bf16 (8,1024,512) 8MB: hT then aT
static constexpr size_t WQ_OFF  = HT_OFF + 8388608;      // bf16 (1536,512)
static constexpr size_t WP_OFF  = WQ_OFF + 1572864;      // bf16 (512,512)
static constexpr size_t MM_OFF  = WP_OFF + 524288;       // pmm partials: 3*256*2 f32
static constexpr size_t KI_OFF  = MM_OFF + 8192;         // bf16 (64,1024,64) 8MB
static constexpr size_t VI_OFF  = KI_OFF + 8388608;      // bf16 (64,64,1024) 8MB
static constexpr size_t NEED_NEW = VI_OFF + 8388608;

// integer-valued dequant core: clip(rint(x/s)+zp,0,255)-zp == clip(rint(x/s), -zp, 255-zp)
__device__ __forceinline__ float dqi(float x, float inv_s, float zp) {
    float y = rintf(x * inv_s);
    return fminf(fmaxf(y, -zp), 255.0f - zp);
}
__device__ __forceinline__ f32x4 mfma16(bf16x8 a, bf16x8 b, f32x4 c) {
    return __builtin_amdgcn_mfma_f32_16x16x32_bf16(a, b, c, 0, 0, 0);
}
__device__ __forceinline__ float exp2i(float x) {  // raw v_exp_f32 (2^x)
    float r;
    asm("v_exp_f32 %0, %1" : "=v"(r) : "v"(x));
    return r;
}
__device__ __forceinline__ void glds16(const __bf16* g, __bf16* l) {
    __builtin_amdgcn_global_load_lds((const __attribute__((address_space(1))) void*)g,
                                     (__attribute__((address_space(3))) void*)l, 16, 0, 0);
}
template <int N> __device__ __forceinline__ void waitv() {
    asm volatile("s_waitcnt vmcnt(%0)" :: "n"(N) : "memory");
}
__device__ __forceinline__ void bar_raw() {
    asm volatile("s_barrier" ::: "memory");
}

// reduce pmm[id][256][2] partials -> (mn, mx). 256-thread version.
__device__ __forceinline__ void red_mm(const float* __restrict__ pmm, int id, int tid,
                                       float* sred, float& mn_out, float& mx_out) {
    float mn = pmm[id * 512 + tid * 2];
    float mx = pmm[id * 512 + tid * 2 + 1];
#pragma unroll
    for (int m = 1; m < 64; m <<= 1) {
        mn = fminf(mn, __shfl_xor(mn, m));
        mx = fmaxf(mx, __shfl_xor(mx, m));
    }
    if ((tid & 63) == 0) { sred[(tid >> 6) * 2] = mn; sred[(tid >> 6) * 2 + 1] = mx; }
    __syncthreads();
    mn = fminf(fminf(sred[0], sred[2]), fminf(sred[4], sred[6]));
    mx = fmaxf(fmaxf(sred[1], sred[3]), fmaxf(sred[5], sred[7]));
    __syncthreads();
    mn_out = fminf(mn, 0.0f);
    mx_out = fmaxf(mx, 0.0f);
}

// 512-thread version (slots read twice; harmless for min/max)
__device__ __forceinline__ void red_mm8(const float* __restrict__ pmm, int id, int tid,
                                        float* sred, float& mn_out, float& mx_out) {
    int slot = tid & 255;
    float mn = pmm[id * 512 + slot * 2];
    float mx = pmm[id * 512 + slot * 2 + 1];
#pragma unroll
    for (int m = 1; m < 64; m <<= 1) {
        mn = fminf(mn, __shfl_xor(mn, m));
        mx = fmaxf(mx, __shfl_xor(mx, m));
    }
    if ((tid & 63) == 0) { sred[(tid >> 6) * 2] = mn; sred[(tid >> 6) * 2 + 1] = mx; }
    __syncthreads();
    float a = fminf(fminf(sred[0], sred[2]), fminf(sred[4], sred[6]));
    float b = fminf(fminf(sred[8], sred[10]), fminf(sred[12], sred[14]));
    mn = fminf(a, b);
    a = fmaxf(fmaxf(sred[1], sred[3]), fmaxf(sred[5], sred[7]));
    b = fmaxf(fmaxf(sred[9], sred[11]), fmaxf(sred[13], sred[15]));
    mx = fmaxf(a, b);
    __syncthreads();
    mn_out = fminf(mn, 0.0f);
    mx_out = fmaxf(mx, 0.0f);
}

// ---------------- fused prep (weights fp32->bf16) + GroupNorm ----------------
__global__ __launch_bounds__(256) void gnprep(const float* __restrict__ x,
                                              const float* __restrict__ w,
                                              const float* __restrict__ bv,
                                              __bf16* __restrict__ hT,
                                              const float* __restrict__ qw,
                                              __bf16* __restrict__ wq,
                                              const float* __restrict__ pw,
                                              __bf16* __restrict__ wp) {
    int bid = blockIdx.x, tid = threadIdx.x;
    if (bid < 1024) {
        if (bid < 768) {
            int i = bid * 256 + tid;
            float4 v = ((const float4*)qw)[i];
            bf16x4 o = {(__bf16)v.x, (__bf16)v.y, (__bf16)v.z, (__bf16)v.w};
            ((bf16x4*)wq)[i] = o;
        } else {
            int i = (bid - 768) * 256 + tid;
            float4 v = ((const float4*)pw)[i];
            bf16x4 o = {(__bf16)v.x, (__bf16)v.y, (__bf16)v.z, (__bf16)v.w};
            ((bf16x4*)wp)[i] = o;
        }
        return;
    }
    int blk = bid - 1024;
    int b = blk >> 5, g = blk & 31;
    const float* xp = x + (size_t)(b * 512 + g * 16) * 1024;

    float4 v[16];
    float sum = 0.f, ss = 0.f;
#pragma unroll
    for (int i = 0; i < 16; ++i) {
        v[i] = *(const float4*)(xp + (size_t)i * 1024 + tid * 4);
        sum += v[i].x + v[i].y + v[i].z + v[i].w;
        ss  += v[i].x * v[i].x + v[i].y * v[i].y + v[i].z * v[i].z + v[i].w * v[i].w;
    }
#pragma unroll
    for (int m = 1; m < 64; m <<= 1) {
        sum += __shfl_xor(sum, m);
        ss  += __shfl_xor(ss, m);
    }
    __shared__ float s1[4], s2[4];
    int wid = tid >> 6;
    if ((tid & 63) == 0) { s1[wid] = sum; s2[wid] = ss; }
    __syncthreads();
    sum = s1[0] + s1[1] + s1[2] + s1[3];
    ss  = s2[0] + s2[1] + s2[2] + s2[3];
    float mean = sum * (1.0f / 16384.0f);
    float var  = ss * (1.0f / 16384.0f) - mean * mean;
    float rstd = rsqrtf(var + 1e-5f);

    float wc[16], bc[16];
#pragma unroll
    for (int c = 0; c < 16; ++c) { wc[c] = w[g * 16 + c] * rstd; bc[c] = bv[g * 16 + c]; }

#pragma unroll
    for (int j = 0; j < 4; ++j) {
        int t = tid * 4 + j;
        bf16x8 o0, o1;
#pragma unroll
        for (int c = 0; c < 8; ++c)
            o0[c] = (__bf16)(((&v[c].x)[j] - mean) * wc[c] + bc[c]);
#pragma unroll
        for (int c = 0; c < 8; ++c)
            o1[c] = (__bf16)(((&v[c + 8].x)[j] - mean) * wc[c + 8] + bc[c + 8]);
        __bf16* hp = hT + ((size_t)b * 1024 + t) * 512 + g * 16;
        *(bf16x8*)hp = o0;
        *(bf16x8*)(hp + 8) = o1;
    }
}

// ---------------- MFMA GEMM v5: BK=64 conflict-free swizzle + counted-vmcnt dbuf, NO atomics ----------------
template <int MTILE, int MOT, bool MINMAX, bool RESID>
__global__ __launch_bounds__(256, 2) void mgemm5(const __bf16* __restrict__ A,   // [M][512]
                                                 const __bf16* __restrict__ Bt,  // [8][1024][512]
                                                 const float* __restrict__ bias,
                                                 const float* __restrict__ resid,
                                                 float* __restrict__ out,
                                                 int M, float* __restrict__ pmm) {
    constexpr int NF  = (MTILE == 128) ? 4 : 2;
    constexpr int ASZ = MTILE * 64;
    constexpr int BSZ = 128 * 64;
    constexpr int LA  = MTILE / 32;
    constexpr int L   = LA + 4;
    constexpr int STG = 2 * (ASZ + BSZ) * 2;
    constexpr int CSB = 64 * 132 * 4;
    __shared__ __attribute__((aligned(16))) char smem_raw[(STG > CSB) ? STG : CSB];
    __bf16* sA0 = (__bf16*)smem_raw;
    __bf16* sA1 = sA0 + ASZ;
    __bf16* sB0 = sA1 + ASZ;
    __bf16* sB1 = sB0 + BSZ;
    __shared__ float smn[4], smx[4];

    int tid = threadIdx.x;
    int l = tid & 63, w = tid >> 6;
    int lo = l & 15, hi = l >> 4;

    int f = blockIdx.x;
    constexpr int NWG = MOT * 64;
    int wg = (f & 7) * (NWG / 8) + (f >> 3);
    int mo = wg % MOT, nb = wg / MOT;
    int nt = nb & 7, b = nb >> 3;

    const __bf16* Ap = A + (size_t)mo * MTILE * 512;
    const __bf16* Bp = Bt + ((size_t)b * 1024 + (size_t)nt * 128) * 512;
    int m0 = (MTILE == 128) ? (w >> 1) * 64 : 0;
    int n0 = (MTILE == 128) ? (w & 1) * 64 : w * 32;
    f32x4 acc[4][NF] = {};
    int scd = tid & 7;

    auto STAGE = [&](__bf16* dA, __bf16* dB, int k0) {
#pragma unroll
        for (int p = 0; p < LA; ++p) {
            int lin = p * 2048 + tid * 8;
            int row = lin >> 6;
            glds16(Ap + (size_t)row * 512 + k0 + ((scd ^ (row & 7)) << 3), dA + lin);
        }
#pragma unroll
        for (int p = 0; p < 4; ++p) {
            int lin = p * 2048 + tid * 8;
            int row = lin >> 6;
            glds16(Bp + (size_t)row * 512 + k0 + ((scd ^ (row & 7)) << 3), dB + lin);
        }
    };
    auto COMPUTE = [&](const __bf16* cA, const __bf16* cB) {
#pragma unroll
        for (int kk = 0; kk < 2; ++kk) {
            int rch = ((kk * 4 + hi) ^ (lo & 7)) << 3;
            bf16x8 af[4], bfr[NF];
#pragma unroll
            for (int i = 0; i < 4; ++i) af[i] = *(const bf16x8*)&cA[(m0 + 16 * i + lo) * 64 + rch];
#pragma unroll
            for (int j = 0; j < NF; ++j) bfr[j] = *(const bf16x8*)&cB[(n0 + 16 * j + lo) * 64 + rch];
#pragma unroll
            for (int i = 0; i < 4; ++i)
#pragma unroll
                for (int j = 0; j < NF; ++j) acc[i][j] = mfma16(af[i], bfr[j], acc[i][j]);
        }
    };

    STAGE(sA0, sB0, 0);
#pragma unroll
    for (int kp = 0; kp < 8; kp += 2) {
        if (kp + 1 < 8) { STAGE(sA1, sB1, (kp + 1) * 64); waitv<L>(); } else { waitv<0>(); }
        bar_raw();
        COMPUTE(sA0, sB0);
        bar_raw();
        if (kp + 2 < 8) { STAGE(sA0, sB0, (kp + 2) * 64); waitv<L>(); } else { waitv<0>(); }
        bar_raw();
        COMPUTE(sA1, sB1);
        bar_raw();
    }

    float* cs = (float*)smem_raw;
    float mn = 1e30f, mx = -1e30f;
    constexpr int NH = (MTILE == 128) ? 2 : 1;
#pragma unroll
    for (int h = 0; h < NH; ++h) {
        __syncthreads();
        if (MTILE == 64 || (w >> 1) == h) {
#pragma unroll
            for (int i = 0; i < 4; ++i)
#pragma unroll
                for (int r = 0; r < 4; ++r) {
                    int rl = 16 * i + hi * 4 + r;
                    float bi = bias[mo * MTILE + h * 64 + rl];
#pragma unroll
                    for (int j = 0; j < NF; ++j)
                        cs[rl * 132 + n0 + 16 * j + lo] = acc[i][j][r] + bi;
                }
        }
        __syncthreads();
#pragma unroll
        for (int it = 0; it < 8; ++it) {
            int lin = it * 256 + tid;
            int rr = lin >> 5, cc = (lin & 31) << 2;
            float4 v = *(const float4*)&cs[rr * 132 + cc];
            if (MINMAX) {
                mn = fminf(mn, fminf(fminf(v.x, v.y), fminf(v.z, v.w)));
                mx = fmaxf(mx, fmaxf(fmaxf(v.x, v.y), fmaxf(v.z, v.w)));
            }
            int grow = mo * MTILE + h * 64 + rr;
            size_t gaddr = ((size_t)b * M + grow) * 1024 + nt * 128 + cc;
            if (RESID) {
                float4 rv = *(const float4*)&resid[gaddr];
                v.x += rv.x; v.y += rv.y; v.z += rv.z; v.w += rv.w;
            }
            *(float4*)&out[gaddr] = v;
        }
    }

    if (MINMAX) {
#pragma unroll
        for (int msk = 1; msk < 64; msk <<= 1) {
            mn = fminf(mn, __shfl_xor(mn, msk));
            mx = fmaxf(mx, __shfl_xor(mx, msk));
        }
        if (l == 0) { smn[w] = mn; smx[w] = mx; }
        __syncthreads();
        if (tid == 0) {
            mn = fminf(fminf(smn[0], smn[1]), fminf(smn[2], smn[3]));
            mx = fmaxf(fmaxf(smx[0], smx[1]), fmaxf(smx[2], smx[3]));
            int id = mo >> 2;
            int slot = nb * 4 + (mo & 3);
            pmm[id * 512 + slot * 2]     = mn;
            pmm[id * 512 + slot * 2 + 1] = mx;
        }
    }
}

// ---------------- quant K/V pass (q now inlined in attn) ----------------
__global__ __launch_bounds__(256) void quant_kv(const float* __restrict__ qkv,
                                                const float* __restrict__ pmm,
                                                __bf16* __restrict__ ki,
                                                __bf16* __restrict__ vi) {
    int bh = blockIdx.x, tt = blockIdx.y;
    int b = bh >> 3, hh = bh & 7;
    int t0 = tt * 64;
    const float* kg = qkv + ((size_t)(b * 1536 + hh * 192) + 64) * 1024;
    const float* vg = kg + 65536;
    int tid = threadIdx.x;

    __shared__ float sred[8];
    float mn1, mx1, mn2, mx2;
    red_mm(pmm, 1, tid, sred, mn1, mx1);
    red_mm(pmm, 2, tid, sred, mn2, mx2);
    float ksc = fmaxf((mx1 - mn1) * (1.f / 255.f), 1e-8f), kzp = rintf(-mn1 / ksc);
    float vsc = fmaxf((mx2 - mn2) * (1.f / 255.f), 1e-8f), vzp = rintf(-mn2 / vsc);
    float inv_k = 1.f / ksc, inv_v = 1.f / vsc;

    __shared__ __bf16 sT[64][68];
    int cr = tid >> 4, t4 = tid & 15;
    int s = tid >> 2, c0 = (tid & 3) * 16;

    // V stream
    __bf16* vd = vi + (size_t)bh * 65536;
#pragma unroll
    for (int r = 0; r < 4; ++r) {
        int c = 16 * r + cr;
        float4 v = *(const float4*)(vg + (size_t)c * 1024 + t0 + t4 * 4);
        bf16x4 o = {(__bf16)dqi(v.x, inv_v, vzp), (__bf16)dqi(v.y, inv_v, vzp),
                    (__bf16)dqi(v.z, inv_v, vzp), (__bf16)dqi(v.w, inv_v, vzp)};
        *(bf16x4*)(vd + (size_t)c * 1024 + t0 + t4 * 4) = o;
    }

    // K transpose -> (s, c)
#pragma unroll
    for (int r = 0; r < 4; ++r) {
        int c = 16 * r + cr;
        float4 v = *(const float4*)(kg + (size_t)c * 1024 + t0 + t4 * 4);
        sT[t4 * 4 + 0][c] = (__bf16)dqi(v.x, inv_k, kzp);
        sT[t4 * 4 + 1][c] = (__bf16)dqi(v.y, inv_k, kzp);
        sT[t4 * 4 + 2][c] = (__bf16)dqi(v.z, inv_k, kzp);
        sT[t4 * 4 + 3][c] = (__bf16)dqi(v.w, inv_k, kzp);
    }
    __syncthreads();
    bf16x8 a0 = *(const bf16x8*)&sT[s][c0];
    bf16x8 a1 = *(const bf16x8*)&sT[s][c0 + 8];
    __bf16* kd = ki + ((size_t)bh * 1024 + t0 + s) * 64 + c0;
    *(bf16x8*)kd = a0;
    *(bf16x8*)(kd + 8) = a1;
}

// ---------------- attention v6: QBLK=128, 8 waves, dbuf K/V, 1 barrier/tile ----------------
__global__ __launch_bounds__(512, 4) void attn5(const float* __restrict__ qkv,
                                                const __bf16* __restrict__ ki,
                                                const __bf16* __restrict__ vi,
                                                const float* __restrict__ pmm,
                                                __bf16* __restrict__ aT) {
    int f = blockIdx.x;
    int bh = (f & 7) * 8 + ((f >> 3) & 7);  // 8 heads x 8 t-tiles per XCD
    int tt = f >> 6;                        // 0..7
    int b = bh >> 3, hh = bh & 7;
    int t0 = tt * 128;
    const float* qg = qkv + (size_t)(b * 1536 + hh * 192) * 1024;
    const __bf16* kb = ki + (size_t)bh * 65536;
    const __bf16* vb = vi + (size_t)bh * 65536;
    int tid = threadIdx.x;

    __shared__ float sred[16];
    float mn0, mx0, mn1, mx1, mn2, mx2;
    red_mm8(pmm, 0, tid, sred, mn0, mx0);
    red_mm8(pmm, 1, tid, sred, mn1, mx1);
    red_mm8(pmm, 2, tid, sred, mn2, mx2);
    float qsc = fmaxf((mx0 - mn0) * (1.f / 255.f), 1e-8f), qzp = rintf(-mn0 / qsc);
    float ksc = fmaxf((mx1 - mn1) * (1.f / 255.f), 1e-8f);
    float vsc = fmaxf((mx2 - mn2) * (1.f / 255.f), 1e-8f);
    float inv_q = 1.f / qsc;
    float alpha2 = qsc * ksc * 0.125f * 1.4426950408889634f;  // alpha * log2(e)
    float thr = 11.5415603f / alpha2;                          // 8 nats in raw-score units

    __shared__ __bf16 sh[128][72];   // q stage -> per-wave P -> output stage
    __shared__ __bf16 kS[2][4096];   // K tile (s,c), chunk-swizzled, double-buffered
    __shared__ __bf16 vS[2][4096];   // V tile (c,s), chunk-swizzled, double-buffered
    int l = tid & 63, w = tid >> 6;
    int lo = l & 15, hi = l >> 4;

    // staging geometry: thread -> row (0..63), one 16B chunk each for K and V
    int srow = tid >> 3, sc = tid & 7;
    int swz = (sc ^ (srow & 7)) << 3;
    const __bf16* kROW = kb + (size_t)srow * 64;          // + st*4096
    const __bf16* vROW = vb + (size_t)srow * 1024;        // + st*64
    int lx = lo & 7;
    int rc0 = (hi ^ lx) << 3;
    int rc1 = ((4 + hi) ^ lx) << 3;

    // issue tile-0 loads early; hide under q staging
    bf16x8 kr = *(const bf16x8*)(kROW + sc * 8);
    bf16x8 vr = *(const bf16x8*)(vROW + sc * 8);

    // inline q stage: transpose + dequant to integer-valued bf16 (128 t x 64 c)
    {
        int c0 = (tid >> 5) * 4;     // 0..60
        int tl = tid & 31;
#pragma unroll
        for (int r = 0; r < 4; ++r) {
            int t = tl + 32 * r;
            float y0 = dqi(qg[(size_t)(c0 + 0) * 1024 + t0 + t], inv_q, qzp);
            float y1 = dqi(qg[(size_t)(c0 + 1) * 1024 + t0 + t], inv_q, qzp);
            float y2 = dqi(qg[(size_t)(c0 + 2) * 1024 + t0 + t], inv_q, qzp);
            float y3 = dqi(qg[(size_t)(c0 + 3) * 1024 + t0 + t], inv_q, qzp);
            bf16x4 o = {(__bf16)y0, (__bf16)y1, (__bf16)y2, (__bf16)y3};
            *(bf16x4*)&sh[t][c0] = o;
        }
    }
    __syncthreads();
    bf16x8 qf0 = *(const bf16x8*)&sh[16 * w + lo][hi * 8];
    bf16x8 qf1 = *(const bf16x8*)&sh[16 * w + lo][32 + hi * 8];
    // stage tile 0 (waits vmcnt via data dep)
    *(bf16x8*)(kS[0] + srow * 64 + swz) = kr;
    *(bf16x8*)(vS[0] + srow * 64 + swz) = vr;
    __syncthreads();   // q reads done + tile 0 staged

    f32x4 acc0 = {}, acc1 = {}, acc2 = {}, acc3 = {};
    float m_run = -1e30f, l_run = 0.f;

    for (int st = 0; st < 16; ++st) {
        const __bf16* kc = kS[st & 1];
        const __bf16* vc = vS[st & 1];
        if (st < 15) {   // T14: issue next-tile loads before compute
            kr = *(const bf16x8*)(kROW + (st + 1) * 4096 + sc * 8);
            vr = *(const bf16x8*)(vROW + (st + 1) * 64 + sc * 8);
        }

        // scores: D[s][t] = K·Q (raw integer dot products)
        f32x4 sf[4] = {};
        __builtin_amdgcn_s_setprio(1);
#pragma unroll
        for (int sm = 0; sm < 4; ++sm)
            sf[sm] = mfma16(*(const bf16x8*)(kc + (16 * sm + lo) * 64 + rc0), qf0, sf[sm]);
#pragma unroll
        for (int sm = 0; sm < 4; ++sm)
            sf[sm] = mfma16(*(const bf16x8*)(kc + (16 * sm + lo) * 64 + rc1), qf1, sf[sm]);
        __builtin_amdgcn_s_setprio(0);

        // online softmax in exp2 space (t = lane-local)
        float tm = -1e30f;
#pragma unroll
        for (int sm = 0; sm < 4; ++sm) {
            float a = fmaxf(sf[sm][0], sf[sm][1]);
            float c = fmaxf(sf[sm][2], sf[sm][3]);
            tm = fmaxf(tm, fmaxf(a, c));
        }
        tm = fmaxf(tm, __shfl_xor(tm, 16));
        tm = fmaxf(tm, __shfl_xor(tm, 32));
        if (!__all(tm <= m_run + thr)) {   // defer-max
            float mnew = fmaxf(m_run, tm);
            float fr = exp2i(alpha2 * (m_run - mnew));
            acc0 *= fr; acc1 *= fr; acc2 *= fr; acc3 *= fr;
            l_run *= fr;
            m_run = mnew;
        }
        float cc = -alpha2 * m_run;
        float ts = 0.f;
#pragma unroll
        for (int sm = 0; sm < 4; ++sm)
#pragma unroll
            for (int r = 0; r < 4; ++r) {
                float p = exp2i(fmaf(sf[sm][r], alpha2, cc));
                sf[sm][r] = p;
                ts += p;
            }
        ts += __shfl_xor(ts, 16);
        ts += __shfl_xor(ts, 32);
        l_run += ts;

        // P -> LDS (wave-private rows)
#pragma unroll
        for (int sm = 0; sm < 4; ++sm) {
            bf16x4 pb = {(__bf16)sf[sm][0], (__bf16)sf[sm][1], (__bf16)sf[sm][2], (__bf16)sf[sm][3]};
            *(bf16x4*)&sh[16 * w + lo][16 * sm + hi * 4] = pb;
        }
        bf16x8 pf0 = *(const bf16x8*)&sh[16 * w + lo][hi * 8];
        bf16x8 pf1 = *(const bf16x8*)&sh[16 * w + lo][32 + hi * 8];

        // PV: D[c][t] += V·P
        __builtin_amdgcn_s_setprio(1);
        acc0 = mfma16(*(const bf16x8*)(vc + (lo) * 64 + rc0), pf0, acc0);
        acc1 = mfma16(*(const bf16x8*)(vc + (16 + lo) * 64 + rc0), pf0, acc1);
        acc2 = mfma16(*(const bf16x8*)(vc + (32 + lo) * 64 + rc0), pf0, acc2);
        acc3 = mfma16(*(const bf16x8*)(vc + (48 + lo) * 64 + rc0), pf0, acc3);
        acc0 = mfma16(*(const bf16x8*)(vc + (lo) * 64 + rc1), pf1, acc0);
        acc1 = mfma16(*(const bf16x8*)(vc + (16 + lo) * 64 + rc1), pf1, acc1);
        acc2 = mfma16(*(const bf16x8*)(vc + (32 + lo) * 64 + rc1), pf1, acc2);
        acc3 = mfma16(*(const bf16x8*)(vc + (48 + lo) * 64 + rc1), pf1, acc3);
        __builtin_amdgcn_s_setprio(0);

        if (st < 15) {   // write-late into the other buffer (readers finished at prev barrier)
            *(bf16x8*)(kS[(st + 1) & 1] + srow * 64 + swz) = kr;
            *(bf16x8*)(vS[(st + 1) & 1] + srow * 64 + swz) = vr;
        }
        __syncthreads();   // single barrier per tile
    }

    float rl = vsc / l_run;
    {
        bf16x4 o0 = {(__bf16)(acc0[0] * rl), (__bf16)(acc0[1] * rl), (__bf16)(acc0[2] * rl), (__bf16)(acc0[3] * rl)};
        bf16x4 o1 = {(__bf16)(acc1[0] * rl), (__bf16)(acc1[1] * rl), (__bf16)(acc1[2] * rl), (__bf16)(acc1[3] * rl)};
        bf16x4 o2 = {(__bf16)(acc2[0] * rl), (__bf16)(acc2[1] * rl), (__bf16)(acc2[2] * rl), (__bf16)(acc2[3] * rl)};
        bf16x4 o3 = {(__bf16)(acc3[0] * rl), (__bf16)(acc3[1] * rl), (__bf16)(acc3[2] * rl), (__bf16)(acc3[3] * rl)};
        *(bf16x4*)&sh[16 * w + lo][0  + hi * 4] = o0;
        *(bf16x4*)&sh[16 * w + lo][16 + hi * 4] = o1;
        *(bf16x4*)&sh[16 * w + lo][32 + hi * 4] = o2;
        *(bf16x4*)&sh[16 * w + lo][48 + hi * 4] = o3;
    }
    __syncthreads();
    __bf16* ap = aT + ((size_t)b * 1024 + t0 + (tid >> 2)) * 512 + hh * 64;
    bf16x8 v0 = *(const bf16x8*)&sh[tid >> 2][(tid & 3) * 8];
    bf16x8 v1 = *(const bf16x8*)&sh[tid >> 2][32 + (tid & 3) * 8];
    *(bf16x8*)(ap + (tid & 3) * 8) = v0;
    *(bf16x8*)(ap + 32 + (tid & 3) * 8) = v1;
}

// ---------------- fallback attention (fp32 qkv, used if ws too small) ----------------
__global__ __launch_bounds__(256) void attn_mfma(const float* __restrict__ qkv,
                                                 const float* __restrict__ pmm,
                                                 __bf16* __restrict__ aT) {
    int f = blockIdx.x;
    int bh = (f & 7) * 8 + ((f >> 3) & 7);
    int tt = f >> 6;
    int b = bh >> 3, hh = bh & 7;
    int t0 = tt * 64;
    const float* qg = qkv + (size_t)(b * 1536 + hh * 192) * 1024;
    const float* kg = qg + (size_t)64 * 1024;
    const float* vg = qg + (size_t)128 * 1024;
    int tid = threadIdx.x;

    __shared__ float sred[8];
    float mn0, mx0, mn1, mx1, mn2, mx2;
    red_mm(pmm, 0, tid, sred, mn0, mx0);
    red_mm(pmm, 1, tid, sred, mn1, mx1);
    red_mm(pmm, 2, tid, sred, mn2, mx2);
    float qsc = fmaxf((mx0 - mn0) * (1.f / 255.f), 1e-8f), qzp = rintf(-mn0 / qsc);
    float ksc = fmaxf((mx1 - mn1) * (1.f / 255.f), 1e-8f), kzp = rintf(-mn1 / ksc);
    float vsc = fmaxf((mx2 - mn2) * (1.f / 255.f), 1e-8f), vzp = rintf(-mn2 / vsc);
    float inv_q = 1.f / qsc, inv_k = 1.f / ksc, inv_v = 1.f / vsc;
    float alpha = qsc * ksc * 0.125f;

    __shared__ __bf16 qT[64][72];
    __shared__ __bf16 kT[64][72];
    __shared__ __bf16 vL[64][72];
    __shared__ __bf16 pL[4][16][72];

    int l = tid & 63, w = tid >> 6;
    int lo = l & 15, hi = l >> 4;
    int c0 = (tid >> 4) * 4;
    int tl = tid & 15;

#pragma unroll
    for (int r = 0; r < 4; ++r) {
        int t = tl + 16 * r;
        float y0 = dqi(qg[(size_t)(c0 + 0) * 1024 + t0 + t], inv_q, qzp);
        float y1 = dqi(qg[(size_t)(c0 + 1) * 1024 + t0 + t], inv_q, qzp);
        float y2 = dqi(qg[(size_t)(c0 + 2) * 1024 + t0 + t], inv_q, qzp);
        float y3 = dqi(qg[(size_t)(c0 + 3) * 1024 + t0 + t], inv_q, qzp);
        bf16x4 o = {(__bf16)y0, (__bf16)y1, (__bf16)y2, (__bf16)y3};
        *(bf16x4*)&qT[t][c0] = o;
    }
    __syncthreads();
    bf16x8 qf0 = *(const bf16x8*)&qT[16 * w + lo][hi * 8];
    bf16x8 qf1 = *(const bf16x8*)&qT[16 * w + lo][32 + hi * 8];

    f32x4 acc0 = {}, acc1 = {}, acc2 = {}, acc3 = {};
    float m_run = -1e30f, l_run = 0.f;

    for (int st = 0; st < 16; ++st) {
        int s0 = st * 64;
        __syncthreads();
#pragma unroll
        for (int r = 0; r < 4; ++r) {
            int srow = tl + 16 * r;
            float y0 = dqi(kg[(size_t)(c0 + 0) * 1024 + s0 + srow], inv_k, kzp);
            float y1 = dqi(kg[(size_t)(c0 + 1) * 1024 + s0 + srow], inv_k, kzp);
            float y2 = dqi(kg[(size_t)(c0 + 2) * 1024 + s0 + srow], inv_k, kzp);
            float y3 = dqi(kg[(size_t)(c0 + 3) * 1024 + s0 + srow], inv_k, kzp);
            bf16x4 ok = {(__bf16)y0, (__bf16)y1, (__bf16)y2, (__bf16)y3};
            *(bf16x4*)&kT[srow][c0] = ok;
            int c = (tid >> 4) + 16 * r;
            float4 vv = *(const float4*)(vg + (size_t)c * 1024 + s0 + (tid & 15) * 4);
            bf16x4 ov = {(__bf16)dqi(vv.x, inv_v, vzp), (__bf16)dqi(vv.y, inv_v, vzp),
                         (__bf16)dqi(vv.z, inv_v, vzp), (__bf16)dqi(vv.w, inv_v, vzp)};
            *(bf16x4*)&vL[c][(tid & 15) * 4] = ov;
        }
        __syncthreads();

        f32x4 sf[4] = {};
#pragma unroll
        for (int sm = 0; sm < 4; ++sm)
            sf[sm] = mfma16(*(const bf16x8*)&kT[16 * sm + lo][hi * 8], qf0, sf[sm]);
#pragma unroll
        for (int sm = 0; sm < 4; ++sm)
            sf[sm] = mfma16(*(const bf16x8*)&kT[16 * sm + lo][32 + hi * 8], qf1, sf[sm]);

        float tm = -1e30f;
#pragma unroll
        for (int sm = 0; sm < 4; ++sm)
#pragma unroll
            for (int r = 0; r < 4; ++r) { sf[sm][r] *= alpha; tm = fmaxf(tm, sf[sm][r]); }
        tm = fmaxf(tm, __shfl_xor(tm, 16));
        tm = fmaxf(tm, __shfl_xor(tm, 32));
        float mnew = fmaxf(m_run, tm);
        float ts = 0.f;
#pragma unroll
        for (int sm = 0; sm < 4; ++sm)
#pragma unroll
            for (int r = 0; r < 4; ++r) {
                float p = __expf(sf[sm][r] - mnew);
                sf[sm][r] = p;
                ts += p;
            }
        ts += __shfl_xor(ts, 16);
        ts += __shfl_xor(ts, 32);
        float fr = __expf(m_run - mnew);
        l_run = l_run * fr + ts;
        m_run = mnew;
        acc0 *= fr; acc1 *= fr; acc2 *= fr; acc3 *= fr;

#pragma unroll
        for (int sm = 0; sm < 4; ++sm) {
            bf16x4 pb = {(__bf16)sf[sm][0], (__bf16)sf[sm][1], (__bf16)sf[sm][2], (__bf16)sf[sm][3]};
            *(bf16x4*)&pL[w][lo][16 * sm + hi * 4] = pb;
        }
        bf16x8 pf0 = *(const bf16x8*)&pL[w][lo][hi * 8];
        bf16x8 pf1 = *(const bf16x8*)&pL[w][lo][32 + hi * 8];
        acc0 = mfma16(*(const bf16x8*)&vL[lo][hi * 8], pf0, acc0);
        acc1 = mfma16(*(const bf16x8*)&vL[16 + lo][hi * 8], pf0, acc1);
        acc2 = mfma16(*(const bf16x8*)&vL[32 + lo][hi * 8], pf0, acc2);
        acc3 = mfma16(*(const bf16x8*)&vL[48 + lo][hi * 8], pf0, acc3);
        acc0 = mfma16(*(const bf16x8*)&vL[lo][32 + hi * 8], pf1, acc0);
        acc1 = mfma16(*(const bf16x8*)&vL[16 + lo][32 + hi * 8], pf1, acc1);
        acc2 = mfma16(*(const bf16x8*)&vL[32 + lo][32 + hi * 8], pf1, acc2);
        acc3 = mfma16(*(const bf16x8*)&vL[48 + lo][32 + hi * 8], pf1, acc3);
    }

    float rl = vsc / l_run;
    __syncthreads();
    {
        bf16x4 o0 = {(__bf16)(acc0[0] * rl), (__bf16)(acc0[1] * rl), (__bf16)(acc0[2] * rl), (__bf16)(acc0[3] * rl)};
        bf16x4 o1 = {(__bf16)(acc1[0] * rl), (__bf16)(acc1[1] * rl), (__bf16)(acc1[2] * rl), (__bf16)(acc1[3] * rl)};
        bf16x4 o2 = {(__bf16)(acc2[0] * rl), (__bf16)(acc2[1] * rl), (__bf16)(acc2[2] * rl), (__bf16)(acc2[3] * rl)};
        bf16x4 o3 = {(__bf16)(acc3[0] * rl), (__bf16)(acc3[1] * rl), (__bf16)(acc3[2] * rl), (__bf16)(acc3[3] * rl)};
        *(bf16x4*)&qT[16 * w + lo][0  + hi * 4] = o0;
        *(bf16x4*)&qT[16 * w + lo][16 + hi * 4] = o1;
        *(bf16x4*)&qT[16 * w + lo][32 + hi * 4] = o2;
        *(bf16x4*)&qT[16 * w + lo][48 + hi * 4] = o3;
    }
    __syncthreads();
    __bf16* ap = aT + ((size_t)b * 1024 + t0 + (tid >> 2)) * 512 + hh * 64;
    bf16x8 v0 = *(const bf16x8*)&qT[tid >> 2][(tid & 3) * 8];
    bf16x8 v1 = *(const bf16x8*)&qT[tid >> 2][32 + (tid & 3) * 8];
    *(bf16x8*)(ap + (tid & 3) * 8) = v0;
    *(bf16x8*)(ap + 32 + (tid & 3) * 8) = v1;
}

extern "C" void kernel_launch(void* const* d_in, const int* in_sizes, int n_in,
                              void* d_out, int out_size, void* d_ws, size_t ws_size,
                              hipStream_t stream) {
    const float* x      = (const float*)d_in[0];
    const float* gn_w   = (const float*)d_in[1];
    const float* gn_b   = (const float*)d_in[2];
    const float* qkv_w  = (const float*)d_in[3];
    const float* qkv_b  = (const float*)d_in[4];
    const float* proj_w = (const float*)d_in[5];
    const float* proj_b = (const float*)d_in[6];
    char* ws = (char*)d_ws;
    float*    qkv = (float*)(ws + QKV_OFF);
    __bf16*   hT  = (__bf16*)(ws + HT_OFF);   // hT, later reused as aT
    __bf16*   wq  = (__bf16*)(ws + WQ_OFF);
    __bf16*   wp  = (__bf16*)(ws + WP_OFF);
    float*    pmm = (float*)(ws + MM_OFF);    // 3 x 256 x {mn,mx} partials
    __bf16*   ki  = (__bf16*)(ws + KI_OFF);
    __bf16*   vi  = (__bf16*)(ws + VI_OFF);
    float* out = (float*)d_out;

    gnprep<<<1280, 256, 0, stream>>>(x, gn_w, gn_b, hT, qkv_w, wq, proj_w, wp);
    mgemm5<128, 12, true, false><<<768, 256, 0, stream>>>(wq, hT, qkv_b, nullptr, qkv, 1536, pmm);
    if (ws_size >= NEED_NEW) {
        quant_kv<<<dim3(64, 16), 256, 0, stream>>>(qkv, pmm, ki, vi);
        attn5<<<512, 512, 0, stream>>>(qkv, ki, vi, pmm, hT);
    } else {
        attn_mfma<<<1024, 256, 0, stream>>>(qkv, pmm, hT);
    }
    mgemm5<64, 8, false, true><<<512, 256, 0, stream>>>(wp, hT, proj_b, x, out, 512, nullptr);
}